// Round 1
// baseline (668.021 us; speedup 1.0000x reference)
//
#include <hip/hip_runtime.h>
#include <hip/hip_bf16.h>
#include <math.h>

#define DIMS 1024
#define NHEADS 16
#define HDIM 64
#define NFEAT 128
#define BB 2
#define NN 1024
#define BN (BB*NN)   // 2048

#define SCALE 0.3535533905932738f      // 64^-0.25
#define INV_SQRT_M 0.08838834764831845f // 1/sqrt(128)

// ---------------- GEMM NT: C[i,j] = sum_k A[i,k]*B[j,k] (+bias[j]) ----------------
#define TILE 64
#define KT 16
__global__ __launch_bounds__(256) void gemm_nt(const float* __restrict__ A,
                                               const float* __restrict__ B,
                                               float* __restrict__ C,
                                               const float* __restrict__ bias,
                                               int M, int N, int K) {
    __shared__ float As[KT][TILE + 4];
    __shared__ float Bs[KT][TILE + 4];
    const int tx = threadIdx.x & 15;
    const int ty = threadIdx.x >> 4;
    const int bi = blockIdx.x * TILE;
    const int bj = blockIdx.y * TILE;
    const int lr = threadIdx.x >> 2;          // 0..63 tile row
    const int lc = (threadIdx.x & 3) << 2;    // k sub-offset
    float c[4][4] = {};
    for (int k0 = 0; k0 < K; k0 += KT) {
        float4 a4 = *(const float4*)&A[(size_t)(bi + lr) * K + k0 + lc];
        float4 b4 = *(const float4*)&B[(size_t)(bj + lr) * K + k0 + lc];
        __syncthreads();
        As[lc + 0][lr] = a4.x; As[lc + 1][lr] = a4.y; As[lc + 2][lr] = a4.z; As[lc + 3][lr] = a4.w;
        Bs[lc + 0][lr] = b4.x; Bs[lc + 1][lr] = b4.y; Bs[lc + 2][lr] = b4.z; Bs[lc + 3][lr] = b4.w;
        __syncthreads();
        #pragma unroll
        for (int kk = 0; kk < KT; ++kk) {
            float4 av = *(const float4*)&As[kk][ty << 2];
            float4 bv = *(const float4*)&Bs[kk][tx << 2];
            float a_[4] = {av.x, av.y, av.z, av.w};
            float b_[4] = {bv.x, bv.y, bv.z, bv.w};
            #pragma unroll
            for (int i = 0; i < 4; ++i)
                #pragma unroll
                for (int j = 0; j < 4; ++j)
                    c[i][j] += a_[i] * b_[j];
        }
    }
    #pragma unroll
    for (int i = 0; i < 4; ++i) {
        const int row = bi + (ty << 2) + i;
        #pragma unroll
        for (int j = 0; j < 4; ++j) {
            const int col = bj + (tx << 2) + j;
            float r = c[i][j];
            if (bias) r += bias[col];
            C[(size_t)row * N + col] = r;
        }
    }
}

// ---------------- phi_q: one block per (b,h,n) row ----------------
__global__ __launch_bounds__(128) void phi_q_kernel(const float* __restrict__ qbuf,
                                                    const float* __restrict__ omega,
                                                    float* __restrict__ phiq) {
    const int r = blockIdx.x;               // bh*NN + n
    const int bh = r >> 10, n = r & (NN - 1);
    const int b = bh >> 4, h = bh & 15;
    const int m = threadIdx.x;
    __shared__ float qs[HDIM];
    __shared__ float wred[2];
    const float* qrow = &qbuf[((size_t)(b * NN + n)) * DIMS + h * HDIM];
    if (m < HDIM) qs[m] = qrow[m] * SCALE;
    __syncthreads();
    float norm = 0.f, proj = 0.f;
    const float* om = &omega[m * HDIM];
    #pragma unroll 8
    for (int d0 = 0; d0 < HDIM; ++d0) {
        float qv = qs[d0];
        norm += qv * qv;
        proj += qv * om[d0];
    }
    const float lp = proj - 0.5f * norm;
    float mx = lp;
    #pragma unroll
    for (int o = 32; o >= 1; o >>= 1) mx = fmaxf(mx, __shfl_xor(mx, o));
    if ((threadIdx.x & 63) == 0) wred[threadIdx.x >> 6] = mx;
    __syncthreads();
    mx = fmaxf(wred[0], wred[1]);
    phiq[(size_t)r * NFEAT + m] = expf(lp - mx) * INV_SQRT_M + 1e-4f;
}

// ---------------- phi_k pass 1: logits + per-block max ----------------
__global__ __launch_bounds__(128) void phi_k_logits_kernel(const float* __restrict__ kbuf,
                                                           const float* __restrict__ omega,
                                                           float* __restrict__ lk,
                                                           float* __restrict__ blockmax) {
    const int r = blockIdx.x;
    const int bh = r >> 10, n = r & (NN - 1);
    const int b = bh >> 4, h = bh & 15;
    const int m = threadIdx.x;
    __shared__ float qs[HDIM];
    __shared__ float wred[2];
    const float* krow = &kbuf[((size_t)(b * NN + n)) * DIMS + h * HDIM];
    if (m < HDIM) qs[m] = krow[m] * SCALE;
    __syncthreads();
    float norm = 0.f, proj = 0.f;
    const float* om = &omega[m * HDIM];
    #pragma unroll 8
    for (int d0 = 0; d0 < HDIM; ++d0) {
        float kv = qs[d0];
        norm += kv * kv;
        proj += kv * om[d0];
    }
    const float lp = proj - 0.5f * norm;
    lk[(size_t)r * NFEAT + m] = lp;
    float mx = lp;
    #pragma unroll
    for (int o = 32; o >= 1; o >>= 1) mx = fmaxf(mx, __shfl_xor(mx, o));
    if ((threadIdx.x & 63) == 0) wred[threadIdx.x >> 6] = mx;
    __syncthreads();
    if (threadIdx.x == 0) blockmax[r] = fmaxf(wred[0], wred[1]);
}

__global__ __launch_bounds__(256) void reduce_max_kernel(const float* __restrict__ in,
                                                         int n, float* __restrict__ out) {
    float mx = -3.4e38f;
    for (int i = threadIdx.x; i < n; i += 256) mx = fmaxf(mx, in[i]);
    #pragma unroll
    for (int o = 32; o >= 1; o >>= 1) mx = fmaxf(mx, __shfl_xor(mx, o));
    __shared__ float r[4];
    if ((threadIdx.x & 63) == 0) r[threadIdx.x >> 6] = mx;
    __syncthreads();
    if (threadIdx.x == 0) out[0] = fmaxf(fmaxf(r[0], r[1]), fmaxf(r[2], r[3]));
}

__global__ __launch_bounds__(256) void phik_exp_kernel(float* __restrict__ lk,
                                                       const float* __restrict__ gmax, int n) {
    const int i = blockIdx.x * 256 + threadIdx.x;
    const float gm = gmax[0];
    if (i < n) lk[i] = expf(lk[i] - gm) * INV_SQRT_M + 1e-4f;
}

// ---------------- causal linear attention, chunked scan ----------------
// thread (g = tid&3, d = tid>>2) owns state S[m=g*32+j][d], j=0..31
#define CH 16
#define GS 36   // 32 + 4 pad: keeps the 4 g-groups on distinct banks, 16B-aligned

__global__ __launch_bounds__(256) void scan_partial(const float* __restrict__ phik,
                                                    const float* __restrict__ vbuf,
                                                    float* __restrict__ kvsum,
                                                    float* __restrict__ ksum) {
    const int c = blockIdx.x & 7, bh = blockIdx.x >> 3;
    const int b = bh >> 4, h = bh & 15;
    const int tid = threadIdx.x, g = tid & 3, d = tid >> 2;
    __shared__ float lpk[CH][4 * GS];
    __shared__ float lv[CH][HDIM];
    float S[32], Kc[32];
    #pragma unroll
    for (int j = 0; j < 32; ++j) { S[j] = 0.f; Kc[j] = 0.f; }
    const int n0 = c * 128;
    for (int st = 0; st < 128; st += CH) {
        __syncthreads();
        for (int e = tid; e < CH * NFEAT; e += 256) {
            const int s = e >> 7, m = e & 127;
            lpk[s][(m >> 5) * GS + (m & 31)] = phik[((size_t)bh * NN + n0 + st + s) * NFEAT + m];
        }
        for (int e = tid; e < CH * HDIM; e += 256) {
            const int s = e >> 6, dd = e & 63;
            lv[s][dd] = vbuf[((size_t)(b * NN + n0 + st + s)) * DIMS + h * HDIM + dd];
        }
        __syncthreads();
        for (int s = 0; s < CH; ++s) {
            const float vd = lv[s][d];
            #pragma unroll
            for (int j4 = 0; j4 < 8; ++j4) {
                const float4 fk = *(const float4*)&lpk[s][g * GS + (j4 << 2)];
                const int jj = j4 << 2;
                S[jj + 0] += fk.x * vd; Kc[jj + 0] += fk.x;
                S[jj + 1] += fk.y * vd; Kc[jj + 1] += fk.y;
                S[jj + 2] += fk.z * vd; Kc[jj + 2] += fk.z;
                S[jj + 3] += fk.w * vd; Kc[jj + 3] += fk.w;
            }
        }
    }
    const size_t base = (size_t)blockIdx.x * (NFEAT * HDIM);
    #pragma unroll
    for (int j = 0; j < 32; ++j) kvsum[base + (size_t)(g * 32 + j) * HDIM + d] = S[j];
    if (d == 0) {
        #pragma unroll
        for (int j = 0; j < 32; ++j) ksum[blockIdx.x * NFEAT + g * 32 + j] = Kc[j];
    }
}

__global__ __launch_bounds__(256) void scan_final(const float* __restrict__ phiq,
                                                  const float* __restrict__ phik,
                                                  const float* __restrict__ vbuf,
                                                  const float* __restrict__ kvsum,
                                                  const float* __restrict__ ksum,
                                                  float* __restrict__ att) {
    const int c = blockIdx.x & 7, bh = blockIdx.x >> 3;
    const int b = bh >> 4, h = bh & 15;
    const int tid = threadIdx.x, g = tid & 3, d = tid >> 2;
    __shared__ float lpq[CH][4 * GS];
    __shared__ float lpk[CH][4 * GS];
    __shared__ float lv[CH][HDIM];
    float S[32], Kc[32];
    #pragma unroll
    for (int j = 0; j < 32; ++j) { S[j] = 0.f; Kc[j] = 0.f; }
    for (int cp = 0; cp < c; ++cp) {
        const size_t base = ((size_t)bh * 8 + cp) * (NFEAT * HDIM);
        const float* kp = &ksum[(bh * 8 + cp) * NFEAT];
        #pragma unroll
        for (int j = 0; j < 32; ++j) {
            S[j]  += kvsum[base + (size_t)(g * 32 + j) * HDIM + d];
            Kc[j] += kp[g * 32 + j];
        }
    }
    const int n0 = c * 128;
    for (int st = 0; st < 128; st += CH) {
        __syncthreads();
        for (int e = tid; e < CH * NFEAT; e += 256) {
            const int s = e >> 7, m = e & 127;
            const size_t gi = ((size_t)bh * NN + n0 + st + s) * NFEAT + m;
            const int li = (m >> 5) * GS + (m & 31);
            lpq[s][li] = phiq[gi];
            lpk[s][li] = phik[gi];
        }
        for (int e = tid; e < CH * HDIM; e += 256) {
            const int s = e >> 6, dd = e & 63;
            lv[s][dd] = vbuf[((size_t)(b * NN + n0 + st + s)) * DIMS + h * HDIM + dd];
        }
        __syncthreads();
        for (int s = 0; s < CH; ++s) {
            const float vd = lv[s][d];
            float po = 0.f, pz = 0.f;
            #pragma unroll
            for (int j4 = 0; j4 < 8; ++j4) {
                const float4 fk = *(const float4*)&lpk[s][g * GS + (j4 << 2)];
                const float4 fq = *(const float4*)&lpq[s][g * GS + (j4 << 2)];
                const int jj = j4 << 2;
                S[jj + 0] += fk.x * vd; Kc[jj + 0] += fk.x; po += fq.x * S[jj + 0]; pz += fq.x * Kc[jj + 0];
                S[jj + 1] += fk.y * vd; Kc[jj + 1] += fk.y; po += fq.y * S[jj + 1]; pz += fq.y * Kc[jj + 1];
                S[jj + 2] += fk.z * vd; Kc[jj + 2] += fk.z; po += fq.z * S[jj + 2]; pz += fq.z * Kc[jj + 2];
                S[jj + 3] += fk.w * vd; Kc[jj + 3] += fk.w; po += fq.w * S[jj + 3]; pz += fq.w * Kc[jj + 3];
            }
            po += __shfl_xor(po, 1); po += __shfl_xor(po, 2);
            pz += __shfl_xor(pz, 1); pz += __shfl_xor(pz, 2);
            if (g == 0)
                att[((size_t)(b * NN + n0 + st + s)) * DIMS + h * HDIM + d] = po / (pz + 1e-6f);
        }
    }
}

extern "C" void kernel_launch(void* const* d_in, const int* in_sizes, int n_in,
                              void* d_out, int out_size, void* d_ws, size_t ws_size,
                              hipStream_t stream) {
    const float* x     = (const float*)d_in[0];
    const float* omega = (const float*)d_in[1];
    const float* Wq    = (const float*)d_in[2];
    const float* Wk    = (const float*)d_in[3];
    const float* Wv    = (const float*)d_in[4];
    const float* Wo    = (const float*)d_in[5];
    const float* bo    = (const float*)d_in[6];
    float* out = (float*)d_out;

    float* ws = (float*)d_ws;
    float* q        = ws;                                   // 2M floats (reused as att)
    float* k        = q + (size_t)BN * DIMS;                // 2M
    float* v        = k + (size_t)BN * DIMS;                // 2M
    float* phiq     = v + (size_t)BN * DIMS;                // 4M
    float* phik     = phiq + (size_t)BB * NHEADS * NN * NFEAT; // 4M (logits then exp'd in place)
    float* kvsum    = phik + (size_t)BB * NHEADS * NN * NFEAT; // 256*8192
    float* ksum     = kvsum + (size_t)256 * NFEAT * HDIM;   // 256*128
    float* blockmax = ksum + 256 * NFEAT;                   // 32768
    float* gmax     = blockmax + (size_t)BB * NHEADS * NN;  // 1

    dim3 gg(BN / TILE, DIMS / TILE);
    gemm_nt<<<gg, 256, 0, stream>>>(x, Wq, q, nullptr, BN, DIMS, DIMS);
    gemm_nt<<<gg, 256, 0, stream>>>(x, Wk, k, nullptr, BN, DIMS, DIMS);
    gemm_nt<<<gg, 256, 0, stream>>>(x, Wv, v, nullptr, BN, DIMS, DIMS);

    const int nrows = BB * NHEADS * NN;  // 32768
    phi_q_kernel<<<nrows, 128, 0, stream>>>(q, omega, phiq);
    phi_k_logits_kernel<<<nrows, 128, 0, stream>>>(k, omega, phik, blockmax);
    reduce_max_kernel<<<1, 256, 0, stream>>>(blockmax, nrows, gmax);
    const int ntot = nrows * NFEAT;
    phik_exp_kernel<<<(ntot + 255) / 256, 256, 0, stream>>>(phik, gmax, ntot);

    scan_partial<<<256, 256, 0, stream>>>(phik, v, kvsum, ksum);
    scan_final<<<256, 256, 0, stream>>>(phiq, phik, v, kvsum, ksum, q /* att reuse */);

    gemm_nt<<<gg, 256, 0, stream>>>(q, Wo, out, bo, BN, DIMS, DIMS);
}

// Round 2
// 449.830 us; speedup vs baseline: 1.4851x; 1.4851x over previous
//
#include <hip/hip_runtime.h>
#include <hip/hip_bf16.h>
#include <math.h>

#define DIMS 1024
#define NHEADS 16
#define HDIM 64
#define NFEAT 128
#define BB 2
#define NN 1024
#define BN (BB*NN)   // 2048

#define SCALE 0.3535533905932738f       // 64^-0.25
#define INV_SQRT_M 0.08838834764831845f // 1/sqrt(128)

// ---------------- GEMM NT: C[i,j] = sum_k A[i,k]*B[j,k] (+bias[j]) ----------------
#define TILE 64
#define KT 16
__global__ __launch_bounds__(256) void gemm_nt(const float* __restrict__ A,
                                               const float* __restrict__ B,
                                               float* __restrict__ C,
                                               const float* __restrict__ bias,
                                               int M, int N, int K) {
    __shared__ float As[KT][TILE + 4];
    __shared__ float Bs[KT][TILE + 4];
    const int tx = threadIdx.x & 15;
    const int ty = threadIdx.x >> 4;
    const int bi = blockIdx.x * TILE;
    const int bj = blockIdx.y * TILE;
    const int lr = threadIdx.x >> 2;          // 0..63 tile row
    const int lc = (threadIdx.x & 3) << 2;    // k sub-offset
    float c[4][4] = {};
    for (int k0 = 0; k0 < K; k0 += KT) {
        float4 a4 = *(const float4*)&A[(size_t)(bi + lr) * K + k0 + lc];
        float4 b4 = *(const float4*)&B[(size_t)(bj + lr) * K + k0 + lc];
        __syncthreads();
        As[lc + 0][lr] = a4.x; As[lc + 1][lr] = a4.y; As[lc + 2][lr] = a4.z; As[lc + 3][lr] = a4.w;
        Bs[lc + 0][lr] = b4.x; Bs[lc + 1][lr] = b4.y; Bs[lc + 2][lr] = b4.z; Bs[lc + 3][lr] = b4.w;
        __syncthreads();
        #pragma unroll
        for (int kk = 0; kk < KT; ++kk) {
            float4 av = *(const float4*)&As[kk][ty << 2];
            float4 bv = *(const float4*)&Bs[kk][tx << 2];
            float a_[4] = {av.x, av.y, av.z, av.w};
            float b_[4] = {bv.x, bv.y, bv.z, bv.w};
            #pragma unroll
            for (int i = 0; i < 4; ++i)
                #pragma unroll
                for (int j = 0; j < 4; ++j)
                    c[i][j] += a_[i] * b_[j];
        }
    }
    #pragma unroll
    for (int i = 0; i < 4; ++i) {
        const int row = bi + (ty << 2) + i;
        #pragma unroll
        for (int j = 0; j < 4; ++j) {
            const int col = bj + (tx << 2) + j;
            float r = c[i][j];
            if (bias) r += bias[col];
            C[(size_t)row * N + col] = r;
        }
    }
}

// ---------------- phi as tiled GEMM with fused epilogue ----------------
// Block: 256 threads; computes 64 (b,n)-rows x 128 features for one head.
// grid = (BN/64, NHEADS). is_query: fused row-max+exp. else: logits + block max.
#define PTILE 64
#define OMS (NFEAT + 4)  // 132, stride stays 16B-aligned (132%4==0)
#define QS  (HDIM + 4)   // 68

__global__ __launch_bounds__(256) void phi_gemm(const float* __restrict__ qk,
                                                const float* __restrict__ omega,
                                                float* __restrict__ outp,
                                                float* __restrict__ blockmax,
                                                int is_query) {
    __shared__ float omT[HDIM][OMS];  // k-major omega
    __shared__ float qT[HDIM][QS];    // k-major q tile (scaled)
    __shared__ float wred[4];
    const int tid = threadIdx.x;
    const int tx = tid & 15, ty = tid >> 4;
    const int h = blockIdx.y;
    const int bn0 = blockIdx.x * PTILE;

    #pragma unroll
    for (int i = 0; i < 8; ++i) {               // 2048 float4 of omega
        const int f = tid + 256 * i;
        const int m = f >> 4;
        const int d0 = (f & 15) << 2;
        float4 o = *(const float4*)&omega[m * HDIM + d0];
        omT[d0 + 0][m] = o.x; omT[d0 + 1][m] = o.y;
        omT[d0 + 2][m] = o.z; omT[d0 + 3][m] = o.w;
    }
    #pragma unroll
    for (int i = 0; i < 4; ++i) {               // 1024 float4 of q tile
        const int f = tid + 256 * i;
        const int r = f >> 4;
        const int d0 = (f & 15) << 2;
        float4 qv = *(const float4*)&qk[(size_t)(bn0 + r) * DIMS + h * HDIM + d0];
        qT[d0 + 0][r] = qv.x * SCALE; qT[d0 + 1][r] = qv.y * SCALE;
        qT[d0 + 2][r] = qv.z * SCALE; qT[d0 + 3][r] = qv.w * SCALE;
    }
    __syncthreads();

    float c[4][8] = {};
    float nrm[4] = {};
    #pragma unroll 4
    for (int kd = 0; kd < HDIM; ++kd) {
        float4 qv = *(const float4*)&qT[kd][ty << 2];
        float4 o1 = *(const float4*)&omT[kd][tx << 3];
        float4 o2 = *(const float4*)&omT[kd][(tx << 3) + 4];
        float a_[4] = {qv.x, qv.y, qv.z, qv.w};
        float b_[8] = {o1.x, o1.y, o1.z, o1.w, o2.x, o2.y, o2.z, o2.w};
        #pragma unroll
        for (int i = 0; i < 4; ++i) {
            nrm[i] += a_[i] * a_[i];
            #pragma unroll
            for (int j = 0; j < 8; ++j) c[i][j] += a_[i] * b_[j];
        }
    }

    // lp = proj - 0.5*|q|^2
    #pragma unroll
    for (int i = 0; i < 4; ++i) {
        const float nh = 0.5f * nrm[i];
        #pragma unroll
        for (int j = 0; j < 8; ++j) c[i][j] -= nh;
    }

    if (is_query) {
        #pragma unroll
        for (int i = 0; i < 4; ++i) {
            float mx = c[i][0];
            #pragma unroll
            for (int j = 1; j < 8; ++j) mx = fmaxf(mx, c[i][j]);
            // row spans 16 consecutive lanes (same ty)
            #pragma unroll
            for (int o = 8; o >= 1; o >>= 1) mx = fmaxf(mx, __shfl_xor(mx, o));
            const int br = bn0 + (ty << 2) + i;
            const int b = br >> 10, n = br & (NN - 1);
            const size_t orow = ((size_t)(b * NHEADS + h) * NN + n) * NFEAT;
            float4 r0, r1;
            r0.x = expf(c[i][0] - mx) * INV_SQRT_M + 1e-4f;
            r0.y = expf(c[i][1] - mx) * INV_SQRT_M + 1e-4f;
            r0.z = expf(c[i][2] - mx) * INV_SQRT_M + 1e-4f;
            r0.w = expf(c[i][3] - mx) * INV_SQRT_M + 1e-4f;
            r1.x = expf(c[i][4] - mx) * INV_SQRT_M + 1e-4f;
            r1.y = expf(c[i][5] - mx) * INV_SQRT_M + 1e-4f;
            r1.z = expf(c[i][6] - mx) * INV_SQRT_M + 1e-4f;
            r1.w = expf(c[i][7] - mx) * INV_SQRT_M + 1e-4f;
            *(float4*)&outp[orow + (tx << 3)] = r0;
            *(float4*)&outp[orow + (tx << 3) + 4] = r1;
        }
    } else {
        float mx = -3.4e38f;
        #pragma unroll
        for (int i = 0; i < 4; ++i) {
            const int br = bn0 + (ty << 2) + i;
            const int b = br >> 10, n = br & (NN - 1);
            const size_t orow = ((size_t)(b * NHEADS + h) * NN + n) * NFEAT;
            float4 r0 = {c[i][0], c[i][1], c[i][2], c[i][3]};
            float4 r1 = {c[i][4], c[i][5], c[i][6], c[i][7]};
            *(float4*)&outp[orow + (tx << 3)] = r0;
            *(float4*)&outp[orow + (tx << 3) + 4] = r1;
            #pragma unroll
            for (int j = 0; j < 8; ++j) mx = fmaxf(mx, c[i][j]);
        }
        #pragma unroll
        for (int o = 32; o >= 1; o >>= 1) mx = fmaxf(mx, __shfl_xor(mx, o));
        if ((tid & 63) == 0) wred[tid >> 6] = mx;
        __syncthreads();
        if (tid == 0)
            blockmax[blockIdx.y * gridDim.x + blockIdx.x] =
                fmaxf(fmaxf(wred[0], wred[1]), fmaxf(wred[2], wred[3]));
    }
}

__global__ __launch_bounds__(256) void reduce_max_kernel(const float* __restrict__ in,
                                                         int n, float* __restrict__ out) {
    float mx = -3.4e38f;
    for (int i = threadIdx.x; i < n; i += 256) mx = fmaxf(mx, in[i]);
    #pragma unroll
    for (int o = 32; o >= 1; o >>= 1) mx = fmaxf(mx, __shfl_xor(mx, o));
    __shared__ float r[4];
    if ((threadIdx.x & 63) == 0) r[threadIdx.x >> 6] = mx;
    __syncthreads();
    if (threadIdx.x == 0) out[0] = fmaxf(fmaxf(r[0], r[1]), fmaxf(r[2], r[3]));
}

__global__ __launch_bounds__(256) void phik_exp4_kernel(float* __restrict__ lk,
                                                        const float* __restrict__ gmax, int n4) {
    const int i = blockIdx.x * 256 + threadIdx.x;
    if (i >= n4) return;
    const float gm = gmax[0];
    float4 v = ((const float4*)lk)[i];
    v.x = expf(v.x - gm) * INV_SQRT_M + 1e-4f;
    v.y = expf(v.y - gm) * INV_SQRT_M + 1e-4f;
    v.z = expf(v.z - gm) * INV_SQRT_M + 1e-4f;
    v.w = expf(v.w - gm) * INV_SQRT_M + 1e-4f;
    ((float4*)lk)[i] = v;
}

// ---------------- causal linear attention, chunked scan ----------------
#define CH 16
#define GS 36

__global__ __launch_bounds__(256) void scan_partial(const float* __restrict__ phik,
                                                    const float* __restrict__ vbuf,
                                                    float* __restrict__ kvsum,
                                                    float* __restrict__ ksum) {
    const int c = blockIdx.x & 7, bh = blockIdx.x >> 3;
    const int b = bh >> 4, h = bh & 15;
    const int tid = threadIdx.x, g = tid & 3, d = tid >> 2;
    __shared__ float lpk[CH][4 * GS];
    __shared__ float lv[CH][HDIM];
    float S[32], Kc[32];
    #pragma unroll
    for (int j = 0; j < 32; ++j) { S[j] = 0.f; Kc[j] = 0.f; }
    const int n0 = c * 128;
    for (int st = 0; st < 128; st += CH) {
        __syncthreads();
        for (int e = tid; e < CH * NFEAT; e += 256) {
            const int s = e >> 7, m = e & 127;
            lpk[s][(m >> 5) * GS + (m & 31)] = phik[((size_t)bh * NN + n0 + st + s) * NFEAT + m];
        }
        for (int e = tid; e < CH * HDIM; e += 256) {
            const int s = e >> 6, dd = e & 63;
            lv[s][dd] = vbuf[((size_t)(b * NN + n0 + st + s)) * DIMS + h * HDIM + dd];
        }
        __syncthreads();
        for (int s = 0; s < CH; ++s) {
            const float vd = lv[s][d];
            #pragma unroll
            for (int j4 = 0; j4 < 8; ++j4) {
                const float4 fk = *(const float4*)&lpk[s][g * GS + (j4 << 2)];
                const int jj = j4 << 2;
                S[jj + 0] += fk.x * vd; Kc[jj + 0] += fk.x;
                S[jj + 1] += fk.y * vd; Kc[jj + 1] += fk.y;
                S[jj + 2] += fk.z * vd; Kc[jj + 2] += fk.z;
                S[jj + 3] += fk.w * vd; Kc[jj + 3] += fk.w;
            }
        }
    }
    const size_t base = (size_t)blockIdx.x * (NFEAT * HDIM);
    #pragma unroll
    for (int j = 0; j < 32; ++j) kvsum[base + (size_t)(g * 32 + j) * HDIM + d] = S[j];
    if (d == 0) {
        #pragma unroll
        for (int j = 0; j < 32; ++j) ksum[blockIdx.x * NFEAT + g * 32 + j] = Kc[j];
    }
}

__global__ __launch_bounds__(256) void scan_final(const float* __restrict__ phiq,
                                                  const float* __restrict__ phik,
                                                  const float* __restrict__ vbuf,
                                                  const float* __restrict__ kvsum,
                                                  const float* __restrict__ ksum,
                                                  float* __restrict__ att) {
    const int c = blockIdx.x & 7, bh = blockIdx.x >> 3;
    const int b = bh >> 4, h = bh & 15;
    const int tid = threadIdx.x, g = tid & 3, d = tid >> 2;
    __shared__ float lpq[CH][4 * GS];
    __shared__ float lpk[CH][4 * GS];
    __shared__ float lv[CH][HDIM];
    float S[32], Kc[32];
    #pragma unroll
    for (int j = 0; j < 32; ++j) { S[j] = 0.f; Kc[j] = 0.f; }
    for (int cp = 0; cp < c; ++cp) {
        const size_t base = ((size_t)bh * 8 + cp) * (NFEAT * HDIM);
        const float* kp = &ksum[(bh * 8 + cp) * NFEAT];
        #pragma unroll
        for (int j = 0; j < 32; ++j) {
            S[j]  += kvsum[base + (size_t)(g * 32 + j) * HDIM + d];
            Kc[j] += kp[g * 32 + j];
        }
    }
    const int n0 = c * 128;
    for (int st = 0; st < 128; st += CH) {
        __syncthreads();
        for (int e = tid; e < CH * NFEAT; e += 256) {
            const int s = e >> 7, m = e & 127;
            const size_t gi = ((size_t)bh * NN + n0 + st + s) * NFEAT + m;
            const int li = (m >> 5) * GS + (m & 31);
            lpq[s][li] = phiq[gi];
            lpk[s][li] = phik[gi];
        }
        for (int e = tid; e < CH * HDIM; e += 256) {
            const int s = e >> 6, dd = e & 63;
            lv[s][dd] = vbuf[((size_t)(b * NN + n0 + st + s)) * DIMS + h * HDIM + dd];
        }
        __syncthreads();
        for (int s = 0; s < CH; ++s) {
            const float vd = lv[s][d];
            float po = 0.f, pz = 0.f;
            #pragma unroll
            for (int j4 = 0; j4 < 8; ++j4) {
                const float4 fk = *(const float4*)&lpk[s][g * GS + (j4 << 2)];
                const float4 fq = *(const float4*)&lpq[s][g * GS + (j4 << 2)];
                const int jj = j4 << 2;
                S[jj + 0] += fk.x * vd; Kc[jj + 0] += fk.x; po += fq.x * S[jj + 0]; pz += fq.x * Kc[jj + 0];
                S[jj + 1] += fk.y * vd; Kc[jj + 1] += fk.y; po += fq.y * S[jj + 1]; pz += fq.y * Kc[jj + 1];
                S[jj + 2] += fk.z * vd; Kc[jj + 2] += fk.z; po += fq.z * S[jj + 2]; pz += fq.z * Kc[jj + 2];
                S[jj + 3] += fk.w * vd; Kc[jj + 3] += fk.w; po += fq.w * S[jj + 3]; pz += fq.w * Kc[jj + 3];
            }
            po += __shfl_xor(po, 1); po += __shfl_xor(po, 2);
            pz += __shfl_xor(pz, 1); pz += __shfl_xor(pz, 2);
            if (g == 0)
                att[((size_t)(b * NN + n0 + st + s)) * DIMS + h * HDIM + d] = po / (pz + 1e-6f);
        }
    }
}

extern "C" void kernel_launch(void* const* d_in, const int* in_sizes, int n_in,
                              void* d_out, int out_size, void* d_ws, size_t ws_size,
                              hipStream_t stream) {
    const float* x     = (const float*)d_in[0];
    const float* omega = (const float*)d_in[1];
    const float* Wq    = (const float*)d_in[2];
    const float* Wk    = (const float*)d_in[3];
    const float* Wv    = (const float*)d_in[4];
    const float* Wo    = (const float*)d_in[5];
    const float* bo    = (const float*)d_in[6];
    float* out = (float*)d_out;

    float* ws = (float*)d_ws;
    float* q        = ws;                                   // 2M floats (reused as att)
    float* k        = q + (size_t)BN * DIMS;                // 2M
    float* v        = k + (size_t)BN * DIMS;                // 2M
    float* phiq     = v + (size_t)BN * DIMS;                // 4M
    float* phik     = phiq + (size_t)BB * NHEADS * NN * NFEAT; // 4M (logits then exp'd in place)
    float* kvsum    = phik + (size_t)BB * NHEADS * NN * NFEAT; // 256*8192
    float* ksum     = kvsum + (size_t)256 * NFEAT * HDIM;   // 256*128
    float* blockmax = ksum + 256 * NFEAT;                   // 512
    float* gmax     = blockmax + 512;                       // 1

    dim3 gg(BN / TILE, DIMS / TILE);
    gemm_nt<<<gg, 256, 0, stream>>>(x, Wq, q, nullptr, BN, DIMS, DIMS);
    gemm_nt<<<gg, 256, 0, stream>>>(x, Wk, k, nullptr, BN, DIMS, DIMS);
    gemm_nt<<<gg, 256, 0, stream>>>(x, Wv, v, nullptr, BN, DIMS, DIMS);

    dim3 pg(BN / PTILE, NHEADS);   // (32, 16)
    phi_gemm<<<pg, 256, 0, stream>>>(q, omega, phiq, nullptr, 1);
    phi_gemm<<<pg, 256, 0, stream>>>(k, omega, phik, blockmax, 0);
    reduce_max_kernel<<<1, 256, 0, stream>>>(blockmax, 512, gmax);
    const int n4 = BB * NHEADS * NN * NFEAT / 4;  // 1,048,576
    phik_exp4_kernel<<<(n4 + 255) / 256, 256, 0, stream>>>(phik, gmax, n4);

    scan_partial<<<256, 256, 0, stream>>>(phik, v, kvsum, ksum);
    scan_final<<<256, 256, 0, stream>>>(phiq, phik, v, kvsum, ksum, q /* att reuse */);

    gemm_nt<<<gg, 256, 0, stream>>>(q, Wo, out, bo, BN, DIMS, DIMS);
}

// Round 4
// 351.549 us; speedup vs baseline: 1.9002x; 1.2796x over previous
//
#include <hip/hip_runtime.h>
#include <hip/hip_bf16.h>
#include <math.h>

#define DIMS 1024
#define NHEADS 16
#define HDIM 64
#define NFEAT 128
#define BB 2
#define NN 1024
#define BN (BB*NN)   // 2048
#define NCH 16       // chunks per (b,h)
#define CSZ 64       // chunk size

#define SCALE 0.3535533905932738f       // 64^-0.25
#define INV_SQRT_M 0.08838834764831845f // 1/sqrt(128)

typedef __attribute__((ext_vector_type(8))) short s8v;   // 8 bf16 (4 VGPRs)
typedef __attribute__((ext_vector_type(4))) float f4v;   // mfma accumulator

__device__ __forceinline__ ushort f2b(float x) {
    __hip_bfloat16 h = __float2bfloat16(x);
    return *(ushort*)&h;
}
__device__ __forceinline__ float b2f(ushort u) {
    __hip_bfloat16 h = *(__hip_bfloat16*)&u;
    return __bfloat162float(h);
}

// ---------------- GEMM NT (f32): C[i,j] = sum_k A[i,k]*B[j,k] (+bias[j]) ----------------
#define TILE 64
#define KT 16
__global__ __launch_bounds__(256) void gemm_nt(const float* __restrict__ A,
                                               const float* __restrict__ B,
                                               float* __restrict__ C,
                                               const float* __restrict__ bias,
                                               int M, int N, int K) {
    __shared__ float As[KT][TILE + 4];
    __shared__ float Bs[KT][TILE + 4];
    const int tx = threadIdx.x & 15;
    const int ty = threadIdx.x >> 4;
    const int bi = blockIdx.x * TILE;
    const int bj = blockIdx.y * TILE;
    const int lr = threadIdx.x >> 2;
    const int lc = (threadIdx.x & 3) << 2;
    float c[4][4] = {};
    for (int k0 = 0; k0 < K; k0 += KT) {
        float4 a4 = *(const float4*)&A[(size_t)(bi + lr) * K + k0 + lc];
        float4 b4 = *(const float4*)&B[(size_t)(bj + lr) * K + k0 + lc];
        __syncthreads();
        As[lc + 0][lr] = a4.x; As[lc + 1][lr] = a4.y; As[lc + 2][lr] = a4.z; As[lc + 3][lr] = a4.w;
        Bs[lc + 0][lr] = b4.x; Bs[lc + 1][lr] = b4.y; Bs[lc + 2][lr] = b4.z; Bs[lc + 3][lr] = b4.w;
        __syncthreads();
        #pragma unroll
        for (int kk = 0; kk < KT; ++kk) {
            float4 av = *(const float4*)&As[kk][ty << 2];
            float4 bv = *(const float4*)&Bs[kk][tx << 2];
            float a_[4] = {av.x, av.y, av.z, av.w};
            float b_[4] = {bv.x, bv.y, bv.z, bv.w};
            #pragma unroll
            for (int i = 0; i < 4; ++i)
                #pragma unroll
                for (int j = 0; j < 4; ++j)
                    c[i][j] += a_[i] * b_[j];
        }
    }
    #pragma unroll
    for (int i = 0; i < 4; ++i) {
        const int row = bi + (ty << 2) + i;
        #pragma unroll
        for (int j = 0; j < 4; ++j) {
            const int col = bj + (tx << 2) + j;
            float r = c[i][j];
            if (bias) r += bias[col];
            C[(size_t)row * N + col] = r;
        }
    }
}

// ---------------- phi as tiled GEMM with fused epilogue ----------------
#define PTILE 64
#define OMS (NFEAT + 4)
#define QS  (HDIM + 4)

__global__ __launch_bounds__(256) void phi_gemm(const float* __restrict__ qk,
                                                const float* __restrict__ omega,
                                                ushort* __restrict__ out_b16,   // query path
                                                float* __restrict__ out_f32,   // key path (logits)
                                                float* __restrict__ blockmax,
                                                int is_query) {
    __shared__ float omT[HDIM][OMS];
    __shared__ float qT[HDIM][QS];
    __shared__ float wred[4];
    const int tid = threadIdx.x;
    const int tx = tid & 15, ty = tid >> 4;
    const int h = blockIdx.y;
    const int bn0 = blockIdx.x * PTILE;

    #pragma unroll
    for (int i = 0; i < 8; ++i) {
        const int f = tid + 256 * i;
        const int m = f >> 4;
        const int d0 = (f & 15) << 2;
        float4 o = *(const float4*)&omega[m * HDIM + d0];
        omT[d0 + 0][m] = o.x; omT[d0 + 1][m] = o.y;
        omT[d0 + 2][m] = o.z; omT[d0 + 3][m] = o.w;
    }
    #pragma unroll
    for (int i = 0; i < 4; ++i) {
        const int f = tid + 256 * i;
        const int r = f >> 4;
        const int d0 = (f & 15) << 2;
        float4 qv = *(const float4*)&qk[(size_t)(bn0 + r) * DIMS + h * HDIM + d0];
        qT[d0 + 0][r] = qv.x * SCALE; qT[d0 + 1][r] = qv.y * SCALE;
        qT[d0 + 2][r] = qv.z * SCALE; qT[d0 + 3][r] = qv.w * SCALE;
    }
    __syncthreads();

    float c[4][8] = {};
    float nrm[4] = {};
    #pragma unroll 4
    for (int kd = 0; kd < HDIM; ++kd) {
        float4 qv = *(const float4*)&qT[kd][ty << 2];
        float4 o1 = *(const float4*)&omT[kd][tx << 3];
        float4 o2 = *(const float4*)&omT[kd][(tx << 3) + 4];
        float a_[4] = {qv.x, qv.y, qv.z, qv.w};
        float b_[8] = {o1.x, o1.y, o1.z, o1.w, o2.x, o2.y, o2.z, o2.w};
        #pragma unroll
        for (int i = 0; i < 4; ++i) {
            nrm[i] += a_[i] * a_[i];
            #pragma unroll
            for (int j = 0; j < 8; ++j) c[i][j] += a_[i] * b_[j];
        }
    }
    #pragma unroll
    for (int i = 0; i < 4; ++i) {
        const float nh = 0.5f * nrm[i];
        #pragma unroll
        for (int j = 0; j < 8; ++j) c[i][j] -= nh;
    }

    if (is_query) {
        #pragma unroll
        for (int i = 0; i < 4; ++i) {
            float mx = c[i][0];
            #pragma unroll
            for (int j = 1; j < 8; ++j) mx = fmaxf(mx, c[i][j]);
            #pragma unroll
            for (int o = 8; o >= 1; o >>= 1) mx = fmaxf(mx, __shfl_xor(mx, o));
            const int br = bn0 + (ty << 2) + i;
            const int b = br >> 10, n = br & (NN - 1);
            const size_t orow = ((size_t)(b * NHEADS + h) * NN + n) * NFEAT;
            ushort pk[8];
            #pragma unroll
            for (int j = 0; j < 8; ++j)
                pk[j] = f2b(expf(c[i][j] - mx) * INV_SQRT_M + 1e-4f);
            *(s8v*)&out_b16[orow + (tx << 3)] = *(s8v*)&pk[0];
        }
    } else {
        float mx = -3.4e38f;
        #pragma unroll
        for (int i = 0; i < 4; ++i) {
            const int br = bn0 + (ty << 2) + i;
            const int b = br >> 10, n = br & (NN - 1);
            const size_t orow = ((size_t)(b * NHEADS + h) * NN + n) * NFEAT;
            float4 r0 = {c[i][0], c[i][1], c[i][2], c[i][3]};
            float4 r1 = {c[i][4], c[i][5], c[i][6], c[i][7]};
            *(float4*)&out_f32[orow + (tx << 3)] = r0;
            *(float4*)&out_f32[orow + (tx << 3) + 4] = r1;
            #pragma unroll
            for (int j = 0; j < 8; ++j) mx = fmaxf(mx, c[i][j]);
        }
        #pragma unroll
        for (int o = 32; o >= 1; o >>= 1) mx = fmaxf(mx, __shfl_xor(mx, o));
        if ((tid & 63) == 0) wred[tid >> 6] = mx;
        __syncthreads();
        if (tid == 0)
            blockmax[blockIdx.y * gridDim.x + blockIdx.x] =
                fmaxf(fmaxf(wred[0], wred[1]), fmaxf(wred[2], wred[3]));
    }
}

__global__ __launch_bounds__(256) void reduce_max_kernel(const float* __restrict__ in,
                                                         int n, float* __restrict__ out) {
    float mx = -3.4e38f;
    for (int i = threadIdx.x; i < n; i += 256) mx = fmaxf(mx, in[i]);
    #pragma unroll
    for (int o = 32; o >= 1; o >>= 1) mx = fmaxf(mx, __shfl_xor(mx, o));
    __shared__ float r[4];
    if ((threadIdx.x & 63) == 0) r[threadIdx.x >> 6] = mx;
    __syncthreads();
    if (threadIdx.x == 0) out[0] = fmaxf(fmaxf(r[0], r[1]), fmaxf(r[2], r[3]));
}

// ---------------- phik: exp + write row-major bf16 AND transposed bf16 ----------------
__global__ __launch_bounds__(256) void phik_exp_t(const float* __restrict__ logits,
                                                  const float* __restrict__ gmax,
                                                  ushort* __restrict__ phik,
                                                  ushort* __restrict__ phikT) {
    const int bh = blockIdx.y, n0 = blockIdx.x * CSZ;
    const int tid = threadIdx.x;
    __shared__ __attribute__((aligned(16))) ushort lt[64][136];
    const float gm = gmax[0];
    const int r = tid >> 2, c0 = (tid & 3) * 32;
    const size_t gbase = ((size_t)bh * NN + n0 + r) * NFEAT + c0;
    ushort tmp[32];
    #pragma unroll
    for (int i = 0; i < 8; ++i) {
        float4 v = *(const float4*)&logits[gbase + i * 4];
        tmp[i * 4 + 0] = f2b(expf(v.x - gm) * INV_SQRT_M + 1e-4f);
        tmp[i * 4 + 1] = f2b(expf(v.y - gm) * INV_SQRT_M + 1e-4f);
        tmp[i * 4 + 2] = f2b(expf(v.z - gm) * INV_SQRT_M + 1e-4f);
        tmp[i * 4 + 3] = f2b(expf(v.w - gm) * INV_SQRT_M + 1e-4f);
    }
    #pragma unroll
    for (int i = 0; i < 4; ++i) {
        *(s8v*)&phik[gbase + i * 8] = *(s8v*)&tmp[i * 8];
        *(s8v*)&lt[r][c0 + i * 8] = *(s8v*)&tmp[i * 8];
    }
    __syncthreads();
    const int m = tid >> 1, nh = (tid & 1) * 32;
    ushort tp[32];
    #pragma unroll
    for (int i = 0; i < 32; ++i) tp[i] = lt[nh + i][m];
    const size_t tbase = ((size_t)bh * NFEAT + m) * NN + n0 + nh;
    #pragma unroll
    for (int i = 0; i < 4; ++i) *(s8v*)&phikT[tbase + i * 8] = *(s8v*)&tp[i * 8];
}

// ---------------- V transpose+cast: Vt[bh][d][n] bf16 ----------------
__global__ __launch_bounds__(256) void vt_cast(const float* __restrict__ v,
                                               ushort* __restrict__ vt) {
    const int bh = blockIdx.y, n0 = blockIdx.x * CSZ;
    const int b = bh >> 4, h = bh & 15;
    __shared__ float lv[64][65];
    const int tid = threadIdx.x;
    const int r = tid >> 2, c0 = (tid & 3) * 16;
    #pragma unroll
    for (int i = 0; i < 4; ++i) {
        float4 q = *(const float4*)&v[((size_t)(b * NN + n0 + r)) * DIMS + h * HDIM + c0 + i * 4];
        lv[r][c0 + i * 4 + 0] = q.x; lv[r][c0 + i * 4 + 1] = q.y;
        lv[r][c0 + i * 4 + 2] = q.z; lv[r][c0 + i * 4 + 3] = q.w;
    }
    __syncthreads();
    const int d = tid >> 2, s0 = (tid & 3) * 16;
    ushort tp[16];
    #pragma unroll
    for (int i = 0; i < 16; ++i) tp[i] = f2b(lv[s0 + i][d]);
    const size_t tb = ((size_t)bh * HDIM + d) * NN + n0 + s0;
    *(s8v*)&vt[tb] = *(s8v*)&tp[0];
    *(s8v*)&vt[tb + 8] = *(s8v*)&tp[8];
}

// ---------------- per-chunk sums: SsumT[bh][c][d][m] = sum_n V[n,d]*phik[n,m] ----------------
__global__ __launch_bounds__(256) void chunk_sums(const ushort* __restrict__ phikT,
                                                  const ushort* __restrict__ vt,
                                                  float* __restrict__ ssum,
                                                  float* __restrict__ kcsum) {
    const int c = blockIdx.x, bh = blockIdx.y, n0 = c * CSZ;
    __shared__ __attribute__((aligned(16))) ushort lvt[64][72];
    __shared__ __attribute__((aligned(16))) ushort lkt[128][72];
    const int tid = threadIdx.x;
    {
        const int d = tid >> 2, s = (tid & 3) * 16;
        const size_t g = ((size_t)bh * HDIM + d) * NN + n0 + s;
        *(s8v*)&lvt[d][s]     = *(const s8v*)&vt[g];
        *(s8v*)&lvt[d][s + 8] = *(const s8v*)&vt[g + 8];
    }
    {
        const int m = tid >> 1, s = (tid & 1) * 32;
        const size_t g = ((size_t)bh * NFEAT + m) * NN + n0 + s;
        #pragma unroll
        for (int i = 0; i < 4; ++i) *(s8v*)&lkt[m][s + i * 8] = *(const s8v*)&phikT[g + i * 8];
    }
    __syncthreads();
    const int w = tid >> 6, l = tid & 63, lr = l & 15, lg = l >> 4;
    f4v acc[8] = {};
    #pragma unroll
    for (int k0 = 0; k0 < 64; k0 += 32) {
        s8v a = *(s8v*)&lvt[w * 16 + lr][k0 + lg * 8];
        #pragma unroll
        for (int ct = 0; ct < 8; ++ct) {
            s8v bf = *(s8v*)&lkt[ct * 16 + lr][k0 + lg * 8];
            acc[ct] = __builtin_amdgcn_mfma_f32_16x16x32_bf16(a, bf, acc[ct], 0, 0, 0);
        }
    }
    const size_t obase = ((size_t)bh * NCH + c) * (HDIM * NFEAT);
    #pragma unroll
    for (int ct = 0; ct < 8; ++ct)
        #pragma unroll
        for (int rg = 0; rg < 4; ++rg) {
            const int d = w * 16 + lg * 4 + rg, m = ct * 16 + lr;
            ssum[obase + (size_t)d * NFEAT + m] = acc[ct][rg];
        }
    if (tid < 128) {
        float s = 0.f;
        #pragma unroll 8
        for (int i = 0; i < 64; ++i) s += b2f(lkt[tid][i]);
        kcsum[((size_t)bh * NCH + c) * NFEAT + tid] = s;
    }
}

// ---------------- prefix over chunks ----------------
__global__ void kc_prefix(const float* __restrict__ kcsum, float* __restrict__ kcpre) {
    const int bh = blockIdx.x, m = threadIdx.x;
    float a = 0.f;
    for (int c = 0; c < NCH; ++c) {
        kcpre[((size_t)bh * NCH + c) * NFEAT + m] = a;
        a += kcsum[((size_t)bh * NCH + c) * NFEAT + m];
    }
}

__global__ __launch_bounds__(256) void chunk_prefix(const float* __restrict__ ssum,
                                                    ushort* __restrict__ spre) {
    const int bh = blockIdx.y, sl = blockIdx.x;
    const int base_e = sl * 2048 + threadIdx.x;
    float acc[8] = {};
    const size_t bb = (size_t)bh * NCH * (HDIM * NFEAT);
    for (int c = 0; c < NCH; ++c) {
        const size_t cb = bb + (size_t)c * (HDIM * NFEAT);
        #pragma unroll
        for (int e = 0; e < 8; ++e) {
            spre[cb + base_e + e * 256] = f2b(acc[e]);
            acc[e] += ssum[cb + base_e + e * 256];
        }
    }
}

// ---------------- chunked causal attention via MFMA ----------------
__global__ __launch_bounds__(256) void scan_final(const ushort* __restrict__ phiq,
                                                  const ushort* __restrict__ phik,
                                                  const ushort* __restrict__ vt,
                                                  const ushort* __restrict__ spre,
                                                  const float* __restrict__ kcpre,
                                                  float* __restrict__ att) {
    const int c = blockIdx.x, bh = blockIdx.y;
    const int b = bh >> 4, h = bh & 15;
    const int n0 = c * CSZ;
    __shared__ __attribute__((aligned(16))) ushort lq[64][136];
    __shared__ __attribute__((aligned(16))) ushort lk[64][136];
    __shared__ __attribute__((aligned(16))) ushort lvt[64][72];
    __shared__ __attribute__((aligned(16))) ushort lsp[64][136];
    __shared__ __attribute__((aligned(16))) ushort lA[64][72];
    __shared__ float kc[NFEAT];
    __shared__ float zin[64];
    __shared__ float zp[4][64];
    const int tid = threadIdx.x;

    const size_t qb = ((size_t)bh * NN + n0) * NFEAT;
    #pragma unroll
    for (int i = 0; i < 4; ++i) {
        const int idx = tid + 256 * i;
        const int r = idx >> 4, cs = (idx & 15) * 8;
        *(s8v*)&lq[r][cs] = *(const s8v*)&phiq[qb + (size_t)r * NFEAT + cs];
        *(s8v*)&lk[r][cs] = *(const s8v*)&phik[qb + (size_t)r * NFEAT + cs];
    }
    const size_t sb = ((size_t)bh * NCH + c) * (HDIM * NFEAT);
    #pragma unroll
    for (int i = 0; i < 4; ++i) {
        const int idx = tid + 256 * i;
        const int r = idx >> 4, cs = (idx & 15) * 8;
        *(s8v*)&lsp[r][cs] = *(const s8v*)&spre[sb + (size_t)r * NFEAT + cs];
    }
    {
        const int d = tid >> 2, s = (tid & 3) * 16;
        const size_t g = ((size_t)bh * HDIM + d) * NN + n0 + s;
        *(s8v*)&lvt[d][s]     = *(const s8v*)&vt[g];
        *(s8v*)&lvt[d][s + 8] = *(const s8v*)&vt[g + 8];
    }
    if (tid < NFEAT) kc[tid] = kcpre[((size_t)bh * NCH + c) * NFEAT + tid];
    __syncthreads();

    const int w = tid >> 6, l = tid & 63, lr = l & 15, lg = l >> 4;

    // Phase 1: A = phiq @ phik^T
    f4v a4[4] = {};
    #pragma unroll
    for (int k0 = 0; k0 < 128; k0 += 32) {
        s8v av = *(s8v*)&lq[w * 16 + lr][k0 + lg * 8];
        #pragma unroll
        for (int ct = 0; ct < 4; ++ct) {
            s8v bv = *(s8v*)&lk[ct * 16 + lr][k0 + lg * 8];
            a4[ct] = __builtin_amdgcn_mfma_f32_16x16x32_bf16(av, bv, a4[ct], 0, 0, 0);
        }
    }
    float zi[4] = {0.f, 0.f, 0.f, 0.f};
    #pragma unroll
    for (int ct = 0; ct < 4; ++ct) {
        #pragma unroll
        for (int rg = 0; rg < 4; ++rg) {
            const int row = w * 16 + lg * 4 + rg;
            const int col = ct * 16 + lr;
            const float val = (col <= row) ? a4[ct][rg] : 0.f;
            zi[rg] += val;
            lA[row][col] = f2b(val);
        }
    }
    #pragma unroll
    for (int rg = 0; rg < 4; ++rg) {
        float z = zi[rg];
        z += __shfl_xor(z, 1); z += __shfl_xor(z, 2);
        z += __shfl_xor(z, 4); z += __shfl_xor(z, 8);
        if (lr == 0) zin[w * 16 + lg * 4 + rg] = z;
    }
    {
        const int row = tid & 63, qq = tid >> 6;
        float s = 0.f;
        #pragma unroll 8
        for (int m = 0; m < 32; ++m) s += b2f(lq[row][qq * 32 + m]) * kc[qq * 32 + m];
        zp[qq][row] = s;
    }
    __syncthreads();

    // Phase 2: out = Amask @ V + phiq @ Spre
    f4v o4[4] = {};
    #pragma unroll
    for (int k0 = 0; k0 < 64; k0 += 32) {
        s8v av = *(s8v*)&lA[w * 16 + lr][k0 + lg * 8];
        #pragma unroll
        for (int ct = 0; ct < 4; ++ct) {
            s8v bv = *(s8v*)&lvt[ct * 16 + lr][k0 + lg * 8];
            o4[ct] = __builtin_amdgcn_mfma_f32_16x16x32_bf16(av, bv, o4[ct], 0, 0, 0);
        }
    }
    #pragma unroll
    for (int k0 = 0; k0 < 128; k0 += 32) {
        s8v av = *(s8v*)&lq[w * 16 + lr][k0 + lg * 8];
        #pragma unroll
        for (int ct = 0; ct < 4; ++ct) {
            s8v bv = *(s8v*)&lsp[ct * 16 + lr][k0 + lg * 8];
            o4[ct] = __builtin_amdgcn_mfma_f32_16x16x32_bf16(av, bv, o4[ct], 0, 0, 0);
        }
    }
    #pragma unroll
    for (int rg = 0; rg < 4; ++rg) {
        const int row = w * 16 + lg * 4 + rg;
        const float z = zin[row] + zp[0][row] + zp[1][row] + zp[2][row] + zp[3][row] + 1e-6f;
        const float rz = 1.f / z;
        #pragma unroll
        for (int ct = 0; ct < 4; ++ct) {
            const int d = ct * 16 + lr;
            att[((size_t)(b * NN + n0 + row)) * DIMS + h * HDIM + d] = o4[ct][rg] * rz;
        }
    }
}

extern "C" void kernel_launch(void* const* d_in, const int* in_sizes, int n_in,
                              void* d_out, int out_size, void* d_ws, size_t ws_size,
                              hipStream_t stream) {
    const float* x     = (const float*)d_in[0];
    const float* omega = (const float*)d_in[1];
    const float* Wq    = (const float*)d_in[2];
    const float* Wk    = (const float*)d_in[3];
    const float* Wv    = (const float*)d_in[4];
    const float* Wo    = (const float*)d_in[5];
    const float* bo    = (const float*)d_in[6];
    float* out = (float*)d_out;

    float* ws = (float*)d_ws;
    const size_t PROJ = (size_t)BN * DIMS;                 // 2M floats
    const size_t PHI  = (size_t)BB * NHEADS * NN * NFEAT;  // 4M elements
    float* q      = ws;                  // f32; reused as att output of scan_final
    float* k      = q + PROJ;            // f32; reused as phikT (bf16, 4M ushort = 8MB exact)
    float* v      = k + PROJ;            // f32; reused as spre (bf16, 4M ushort = 8MB exact)
    float* logits = v + PROJ;            // 4M f32; reused as ssum
    ushort* phiq_b  = (ushort*)(logits + PHI);
    ushort* phik_b  = phiq_b + PHI;
    ushort* vt_b    = phik_b + PHI;                        // 2M ushorts (= PROJ elements)
    float* kcsum    = (float*)(vt_b + PROJ);               // FIXED: advance full vt size
    float* kcpre    = kcsum + 32 * NCH * NFEAT;
    float* blockmax = kcpre + 32 * NCH * NFEAT;
    float* gmax     = blockmax + 512;
    ushort* phikT_b = (ushort*)k;        // k is dead after phi_gemm key pass
    ushort* spre_b  = (ushort*)v;        // v is dead after vt_cast
    float* ssum     = logits;            // logits dead after phik_exp_t

    dim3 gg(BN / TILE, DIMS / TILE);
    gemm_nt<<<gg, 256, 0, stream>>>(x, Wq, q, nullptr, BN, DIMS, DIMS);
    gemm_nt<<<gg, 256, 0, stream>>>(x, Wk, k, nullptr, BN, DIMS, DIMS);
    gemm_nt<<<gg, 256, 0, stream>>>(x, Wv, v, nullptr, BN, DIMS, DIMS);

    dim3 pg(BN / PTILE, NHEADS);
    phi_gemm<<<pg, 256, 0, stream>>>(q, omega, phiq_b, nullptr, nullptr, 1);
    phi_gemm<<<pg, 256, 0, stream>>>(k, omega, nullptr, logits, blockmax, 0);
    reduce_max_kernel<<<1, 256, 0, stream>>>(blockmax, 512, gmax);

    dim3 cg(NCH, BB * NHEADS);
    phik_exp_t<<<cg, 256, 0, stream>>>(logits, gmax, phik_b, phikT_b);
    vt_cast<<<cg, 256, 0, stream>>>(v, vt_b);
    chunk_sums<<<cg, 256, 0, stream>>>(phikT_b, vt_b, ssum, kcsum);
    kc_prefix<<<BB * NHEADS, NFEAT, 0, stream>>>(kcsum, kcpre);
    chunk_prefix<<<dim3(4, BB * NHEADS), 256, 0, stream>>>(ssum, spre_b);
    scan_final<<<cg, 256, 0, stream>>>(phiq_b, phik_b, vt_b, spre_b, kcpre, q /* att */);

    gemm_nt<<<gg, 256, 0, stream>>>(q, Wo, out, bo, BN, DIMS, DIMS);
}

// Round 5
// 200.203 us; speedup vs baseline: 3.3367x; 1.7560x over previous
//
#include <hip/hip_runtime.h>
#include <hip/hip_bf16.h>
#include <math.h>

#define DIMS 1024
#define NHEADS 16
#define HDIM 64
#define NFEAT 128
#define BB 2
#define NN 1024
#define BN (BB*NN)   // 2048
#define NCH 16       // chunks per (b,h)
#define CSZ 64       // chunk size
#define WW (DIMS*DIMS)

#define SCALE 0.3535533905932738f       // 64^-0.25
#define INV_SQRT_M 0.08838834764831845f // 1/sqrt(128)

typedef __attribute__((ext_vector_type(8))) short s8v;   // 8 bf16 (4 VGPRs)
typedef __attribute__((ext_vector_type(4))) float f4v;   // mfma accumulator

__device__ __forceinline__ ushort f2b(float x) {
    __hip_bfloat16 h = __float2bfloat16(x);
    return *(ushort*)&h;
}
__device__ __forceinline__ float b2f(ushort u) {
    __hip_bfloat16 h = *(__hip_bfloat16*)&u;
    return __bfloat162float(h);
}

// ---------------- split-cast: hi = bf16(x), lo = bf16(x - hi) ----------------
__global__ __launch_bounds__(256) void cast_split(const float* __restrict__ src,
                                                  ushort* __restrict__ hi,
                                                  ushort* __restrict__ lo, int n8) {
    const int i = blockIdx.x * 256 + threadIdx.x;
    if (i >= n8) return;
    float4 a = ((const float4*)src)[2 * i];
    float4 b = ((const float4*)src)[2 * i + 1];
    float v[8] = {a.x, a.y, a.z, a.w, b.x, b.y, b.z, b.w};
    ushort h8[8];
    #pragma unroll
    for (int j = 0; j < 8; ++j) h8[j] = f2b(v[j]);
    *(s8v*)&hi[(size_t)i * 8] = *(s8v*)&h8[0];
    if (lo) {
        ushort l8[8];
        #pragma unroll
        for (int j = 0; j < 8; ++j) l8[j] = f2b(v[j] - b2f(h8[j]));
        *(s8v*)&lo[(size_t)i * 8] = *(s8v*)&l8[0];
    }
}

// ---------------- MFMA GEMM NT: C[i,j] = sum_k A[i,k]*B[j,k] (+bias[j]) ----------------
// A: [M x K] bf16 (hi[,lo]) row-major; B: [N x K] bf16 (hi[,lo]) row-major.
// SPLIT: C += Ahi*Bhi + Ahi*Blo + Alo*Bhi  (~f32 accuracy). Tile 64x128, BK=32.
template<bool SPLIT>
__global__ __launch_bounds__(256) void gemm_nt_mfma(const ushort* __restrict__ Ahi,
                                                    const ushort* __restrict__ Alo,
                                                    const ushort* __restrict__ Bhi,
                                                    const ushort* __restrict__ Blo,
                                                    float* __restrict__ C,
                                                    const float* __restrict__ bias,
                                                    int M, int N, int K) {
    __shared__ __attribute__((aligned(16))) ushort lA[64][40];
    __shared__ __attribute__((aligned(16))) ushort lB[128][40];
    __shared__ __attribute__((aligned(16))) ushort lAl[64][40];
    __shared__ __attribute__((aligned(16))) ushort lBl[128][40];
    const int tid = threadIdx.x;
    const int w = tid >> 6, l = tid & 63, lr = l & 15, lg = l >> 4;
    const int woffm = (w >> 1) * 32, woffn = (w & 1) * 64;
    const int bi = blockIdx.x * 64, bj = blockIdx.y * 128;
    const int arow = tid >> 2, acol = (tid & 3) * 8;
    const int brow = tid >> 1, bcol = (tid & 1) * 16;

    f4v acc[2][4] = {};
    for (int k0 = 0; k0 < K; k0 += 32) {
        __syncthreads();
        *(s8v*)&lA[arow][acol] = *(const s8v*)&Ahi[(size_t)(bi + arow) * K + k0 + acol];
        *(s8v*)&lB[brow][bcol]     = *(const s8v*)&Bhi[(size_t)(bj + brow) * K + k0 + bcol];
        *(s8v*)&lB[brow][bcol + 8] = *(const s8v*)&Bhi[(size_t)(bj + brow) * K + k0 + bcol + 8];
        if constexpr (SPLIT) {
            *(s8v*)&lAl[arow][acol] = *(const s8v*)&Alo[(size_t)(bi + arow) * K + k0 + acol];
            *(s8v*)&lBl[brow][bcol]     = *(const s8v*)&Blo[(size_t)(bj + brow) * K + k0 + bcol];
            *(s8v*)&lBl[brow][bcol + 8] = *(const s8v*)&Blo[(size_t)(bj + brow) * K + k0 + bcol + 8];
        }
        __syncthreads();
        s8v a0 = *(s8v*)&lA[woffm + lr][lg * 8];
        s8v a1 = *(s8v*)&lA[woffm + 16 + lr][lg * 8];
        s8v b_[4];
        #pragma unroll
        for (int nf = 0; nf < 4; ++nf) b_[nf] = *(s8v*)&lB[woffn + nf * 16 + lr][lg * 8];
        #pragma unroll
        for (int nf = 0; nf < 4; ++nf) {
            acc[0][nf] = __builtin_amdgcn_mfma_f32_16x16x32_bf16(a0, b_[nf], acc[0][nf], 0, 0, 0);
            acc[1][nf] = __builtin_amdgcn_mfma_f32_16x16x32_bf16(a1, b_[nf], acc[1][nf], 0, 0, 0);
        }
        if constexpr (SPLIT) {
            s8v al0 = *(s8v*)&lAl[woffm + lr][lg * 8];
            s8v al1 = *(s8v*)&lAl[woffm + 16 + lr][lg * 8];
            s8v bl_[4];
            #pragma unroll
            for (int nf = 0; nf < 4; ++nf) bl_[nf] = *(s8v*)&lBl[woffn + nf * 16 + lr][lg * 8];
            #pragma unroll
            for (int nf = 0; nf < 4; ++nf) {
                acc[0][nf] = __builtin_amdgcn_mfma_f32_16x16x32_bf16(a0, bl_[nf], acc[0][nf], 0, 0, 0);
                acc[1][nf] = __builtin_amdgcn_mfma_f32_16x16x32_bf16(a1, bl_[nf], acc[1][nf], 0, 0, 0);
                acc[0][nf] = __builtin_amdgcn_mfma_f32_16x16x32_bf16(al0, b_[nf], acc[0][nf], 0, 0, 0);
                acc[1][nf] = __builtin_amdgcn_mfma_f32_16x16x32_bf16(al1, b_[nf], acc[1][nf], 0, 0, 0);
            }
        }
    }
    #pragma unroll
    for (int mf = 0; mf < 2; ++mf)
        #pragma unroll
        for (int nf = 0; nf < 4; ++nf)
            #pragma unroll
            for (int rg = 0; rg < 4; ++rg) {
                const int row = bi + woffm + mf * 16 + lg * 4 + rg;
                const int col = bj + woffn + nf * 16 + lr;
                float r = acc[mf][nf][rg];
                if (bias) r += bias[col];
                C[(size_t)row * N + col] = r;
            }
}

// ---------------- phi as tiled GEMM with fused epilogue ----------------
#define PTILE 64
#define OMS (NFEAT + 4)
#define QS  (HDIM + 4)

__global__ __launch_bounds__(256) void phi_gemm(const float* __restrict__ qk,
                                                const float* __restrict__ omega,
                                                ushort* __restrict__ out_b16,
                                                float* __restrict__ out_f32,
                                                float* __restrict__ blockmax,
                                                int is_query) {
    __shared__ float omT[HDIM][OMS];
    __shared__ float qT[HDIM][QS];
    __shared__ float wred[4];
    const int tid = threadIdx.x;
    const int tx = tid & 15, ty = tid >> 4;
    const int h = blockIdx.y;
    const int bn0 = blockIdx.x * PTILE;

    #pragma unroll
    for (int i = 0; i < 8; ++i) {
        const int f = tid + 256 * i;
        const int m = f >> 4;
        const int d0 = (f & 15) << 2;
        float4 o = *(const float4*)&omega[m * HDIM + d0];
        omT[d0 + 0][m] = o.x; omT[d0 + 1][m] = o.y;
        omT[d0 + 2][m] = o.z; omT[d0 + 3][m] = o.w;
    }
    #pragma unroll
    for (int i = 0; i < 4; ++i) {
        const int f = tid + 256 * i;
        const int r = f >> 4;
        const int d0 = (f & 15) << 2;
        float4 qv = *(const float4*)&qk[(size_t)(bn0 + r) * DIMS + h * HDIM + d0];
        qT[d0 + 0][r] = qv.x * SCALE; qT[d0 + 1][r] = qv.y * SCALE;
        qT[d0 + 2][r] = qv.z * SCALE; qT[d0 + 3][r] = qv.w * SCALE;
    }
    __syncthreads();

    float c[4][8] = {};
    float nrm[4] = {};
    #pragma unroll 4
    for (int kd = 0; kd < HDIM; ++kd) {
        float4 qv = *(const float4*)&qT[kd][ty << 2];
        float4 o1 = *(const float4*)&omT[kd][tx << 3];
        float4 o2 = *(const float4*)&omT[kd][(tx << 3) + 4];
        float a_[4] = {qv.x, qv.y, qv.z, qv.w};
        float b_[8] = {o1.x, o1.y, o1.z, o1.w, o2.x, o2.y, o2.z, o2.w};
        #pragma unroll
        for (int i = 0; i < 4; ++i) {
            nrm[i] += a_[i] * a_[i];
            #pragma unroll
            for (int j = 0; j < 8; ++j) c[i][j] += a_[i] * b_[j];
        }
    }
    #pragma unroll
    for (int i = 0; i < 4; ++i) {
        const float nh = 0.5f * nrm[i];
        #pragma unroll
        for (int j = 0; j < 8; ++j) c[i][j] -= nh;
    }

    if (is_query) {
        #pragma unroll
        for (int i = 0; i < 4; ++i) {
            float mx = c[i][0];
            #pragma unroll
            for (int j = 1; j < 8; ++j) mx = fmaxf(mx, c[i][j]);
            #pragma unroll
            for (int o = 8; o >= 1; o >>= 1) mx = fmaxf(mx, __shfl_xor(mx, o));
            const int br = bn0 + (ty << 2) + i;
            const int b = br >> 10, n = br & (NN - 1);
            const size_t orow = ((size_t)(b * NHEADS + h) * NN + n) * NFEAT;
            ushort pk[8];
            #pragma unroll
            for (int j = 0; j < 8; ++j)
                pk[j] = f2b(expf(c[i][j] - mx) * INV_SQRT_M + 1e-4f);
            *(s8v*)&out_b16[orow + (tx << 3)] = *(s8v*)&pk[0];
        }
    } else {
        float mx = -3.4e38f;
        #pragma unroll
        for (int i = 0; i < 4; ++i) {
            const int br = bn0 + (ty << 2) + i;
            const int b = br >> 10, n = br & (NN - 1);
            const size_t orow = ((size_t)(b * NHEADS + h) * NN + n) * NFEAT;
            float4 r0 = {c[i][0], c[i][1], c[i][2], c[i][3]};
            float4 r1 = {c[i][4], c[i][5], c[i][6], c[i][7]};
            *(float4*)&out_f32[orow + (tx << 3)] = r0;
            *(float4*)&out_f32[orow + (tx << 3) + 4] = r1;
            #pragma unroll
            for (int j = 0; j < 8; ++j) mx = fmaxf(mx, c[i][j]);
        }
        #pragma unroll
        for (int o = 32; o >= 1; o >>= 1) mx = fmaxf(mx, __shfl_xor(mx, o));
        if ((tid & 63) == 0) wred[tid >> 6] = mx;
        __syncthreads();
        if (tid == 0)
            blockmax[blockIdx.y * gridDim.x + blockIdx.x] =
                fmaxf(fmaxf(wred[0], wred[1]), fmaxf(wred[2], wred[3]));
    }
}

__global__ __launch_bounds__(256) void reduce_max_kernel(const float* __restrict__ in,
                                                         int n, float* __restrict__ out) {
    float mx = -3.4e38f;
    for (int i = threadIdx.x; i < n; i += 256) mx = fmaxf(mx, in[i]);
    #pragma unroll
    for (int o = 32; o >= 1; o >>= 1) mx = fmaxf(mx, __shfl_xor(mx, o));
    __shared__ float r[4];
    if ((threadIdx.x & 63) == 0) r[threadIdx.x >> 6] = mx;
    __syncthreads();
    if (threadIdx.x == 0) out[0] = fmaxf(fmaxf(r[0], r[1]), fmaxf(r[2], r[3]));
}

// ---------------- phik: exp + write row-major bf16 AND transposed bf16 ----------------
__global__ __launch_bounds__(256) void phik_exp_t(const float* __restrict__ logits,
                                                  const float* __restrict__ gmax,
                                                  ushort* __restrict__ phik,
                                                  ushort* __restrict__ phikT) {
    const int bh = blockIdx.y, n0 = blockIdx.x * CSZ;
    const int tid = threadIdx.x;
    __shared__ __attribute__((aligned(16))) ushort lt[64][136];
    const float gm = gmax[0];
    const int r = tid >> 2, c0 = (tid & 3) * 32;
    const size_t gbase = ((size_t)bh * NN + n0 + r) * NFEAT + c0;
    ushort tmp[32];
    #pragma unroll
    for (int i = 0; i < 8; ++i) {
        float4 v = *(const float4*)&logits[gbase + i * 4];
        tmp[i * 4 + 0] = f2b(expf(v.x - gm) * INV_SQRT_M + 1e-4f);
        tmp[i * 4 + 1] = f2b(expf(v.y - gm) * INV_SQRT_M + 1e-4f);
        tmp[i * 4 + 2] = f2b(expf(v.z - gm) * INV_SQRT_M + 1e-4f);
        tmp[i * 4 + 3] = f2b(expf(v.w - gm) * INV_SQRT_M + 1e-4f);
    }
    #pragma unroll
    for (int i = 0; i < 4; ++i) {
        *(s8v*)&phik[gbase + i * 8] = *(s8v*)&tmp[i * 8];
        *(s8v*)&lt[r][c0 + i * 8] = *(s8v*)&tmp[i * 8];
    }
    __syncthreads();
    const int m = tid >> 1, nh = (tid & 1) * 32;
    ushort tp[32];
    #pragma unroll
    for (int i = 0; i < 32; ++i) tp[i] = lt[nh + i][m];
    const size_t tbase = ((size_t)bh * NFEAT + m) * NN + n0 + nh;
    #pragma unroll
    for (int i = 0; i < 4; ++i) *(s8v*)&phikT[tbase + i * 8] = *(s8v*)&tp[i * 8];
}

// ---------------- V transpose+cast: Vt[bh][d][n] bf16 ----------------
__global__ __launch_bounds__(256) void vt_cast(const float* __restrict__ v,
                                               ushort* __restrict__ vt) {
    const int bh = blockIdx.y, n0 = blockIdx.x * CSZ;
    const int b = bh >> 4, h = bh & 15;
    __shared__ float lv[64][65];
    const int tid = threadIdx.x;
    const int r = tid >> 2, c0 = (tid & 3) * 16;
    #pragma unroll
    for (int i = 0; i < 4; ++i) {
        float4 q = *(const float4*)&v[((size_t)(b * NN + n0 + r)) * DIMS + h * HDIM + c0 + i * 4];
        lv[r][c0 + i * 4 + 0] = q.x; lv[r][c0 + i * 4 + 1] = q.y;
        lv[r][c0 + i * 4 + 2] = q.z; lv[r][c0 + i * 4 + 3] = q.w;
    }
    __syncthreads();
    const int d = tid >> 2, s0 = (tid & 3) * 16;
    ushort tp[16];
    #pragma unroll
    for (int i = 0; i < 16; ++i) tp[i] = f2b(lv[s0 + i][d]);
    const size_t tb = ((size_t)bh * HDIM + d) * NN + n0 + s0;
    *(s8v*)&vt[tb] = *(s8v*)&tp[0];
    *(s8v*)&vt[tb + 8] = *(s8v*)&tp[8];
}

// ---------------- per-chunk sums: SsumT[bh][c][d][m] = sum_n V[n,d]*phik[n,m] ----------------
__global__ __launch_bounds__(256) void chunk_sums(const ushort* __restrict__ phikT,
                                                  const ushort* __restrict__ vt,
                                                  float* __restrict__ ssum,
                                                  float* __restrict__ kcsum) {
    const int c = blockIdx.x, bh = blockIdx.y, n0 = c * CSZ;
    __shared__ __attribute__((aligned(16))) ushort lvt[64][72];
    __shared__ __attribute__((aligned(16))) ushort lkt[128][72];
    const int tid = threadIdx.x;
    {
        const int d = tid >> 2, s = (tid & 3) * 16;
        const size_t g = ((size_t)bh * HDIM + d) * NN + n0 + s;
        *(s8v*)&lvt[d][s]     = *(const s8v*)&vt[g];
        *(s8v*)&lvt[d][s + 8] = *(const s8v*)&vt[g + 8];
    }
    {
        const int m = tid >> 1, s = (tid & 1) * 32;
        const size_t g = ((size_t)bh * NFEAT + m) * NN + n0 + s;
        #pragma unroll
        for (int i = 0; i < 4; ++i) *(s8v*)&lkt[m][s + i * 8] = *(const s8v*)&phikT[g + i * 8];
    }
    __syncthreads();
    const int w = tid >> 6, l = tid & 63, lr = l & 15, lg = l >> 4;
    f4v acc[8] = {};
    #pragma unroll
    for (int k0 = 0; k0 < 64; k0 += 32) {
        s8v a = *(s8v*)&lvt[w * 16 + lr][k0 + lg * 8];
        #pragma unroll
        for (int ct = 0; ct < 8; ++ct) {
            s8v bf = *(s8v*)&lkt[ct * 16 + lr][k0 + lg * 8];
            acc[ct] = __builtin_amdgcn_mfma_f32_16x16x32_bf16(a, bf, acc[ct], 0, 0, 0);
        }
    }
    const size_t obase = ((size_t)bh * NCH + c) * (HDIM * NFEAT);
    #pragma unroll
    for (int ct = 0; ct < 8; ++ct)
        #pragma unroll
        for (int rg = 0; rg < 4; ++rg) {
            const int d = w * 16 + lg * 4 + rg, m = ct * 16 + lr;
            ssum[obase + (size_t)d * NFEAT + m] = acc[ct][rg];
        }
    if (tid < 128) {
        float s = 0.f;
        #pragma unroll 8
        for (int i = 0; i < 64; ++i) s += b2f(lkt[tid][i]);
        kcsum[((size_t)bh * NCH + c) * NFEAT + tid] = s;
    }
}

// ---------------- prefix over chunks ----------------
__global__ void kc_prefix(const float* __restrict__ kcsum, float* __restrict__ kcpre) {
    const int bh = blockIdx.x, m = threadIdx.x;
    float a = 0.f;
    for (int c = 0; c < NCH; ++c) {
        kcpre[((size_t)bh * NCH + c) * NFEAT + m] = a;
        a += kcsum[((size_t)bh * NCH + c) * NFEAT + m];
    }
}

__global__ __launch_bounds__(256) void chunk_prefix(const float* __restrict__ ssum,
                                                    ushort* __restrict__ spre) {
    const int bh = blockIdx.y, sl = blockIdx.x;
    const int base_e = sl * 2048 + threadIdx.x;
    float acc[8] = {};
    const size_t bb = (size_t)bh * NCH * (HDIM * NFEAT);
    for (int c = 0; c < NCH; ++c) {
        const size_t cb = bb + (size_t)c * (HDIM * NFEAT);
        #pragma unroll
        for (int e = 0; e < 8; ++e) {
            spre[cb + base_e + e * 256] = f2b(acc[e]);
            acc[e] += ssum[cb + base_e + e * 256];
        }
    }
}

// ---------------- chunked causal attention via MFMA (att out in bf16) ----------------
__global__ __launch_bounds__(256) void scan_final(const ushort* __restrict__ phiq,
                                                  const ushort* __restrict__ phik,
                                                  const ushort* __restrict__ vt,
                                                  const ushort* __restrict__ spre,
                                                  const float* __restrict__ kcpre,
                                                  ushort* __restrict__ att_b) {
    const int c = blockIdx.x, bh = blockIdx.y;
    const int b = bh >> 4, h = bh & 15;
    const int n0 = c * CSZ;
    __shared__ __attribute__((aligned(16))) ushort lq[64][136];
    __shared__ __attribute__((aligned(16))) ushort lk[64][136];
    __shared__ __attribute__((aligned(16))) ushort lvt[64][72];
    __shared__ __attribute__((aligned(16))) ushort lsp[64][136];
    __shared__ __attribute__((aligned(16))) ushort lA[64][72];
    __shared__ float kc[NFEAT];
    __shared__ float zin[64];
    __shared__ float zp[4][64];
    const int tid = threadIdx.x;

    const size_t qb = ((size_t)bh * NN + n0) * NFEAT;
    #pragma unroll
    for (int i = 0; i < 4; ++i) {
        const int idx = tid + 256 * i;
        const int r = idx >> 4, cs = (idx & 15) * 8;
        *(s8v*)&lq[r][cs] = *(const s8v*)&phiq[qb + (size_t)r * NFEAT + cs];
        *(s8v*)&lk[r][cs] = *(const s8v*)&phik[qb + (size_t)r * NFEAT + cs];
    }
    const size_t sb = ((size_t)bh * NCH + c) * (HDIM * NFEAT);
    #pragma unroll
    for (int i = 0; i < 4; ++i) {
        const int idx = tid + 256 * i;
        const int r = idx >> 4, cs = (idx & 15) * 8;
        *(s8v*)&lsp[r][cs] = *(const s8v*)&spre[sb + (size_t)r * NFEAT + cs];
    }
    {
        const int d = tid >> 2, s = (tid & 3) * 16;
        const size_t g = ((size_t)bh * HDIM + d) * NN + n0 + s;
        *(s8v*)&lvt[d][s]     = *(const s8v*)&vt[g];
        *(s8v*)&lvt[d][s + 8] = *(const s8v*)&vt[g + 8];
    }
    if (tid < NFEAT) kc[tid] = kcpre[((size_t)bh * NCH + c) * NFEAT + tid];
    __syncthreads();

    const int w = tid >> 6, l = tid & 63, lr = l & 15, lg = l >> 4;

    // Phase 1: A = phiq @ phik^T
    f4v a4[4] = {};
    #pragma unroll
    for (int k0 = 0; k0 < 128; k0 += 32) {
        s8v av = *(s8v*)&lq[w * 16 + lr][k0 + lg * 8];
        #pragma unroll
        for (int ct = 0; ct < 4; ++ct) {
            s8v bv = *(s8v*)&lk[ct * 16 + lr][k0 + lg * 8];
            a4[ct] = __builtin_amdgcn_mfma_f32_16x16x32_bf16(av, bv, a4[ct], 0, 0, 0);
        }
    }
    float zi[4] = {0.f, 0.f, 0.f, 0.f};
    #pragma unroll
    for (int ct = 0; ct < 4; ++ct) {
        #pragma unroll
        for (int rg = 0; rg < 4; ++rg) {
            const int row = w * 16 + lg * 4 + rg;
            const int col = ct * 16 + lr;
            const float val = (col <= row) ? a4[ct][rg] : 0.f;
            zi[rg] += val;
            lA[row][col] = f2b(val);
        }
    }
    #pragma unroll
    for (int rg = 0; rg < 4; ++rg) {
        float z = zi[rg];
        z += __shfl_xor(z, 1); z += __shfl_xor(z, 2);
        z += __shfl_xor(z, 4); z += __shfl_xor(z, 8);
        if (lr == 0) zin[w * 16 + lg * 4 + rg] = z;
    }
    {
        const int row = tid & 63, qq = tid >> 6;
        float s = 0.f;
        #pragma unroll 8
        for (int m = 0; m < 32; ++m) s += b2f(lq[row][qq * 32 + m]) * kc[qq * 32 + m];
        zp[qq][row] = s;
    }
    __syncthreads();

    // Phase 2: out = Amask @ V + phiq @ Spre
    f4v o4[4] = {};
    #pragma unroll
    for (int k0 = 0; k0 < 64; k0 += 32) {
        s8v av = *(s8v*)&lA[w * 16 + lr][k0 + lg * 8];
        #pragma unroll
        for (int ct = 0; ct < 4; ++ct) {
            s8v bv = *(s8v*)&lvt[ct * 16 + lr][k0 + lg * 8];
            o4[ct] = __builtin_amdgcn_mfma_f32_16x16x32_bf16(av, bv, o4[ct], 0, 0, 0);
        }
    }
    #pragma unroll
    for (int k0 = 0; k0 < 128; k0 += 32) {
        s8v av = *(s8v*)&lq[w * 16 + lr][k0 + lg * 8];
        #pragma unroll
        for (int ct = 0; ct < 4; ++ct) {
            s8v bv = *(s8v*)&lsp[ct * 16 + lr][k0 + lg * 8];
            o4[ct] = __builtin_amdgcn_mfma_f32_16x16x32_bf16(av, bv, o4[ct], 0, 0, 0);
        }
    }
    #pragma unroll
    for (int rg = 0; rg < 4; ++rg) {
        const int row = w * 16 + lg * 4 + rg;
        const float z = zin[row] + zp[0][row] + zp[1][row] + zp[2][row] + zp[3][row] + 1e-6f;
        const float rz = 1.f / z;
        #pragma unroll
        for (int ct = 0; ct < 4; ++ct) {
            const int d = ct * 16 + lr;
            att_b[((size_t)(b * NN + n0 + row)) * DIMS + h * HDIM + d] = f2b(o4[ct][rg] * rz);
        }
    }
}

extern "C" void kernel_launch(void* const* d_in, const int* in_sizes, int n_in,
                              void* d_out, int out_size, void* d_ws, size_t ws_size,
                              hipStream_t stream) {
    const float* x     = (const float*)d_in[0];
    const float* omega = (const float*)d_in[1];
    const float* Wq    = (const float*)d_in[2];
    const float* Wk    = (const float*)d_in[3];
    const float* Wv    = (const float*)d_in[4];
    const float* Wo    = (const float*)d_in[5];
    const float* bo    = (const float*)d_in[6];
    float* out = (float*)d_out;

    float* ws = (float*)d_ws;
    const size_t PROJ = (size_t)BN * DIMS;                 // 2M
    const size_t PHI  = (size_t)BB * NHEADS * NN * NFEAT;  // 4M
    float* q      = ws;                  // f32; later reused as att_b (bf16)
    float* k      = q + PROJ;            // f32; later reused as phikT_b
    float* v      = k + PROJ;            // f32; later reused as spre_b
    float* logits = v + PROJ;            // 4M f32; xhi/xlo live here BEFORE logits written
    ushort* phiq_b  = (ushort*)(logits + PHI);   // 8MB; wq hi/lo live here first
    ushort* phik_b  = phiq_b + PHI;              // 8MB; wk hi/lo live here first
    ushort* vt_b    = phik_b + PHI;              // 4MB; wv hi lives here first
    ushort* woh     = vt_b + PROJ;               // 2MB, persists to the end
    float* kcsum    = (float*)(woh + WW);
    float* kcpre    = kcsum + 32 * NCH * NFEAT;
    float* blockmax = kcpre + 32 * NCH * NFEAT;
    float* gmax     = blockmax + 512;
    // aliases (strictly ordered producer->consumer on one stream):
    ushort* xhi     = (ushort*)logits;   // dead after v GEMM; logits written later
    ushort* xlo     = xhi + PROJ;
    ushort* wqh     = phiq_b;            // dead after q GEMM; phiq written later
    ushort* wql     = phiq_b + WW;
    ushort* wkh     = phik_b;            // dead after k GEMM; phik written later
    ushort* wkl     = phik_b + WW;
    ushort* wvh     = vt_b;              // dead after v GEMM; vt written later
    ushort* phikT_b = (ushort*)k;
    ushort* spre_b  = (ushort*)v;
    float* ssum     = logits;
    ushort* att_b   = (ushort*)q;

    // casts
    cast_split<<<(int)(PROJ / 8 + 255) / 256, 256, 0, stream>>>(x, xhi, xlo, (int)(PROJ / 8));
    cast_split<<<(WW / 8 + 255) / 256, 256, 0, stream>>>(Wq, wqh, wql, WW / 8);
    cast_split<<<(WW / 8 + 255) / 256, 256, 0, stream>>>(Wk, wkh, wkl, WW / 8);
    cast_split<<<(WW / 8 + 255) / 256, 256, 0, stream>>>(Wv, wvh, nullptr, WW / 8);
    cast_split<<<(WW / 8 + 255) / 256, 256, 0, stream>>>(Wo, woh, nullptr, WW / 8);

    // projections (split bf16 for q,k; plain for v)
    dim3 gg(BN / 64, DIMS / 128);   // (32, 8) = 256 blocks
    gemm_nt_mfma<true><<<gg, 256, 0, stream>>>(xhi, xlo, wqh, wql, q, nullptr, BN, DIMS, DIMS);
    gemm_nt_mfma<true><<<gg, 256, 0, stream>>>(xhi, xlo, wkh, wkl, k, nullptr, BN, DIMS, DIMS);
    gemm_nt_mfma<false><<<gg, 256, 0, stream>>>(xhi, nullptr, wvh, nullptr, v, nullptr, BN, DIMS, DIMS);

    dim3 pg(BN / PTILE, NHEADS);
    phi_gemm<<<pg, 256, 0, stream>>>(q, omega, phiq_b, nullptr, nullptr, 1);
    phi_gemm<<<pg, 256, 0, stream>>>(k, omega, nullptr, logits, blockmax, 0);
    reduce_max_kernel<<<1, 256, 0, stream>>>(blockmax, 512, gmax);

    dim3 cg(NCH, BB * NHEADS);
    phik_exp_t<<<cg, 256, 0, stream>>>(logits, gmax, phik_b, phikT_b);
    vt_cast<<<cg, 256, 0, stream>>>(v, vt_b);
    chunk_sums<<<cg, 256, 0, stream>>>(phikT_b, vt_b, ssum, kcsum);
    kc_prefix<<<BB * NHEADS, NFEAT, 0, stream>>>(kcsum, kcpre);
    chunk_prefix<<<dim3(4, BB * NHEADS), 256, 0, stream>>>(ssum, spre_b);
    scan_final<<<cg, 256, 0, stream>>>(phiq_b, phik_b, vt_b, spre_b, kcpre, att_b);

    // output projection (plain bf16 MFMA) straight to d_out
    gemm_nt_mfma<false><<<gg, 256, 0, stream>>>(att_b, nullptr, woh, nullptr, out, bo, BN, DIMS, DIMS);
}

// Round 6
// 144.242 us; speedup vs baseline: 4.6313x; 1.3880x over previous
//
#include <hip/hip_runtime.h>
#include <hip/hip_bf16.h>
#include <math.h>

#define DIMS 1024
#define NHEADS 16
#define HDIM 64
#define NFEAT 128
#define BB 2
#define NN 1024
#define BN (BB*NN)   // 2048
#define NCH 16       // chunks per (b,h)
#define CSZ 64       // chunk size
#define WW (DIMS*DIMS)
#define QKVN (3*DIMS) // 3072

#define SCALE 0.3535533905932738f       // 64^-0.25
#define INV_SQRT_M 0.08838834764831845f // 1/sqrt(128)

typedef __attribute__((ext_vector_type(8))) _Float16 h8v;  // 8 fp16 (4 VGPRs)
typedef __attribute__((ext_vector_type(8))) short s8v;     // raw 16B
typedef __attribute__((ext_vector_type(4))) float f4v;     // mfma accumulator

__device__ __forceinline__ ushort f2h(float x) {
    _Float16 h = (_Float16)x;
    return *(ushort*)&h;
}
__device__ __forceinline__ float h2f(ushort u) {
    _Float16 h = *(_Float16*)&u;
    return (float)h;
}

// ---------------- cast f32 -> fp16 ----------------
__global__ __launch_bounds__(256) void cast_h(const float* __restrict__ src,
                                              ushort* __restrict__ dst, int n8) {
    const int i = blockIdx.x * 256 + threadIdx.x;
    if (i >= n8) return;
    float4 a = ((const float4*)src)[2 * i];
    float4 b = ((const float4*)src)[2 * i + 1];
    float v[8] = {a.x, a.y, a.z, a.w, b.x, b.y, b.z, b.w};
    ushort h8[8];
    #pragma unroll
    for (int j = 0; j < 8; ++j) h8[j] = f2h(v[j]);
    *(s8v*)&dst[(size_t)i * 8] = *(s8v*)&h8[0];
}

// ---------------- MFMA GEMM NT (fp16): C[i,j] = sum_k A[i,k]*B[j,k] (+bias[j]) ----------------
// A: [M x K] fp16 row-major; B: [N x K] fp16 row-major; C: [M x N] f32. Tile 64x128, BK=32.
__global__ __launch_bounds__(256) void gemm_nt_mfma(const ushort* __restrict__ A,
                                                    const ushort* __restrict__ B,
                                                    float* __restrict__ C,
                                                    const float* __restrict__ bias,
                                                    int M, int N, int K) {
    __shared__ __attribute__((aligned(16))) ushort lA[64][40];
    __shared__ __attribute__((aligned(16))) ushort lB[128][40];
    const int tid = threadIdx.x;
    const int w = tid >> 6, l = tid & 63, lr = l & 15, lg = l >> 4;
    const int woffm = (w >> 1) * 32, woffn = (w & 1) * 64;
    const int bi = blockIdx.x * 64, bj = blockIdx.y * 128;
    const int arow = tid >> 2, acol = (tid & 3) * 8;
    const int brow = tid >> 1, bcol = (tid & 1) * 16;

    f4v acc[2][4] = {};
    for (int k0 = 0; k0 < K; k0 += 32) {
        __syncthreads();
        *(s8v*)&lA[arow][acol] = *(const s8v*)&A[(size_t)(bi + arow) * K + k0 + acol];
        *(s8v*)&lB[brow][bcol]     = *(const s8v*)&B[(size_t)(bj + brow) * K + k0 + bcol];
        *(s8v*)&lB[brow][bcol + 8] = *(const s8v*)&B[(size_t)(bj + brow) * K + k0 + bcol + 8];
        __syncthreads();
        h8v a0 = *(h8v*)&lA[woffm + lr][lg * 8];
        h8v a1 = *(h8v*)&lA[woffm + 16 + lr][lg * 8];
        #pragma unroll
        for (int nf = 0; nf < 4; ++nf) {
            h8v bv = *(h8v*)&lB[woffn + nf * 16 + lr][lg * 8];
            acc[0][nf] = __builtin_amdgcn_mfma_f32_16x16x32_f16(a0, bv, acc[0][nf], 0, 0, 0);
            acc[1][nf] = __builtin_amdgcn_mfma_f32_16x16x32_f16(a1, bv, acc[1][nf], 0, 0, 0);
        }
    }
    #pragma unroll
    for (int mf = 0; mf < 2; ++mf)
        #pragma unroll
        for (int nf = 0; nf < 4; ++nf)
            #pragma unroll
            for (int rg = 0; rg < 4; ++rg) {
                const int row = bi + woffm + mf * 16 + lg * 4 + rg;
                const int col = bj + woffn + nf * 16 + lr;
                float r = acc[mf][nf][rg];
                if (bias) r += bias[col];
                C[(size_t)row * N + col] = r;
            }
}

// ---------------- phi as tiled GEMM with fused epilogue ----------------
// qsrc: rows of q (or k) in the fused qkv buffer; ld = row stride; head h at col h*64.
#define PTILE 64
#define OMS (NFEAT + 4)
#define QS  (HDIM + 4)

__global__ __launch_bounds__(256) void phi_gemm(const float* __restrict__ qsrc, int ld,
                                                const float* __restrict__ omega,
                                                ushort* __restrict__ out_h16,
                                                float* __restrict__ out_f32,
                                                float* __restrict__ blockmax,
                                                int is_query) {
    __shared__ float omT[HDIM][OMS];
    __shared__ float qT[HDIM][QS];
    __shared__ float wred[4];
    const int tid = threadIdx.x;
    const int tx = tid & 15, ty = tid >> 4;
    const int h = blockIdx.y;
    const int bn0 = blockIdx.x * PTILE;

    #pragma unroll
    for (int i = 0; i < 8; ++i) {
        const int f = tid + 256 * i;
        const int m = f >> 4;
        const int d0 = (f & 15) << 2;
        float4 o = *(const float4*)&omega[m * HDIM + d0];
        omT[d0 + 0][m] = o.x; omT[d0 + 1][m] = o.y;
        omT[d0 + 2][m] = o.z; omT[d0 + 3][m] = o.w;
    }
    #pragma unroll
    for (int i = 0; i < 4; ++i) {
        const int f = tid + 256 * i;
        const int r = f >> 4;
        const int d0 = (f & 15) << 2;
        float4 qv = *(const float4*)&qsrc[(size_t)(bn0 + r) * ld + h * HDIM + d0];
        qT[d0 + 0][r] = qv.x * SCALE; qT[d0 + 1][r] = qv.y * SCALE;
        qT[d0 + 2][r] = qv.z * SCALE; qT[d0 + 3][r] = qv.w * SCALE;
    }
    __syncthreads();

    float c[4][8] = {};
    float nrm[4] = {};
    #pragma unroll 4
    for (int kd = 0; kd < HDIM; ++kd) {
        float4 qv = *(const float4*)&qT[kd][ty << 2];
        float4 o1 = *(const float4*)&omT[kd][tx << 3];
        float4 o2 = *(const float4*)&omT[kd][(tx << 3) + 4];
        float a_[4] = {qv.x, qv.y, qv.z, qv.w};
        float b_[8] = {o1.x, o1.y, o1.z, o1.w, o2.x, o2.y, o2.z, o2.w};
        #pragma unroll
        for (int i = 0; i < 4; ++i) {
            nrm[i] += a_[i] * a_[i];
            #pragma unroll
            for (int j = 0; j < 8; ++j) c[i][j] += a_[i] * b_[j];
        }
    }
    #pragma unroll
    for (int i = 0; i < 4; ++i) {
        const float nh = 0.5f * nrm[i];
        #pragma unroll
        for (int j = 0; j < 8; ++j) c[i][j] -= nh;
    }

    if (is_query) {
        #pragma unroll
        for (int i = 0; i < 4; ++i) {
            float mx = c[i][0];
            #pragma unroll
            for (int j = 1; j < 8; ++j) mx = fmaxf(mx, c[i][j]);
            #pragma unroll
            for (int o = 8; o >= 1; o >>= 1) mx = fmaxf(mx, __shfl_xor(mx, o));
            const int br = bn0 + (ty << 2) + i;
            const int b = br >> 10, n = br & (NN - 1);
            const size_t orow = ((size_t)(b * NHEADS + h) * NN + n) * NFEAT;
            ushort pk[8];
            #pragma unroll
            for (int j = 0; j < 8; ++j)
                pk[j] = f2h(expf(c[i][j] - mx) * INV_SQRT_M + 1e-4f);
            *(s8v*)&out_h16[orow + (tx << 3)] = *(s8v*)&pk[0];
        }
    } else {
        float mx = -3.4e38f;
        #pragma unroll
        for (int i = 0; i < 4; ++i) {
            const int br = bn0 + (ty << 2) + i;
            const int b = br >> 10, n = br & (NN - 1);
            const size_t orow = ((size_t)(b * NHEADS + h) * NN + n) * NFEAT;
            float4 r0 = {c[i][0], c[i][1], c[i][2], c[i][3]};
            float4 r1 = {c[i][4], c[i][5], c[i][6], c[i][7]};
            *(float4*)&out_f32[orow + (tx << 3)] = r0;
            *(float4*)&out_f32[orow + (tx << 3) + 4] = r1;
            #pragma unroll
            for (int j = 0; j < 8; ++j) mx = fmaxf(mx, c[i][j]);
        }
        #pragma unroll
        for (int o = 32; o >= 1; o >>= 1) mx = fmaxf(mx, __shfl_xor(mx, o));
        if ((tid & 63) == 0) wred[tid >> 6] = mx;
        __syncthreads();
        if (tid == 0)
            blockmax[blockIdx.y * gridDim.x + blockIdx.x] =
                fmaxf(fmaxf(wred[0], wred[1]), fmaxf(wred[2], wred[3]));
    }
}

__global__ __launch_bounds__(256) void reduce_max_kernel(const float* __restrict__ in,
                                                         int n, float* __restrict__ out) {
    float mx = -3.4e38f;
    for (int i = threadIdx.x; i < n; i += 256) mx = fmaxf(mx, in[i]);
    #pragma unroll
    for (int o = 32; o >= 1; o >>= 1) mx = fmaxf(mx, __shfl_xor(mx, o));
    __shared__ float r[4];
    if ((threadIdx.x & 63) == 0) r[threadIdx.x >> 6] = mx;
    __syncthreads();
    if (threadIdx.x == 0) out[0] = fmaxf(fmaxf(r[0], r[1]), fmaxf(r[2], r[3]));
}

// ---------------- phik: exp + write row-major fp16 AND transposed fp16 ----------------
__global__ __launch_bounds__(256) void phik_exp_t(const float* __restrict__ logits,
                                                  const float* __restrict__ gmax,
                                                  ushort* __restrict__ phik,
                                                  ushort* __restrict__ phikT) {
    const int bh = blockIdx.y, n0 = blockIdx.x * CSZ;
    const int tid = threadIdx.x;
    __shared__ __attribute__((aligned(16))) ushort lt[64][136];
    const float gm = gmax[0];
    const int r = tid >> 2, c0 = (tid & 3) * 32;
    const size_t gbase = ((size_t)bh * NN + n0 + r) * NFEAT + c0;
    ushort tmp[32];
    #pragma unroll
    for (int i = 0; i < 8; ++i) {
        float4 v = *(const float4*)&logits[gbase + i * 4];
        tmp[i * 4 + 0] = f2h(expf(v.x - gm) * INV_SQRT_M + 1e-4f);
        tmp[i * 4 + 1] = f2h(expf(v.y - gm) * INV_SQRT_M + 1e-4f);
        tmp[i * 4 + 2] = f2h(expf(v.z - gm) * INV_SQRT_M + 1e-4f);
        tmp[i * 4 + 3] = f2h(expf(v.w - gm) * INV_SQRT_M + 1e-4f);
    }
    #pragma unroll
    for (int i = 0; i < 4; ++i) {
        *(s8v*)&phik[gbase + i * 8] = *(s8v*)&tmp[i * 8];
        *(s8v*)&lt[r][c0 + i * 8] = *(s8v*)&tmp[i * 8];
    }
    __syncthreads();
    const int m = tid >> 1, nh = (tid & 1) * 32;
    ushort tp[32];
    #pragma unroll
    for (int i = 0; i < 32; ++i) tp[i] = lt[nh + i][m];
    const size_t tbase = ((size_t)bh * NFEAT + m) * NN + n0 + nh;
    #pragma unroll
    for (int i = 0; i < 4; ++i) *(s8v*)&phikT[tbase + i * 8] = *(s8v*)&tp[i * 8];
}

// ---------------- V transpose+cast: Vt[bh][d][n] fp16 ----------------
__global__ __launch_bounds__(256) void vt_cast(const float* __restrict__ vsrc, int ld,
                                               ushort* __restrict__ vt) {
    const int bh = blockIdx.y, n0 = blockIdx.x * CSZ;
    const int b = bh >> 4, h = bh & 15;
    __shared__ float lv[64][65];
    const int tid = threadIdx.x;
    const int r = tid >> 2, c0 = (tid & 3) * 16;
    #pragma unroll
    for (int i = 0; i < 4; ++i) {
        float4 q = *(const float4*)&vsrc[((size_t)(b * NN + n0 + r)) * ld + h * HDIM + c0 + i * 4];
        lv[r][c0 + i * 4 + 0] = q.x; lv[r][c0 + i * 4 + 1] = q.y;
        lv[r][c0 + i * 4 + 2] = q.z; lv[r][c0 + i * 4 + 3] = q.w;
    }
    __syncthreads();
    const int d = tid >> 2, s0 = (tid & 3) * 16;
    ushort tp[16];
    #pragma unroll
    for (int i = 0; i < 16; ++i) tp[i] = f2h(lv[s0 + i][d]);
    const size_t tb = ((size_t)bh * HDIM + d) * NN + n0 + s0;
    *(s8v*)&vt[tb] = *(s8v*)&tp[0];
    *(s8v*)&vt[tb + 8] = *(s8v*)&tp[8];
}

// ---------------- per-chunk sums: SsumT[bh][c][d][m] = sum_n V[n,d]*phik[n,m] ----------------
__global__ __launch_bounds__(256) void chunk_sums(const ushort* __restrict__ phikT,
                                                  const ushort* __restrict__ vt,
                                                  float* __restrict__ ssum,
                                                  float* __restrict__ kcsum) {
    const int c = blockIdx.x, bh = blockIdx.y, n0 = c * CSZ;
    __shared__ __attribute__((aligned(16))) ushort lvt[64][72];
    __shared__ __attribute__((aligned(16))) ushort lkt[128][72];
    const int tid = threadIdx.x;
    {
        const int d = tid >> 2, s = (tid & 3) * 16;
        const size_t g = ((size_t)bh * HDIM + d) * NN + n0 + s;
        *(s8v*)&lvt[d][s]     = *(const s8v*)&vt[g];
        *(s8v*)&lvt[d][s + 8] = *(const s8v*)&vt[g + 8];
    }
    {
        const int m = tid >> 1, s = (tid & 1) * 32;
        const size_t g = ((size_t)bh * NFEAT + m) * NN + n0 + s;
        #pragma unroll
        for (int i = 0; i < 4; ++i) *(s8v*)&lkt[m][s + i * 8] = *(const s8v*)&phikT[g + i * 8];
    }
    __syncthreads();
    const int w = tid >> 6, l = tid & 63, lr = l & 15, lg = l >> 4;
    f4v acc[8] = {};
    #pragma unroll
    for (int k0 = 0; k0 < 64; k0 += 32) {
        h8v a = *(h8v*)&lvt[w * 16 + lr][k0 + lg * 8];
        #pragma unroll
        for (int ct = 0; ct < 8; ++ct) {
            h8v bf = *(h8v*)&lkt[ct * 16 + lr][k0 + lg * 8];
            acc[ct] = __builtin_amdgcn_mfma_f32_16x16x32_f16(a, bf, acc[ct], 0, 0, 0);
        }
    }
    const size_t obase = ((size_t)bh * NCH + c) * (HDIM * NFEAT);
    #pragma unroll
    for (int ct = 0; ct < 8; ++ct)
        #pragma unroll
        for (int rg = 0; rg < 4; ++rg) {
            const int d = w * 16 + lg * 4 + rg, m = ct * 16 + lr;
            ssum[obase + (size_t)d * NFEAT + m] = acc[ct][rg];
        }
    if (tid < 128) {
        float s = 0.f;
        #pragma unroll 8
        for (int i = 0; i < 64; ++i) s += h2f(lkt[tid][i]);
        kcsum[((size_t)bh * NCH + c) * NFEAT + tid] = s;
    }
}

// ---------------- prefix over chunks ----------------
__global__ void kc_prefix(const float* __restrict__ kcsum, float* __restrict__ kcpre) {
    const int bh = blockIdx.x, m = threadIdx.x;
    float a = 0.f;
    for (int c = 0; c < NCH; ++c) {
        kcpre[((size_t)bh * NCH + c) * NFEAT + m] = a;
        a += kcsum[((size_t)bh * NCH + c) * NFEAT + m];
    }
}

__global__ __launch_bounds__(256) void chunk_prefix(const float* __restrict__ ssum,
                                                    ushort* __restrict__ spre) {
    const int bh = blockIdx.y, sl = blockIdx.x;
    const int base_e = sl * 2048 + threadIdx.x;
    float acc[8] = {};
    const size_t bb = (size_t)bh * NCH * (HDIM * NFEAT);
    for (int c = 0; c < NCH; ++c) {
        const size_t cb = bb + (size_t)c * (HDIM * NFEAT);
        #pragma unroll
        for (int e = 0; e < 8; ++e) {
            spre[cb + base_e + e * 256] = f2h(acc[e]);
            acc[e] += ssum[cb + base_e + e * 256];
        }
    }
}

// ---------------- chunked causal attention via MFMA (att out fp16) ----------------
__global__ __launch_bounds__(256) void scan_final(const ushort* __restrict__ phiq,
                                                  const ushort* __restrict__ phik,
                                                  const ushort* __restrict__ vt,
                                                  const ushort* __restrict__ spre,
                                                  const float* __restrict__ kcpre,
                                                  ushort* __restrict__ att_h) {
    const int c = blockIdx.x, bh = blockIdx.y;
    const int b = bh >> 4, h = bh & 15;
    const int n0 = c * CSZ;
    __shared__ __attribute__((aligned(16))) ushort lq[64][136];
    __shared__ __attribute__((aligned(16))) ushort lk[64][136];
    __shared__ __attribute__((aligned(16))) ushort lvt[64][72];
    __shared__ __attribute__((aligned(16))) ushort lsp[64][136];
    __shared__ __attribute__((aligned(16))) ushort lA[64][72];
    __shared__ float kc[NFEAT];
    __shared__ float zin[64];
    __shared__ float zp[4][64];
    const int tid = threadIdx.x;

    const size_t qb = ((size_t)bh * NN + n0) * NFEAT;
    #pragma unroll
    for (int i = 0; i < 4; ++i) {
        const int idx = tid + 256 * i;
        const int r = idx >> 4, cs = (idx & 15) * 8;
        *(s8v*)&lq[r][cs] = *(const s8v*)&phiq[qb + (size_t)r * NFEAT + cs];
        *(s8v*)&lk[r][cs] = *(const s8v*)&phik[qb + (size_t)r * NFEAT + cs];
    }
    const size_t sb = ((size_t)bh * NCH + c) * (HDIM * NFEAT);
    #pragma unroll
    for (int i = 0; i < 4; ++i) {
        const int idx = tid + 256 * i;
        const int r = idx >> 4, cs = (idx & 15) * 8;
        *(s8v*)&lsp[r][cs] = *(const s8v*)&spre[sb + (size_t)r * NFEAT + cs];
    }
    {
        const int d = tid >> 2, s = (tid & 3) * 16;
        const size_t g = ((size_t)bh * HDIM + d) * NN + n0 + s;
        *(s8v*)&lvt[d][s]     = *(const s8v*)&vt[g];
        *(s8v*)&lvt[d][s + 8] = *(const s8v*)&vt[g + 8];
    }
    if (tid < NFEAT) kc[tid] = kcpre[((size_t)bh * NCH + c) * NFEAT + tid];
    __syncthreads();

    const int w = tid >> 6, l = tid & 63, lr = l & 15, lg = l >> 4;

    // Phase 1: A = phiq @ phik^T
    f4v a4[4] = {};
    #pragma unroll
    for (int k0 = 0; k0 < 128; k0 += 32) {
        h8v av = *(h8v*)&lq[w * 16 + lr][k0 + lg * 8];
        #pragma unroll
        for (int ct = 0; ct < 4; ++ct) {
            h8v bv = *(h8v*)&lk[ct * 16 + lr][k0 + lg * 8];
            a4[ct] = __builtin_amdgcn_mfma_f32_16x16x32_f16(av, bv, a4[ct], 0, 0, 0);
        }
    }
    // mask, quantize to fp16, accumulate z from the SAME quantized values
    float zi[4] = {0.f, 0.f, 0.f, 0.f};
    #pragma unroll
    for (int ct = 0; ct < 4; ++ct) {
        #pragma unroll
        for (int rg = 0; rg < 4; ++rg) {
            const int row = w * 16 + lg * 4 + rg;
            const int col = ct * 16 + lr;
            const float val = (col <= row) ? a4[ct][rg] : 0.f;
            const ushort hq = f2h(val);
            zi[rg] += h2f(hq);
            lA[row][col] = hq;
        }
    }
    #pragma unroll
    for (int rg = 0; rg < 4; ++rg) {
        float z = zi[rg];
        z += __shfl_xor(z, 1); z += __shfl_xor(z, 2);
        z += __shfl_xor(z, 4); z += __shfl_xor(z, 8);
        if (lr == 0) zin[w * 16 + lg * 4 + rg] = z;
    }
    {
        const int row = tid & 63, qq = tid >> 6;
        float s = 0.f;
        #pragma unroll 8
        for (int m = 0; m < 32; ++m) s += h2f(lq[row][qq * 32 + m]) * kc[qq * 32 + m];
        zp[qq][row] = s;
    }
    __syncthreads();

    // Phase 2: out = Amask @ V + phiq @ Spre
    f4v o4[4] = {};
    #pragma unroll
    for (int k0 = 0; k0 < 64; k0 += 32) {
        h8v av = *(h8v*)&lA[w * 16 + lr][k0 + lg * 8];
        #pragma unroll
        for (int ct = 0; ct < 4; ++ct) {
            h8v bv = *(h8v*)&lvt[ct * 16 + lr][k0 + lg * 8];
            o4[ct] = __builtin_amdgcn_mfma_f32_16x16x32_f16(av, bv, o4[ct], 0, 0, 0);
        }
    }
    #pragma unroll
    for (int k0 = 0; k0 < 128; k0 += 32) {
        h8v av = *(h8v*)&lq[w * 16 + lr][k0 + lg * 8];
        #pragma unroll
        for (int ct = 0; ct < 4; ++ct) {
            h8v bv = *(h8v*)&lsp[ct * 16 + lr][k0 + lg * 8];
            o4[ct] = __builtin_amdgcn_mfma_f32_16x16x32_f16(av, bv, o4[ct], 0, 0, 0);
        }
    }
    #pragma unroll
    for (int rg = 0; rg < 4; ++rg) {
        const int row = w * 16 + lg * 4 + rg;
        const float z = zin[row] + zp[0][row] + zp[1][row] + zp[2][row] + zp[3][row] + 1e-6f;
        const float rz = 1.f / z;
        #pragma unroll
        for (int ct = 0; ct < 4; ++ct) {
            const int d = ct * 16 + lr;
            att_h[((size_t)(b * NN + n0 + row)) * DIMS + h * HDIM + d] = f2h(o4[ct][rg] * rz);
        }
    }
}

extern "C" void kernel_launch(void* const* d_in, const int* in_sizes, int n_in,
                              void* d_out, int out_size, void* d_ws, size_t ws_size,
                              hipStream_t stream) {
    const float* x     = (const float*)d_in[0];
    const float* omega = (const float*)d_in[1];
    const float* Wq    = (const float*)d_in[2];
    const float* Wk    = (const float*)d_in[3];
    const float* Wv    = (const float*)d_in[4];
    const float* Wo    = (const float*)d_in[5];
    const float* bo    = (const float*)d_in[6];
    float* out = (float*)d_out;

    float* ws = (float*)d_ws;
    const size_t PROJ = (size_t)BN * DIMS;                 // 2M elems
    const size_t PHI  = (size_t)BB * NHEADS * NN * NFEAT;  // 4M elems
    // fresh regions (ws is ~256 MiB; total here ~92 MB)
    float*  qkv     = ws;                                  // 6M f32  (24 MB)
    float*  logits  = qkv + (size_t)BN * QKVN;             // 4M f32  (16 MB), reused as ssum
    ushort* xh      = (ushort*)(logits + PHI);             // 2M u16  (4 MB)
    ushort* wqkvh   = xh + PROJ;                           // 3M u16  (6 MB)
    ushort* woh     = wqkvh + (size_t)QKVN * DIMS;         // 1M u16  (2 MB)
    ushort* phiq_h  = woh + WW;                            // 4M u16  (8 MB)
    ushort* phik_h  = phiq_h + PHI;                        // 8 MB
    ushort* phikT_h = phik_h + PHI;                        // 8 MB
    ushort* vt_h    = phikT_h + PHI;                       // 2M u16  (4 MB)
    ushort* spre_h  = vt_h + PROJ;                         // 8 MB
    ushort* att_hb  = spre_h + PHI;                        // 4 MB
    float*  kcsum   = (float*)(att_hb + PROJ);
    float*  kcpre   = kcsum + 32 * NCH * NFEAT;
    float*  blockmax= kcpre + 32 * NCH * NFEAT;
    float*  gmax    = blockmax + 512;
    float*  ssum    = logits;   // logits dead after phik_exp_t

    // casts (fp16)
    cast_h<<<(int)(PROJ / 8 + 255) / 256, 256, 0, stream>>>(x, xh, (int)(PROJ / 8));
    cast_h<<<(WW / 8 + 255) / 256, 256, 0, stream>>>(Wq, wqkvh, WW / 8);
    cast_h<<<(WW / 8 + 255) / 256, 256, 0, stream>>>(Wk, wqkvh + WW, WW / 8);
    cast_h<<<(WW / 8 + 255) / 256, 256, 0, stream>>>(Wv, wqkvh + 2 * (size_t)WW, WW / 8);
    cast_h<<<(WW / 8 + 255) / 256, 256, 0, stream>>>(Wo, woh, WW / 8);

    // fused QKV projection: C[2048 x 3072]
    dim3 gq(BN / 64, QKVN / 128);   // (32, 24)
    gemm_nt_mfma<<<gq, 256, 0, stream>>>(xh, wqkvh, qkv, nullptr, BN, QKVN, DIMS);

    dim3 pg(BN / PTILE, NHEADS);
    phi_gemm<<<pg, 256, 0, stream>>>(qkv,        QKVN, omega, phiq_h, nullptr, nullptr, 1);
    phi_gemm<<<pg, 256, 0, stream>>>(qkv + DIMS, QKVN, omega, nullptr, logits, blockmax, 0);
    reduce_max_kernel<<<1, 256, 0, stream>>>(blockmax, 512, gmax);

    dim3 cg(NCH, BB * NHEADS);
    phik_exp_t<<<cg, 256, 0, stream>>>(logits, gmax, phik_h, phikT_h);
    vt_cast<<<cg, 256, 0, stream>>>(qkv + 2 * DIMS, QKVN, vt_h);
    chunk_sums<<<cg, 256, 0, stream>>>(phikT_h, vt_h, ssum, kcsum);
    kc_prefix<<<BB * NHEADS, NFEAT, 0, stream>>>(kcsum, kcpre);
    chunk_prefix<<<dim3(4, BB * NHEADS), 256, 0, stream>>>(ssum, spre_h);
    scan_final<<<cg, 256, 0, stream>>>(phiq_h, phik_h, vt_h, spre_h, kcpre, att_hb);

    // output projection straight to d_out
    dim3 go(BN / 64, DIMS / 128);   // (32, 8)
    gemm_nt_mfma<<<go, 256, 0, stream>>>(att_hb, woh, out, bo, BN, DIMS, DIMS);
}

// Round 7
// 123.357 us; speedup vs baseline: 5.4154x; 1.1693x over previous
//
#include <hip/hip_runtime.h>
#include <hip/hip_bf16.h>
#include <math.h>

#define DIMS 1024
#define NHEADS 16
#define HDIM 64
#define NFEAT 128
#define BB 2
#define NN 1024
#define BN (BB*NN)   // 2048
#define NCH 16       // chunks per (b,h)
#define CSZ 64       // chunk size
#define WW (DIMS*DIMS)
#define QKVN (3*DIMS) // 3072

#define SCALE 0.3535533905932738f       // 64^-0.25
#define INV_SQRT_M 0.08838834764831845f // 1/sqrt(128)

typedef __attribute__((ext_vector_type(8))) _Float16 h8v;  // 8 fp16 (4 VGPRs)
typedef __attribute__((ext_vector_type(8))) short s8v;     // raw 16B
typedef __attribute__((ext_vector_type(4))) float f4v;     // mfma accumulator

__device__ __forceinline__ ushort f2h(float x) {
    _Float16 h = (_Float16)x;
    return *(ushort*)&h;
}
__device__ __forceinline__ float h2f(ushort u) {
    _Float16 h = *(_Float16*)&u;
    return (float)h;
}
__device__ __forceinline__ void gload16(const void* g, void* l) {
    __builtin_amdgcn_global_load_lds(
        (const __attribute__((address_space(1))) unsigned int*)g,
        (__attribute__((address_space(3))) unsigned int*)l,
        16, 0, 0);
}

// ---------------- fused cast f32 -> fp16 for all 5 tensors ----------------
#define NX (BN*DIMS/8)   // 262144 (x)
#define NW (WW/8)        // 131072 (each W)
__global__ __launch_bounds__(256) void cast_all(const float* __restrict__ x,
                                                const float* __restrict__ Wq,
                                                const float* __restrict__ Wk,
                                                const float* __restrict__ Wv,
                                                const float* __restrict__ Wo,
                                                ushort* __restrict__ xh,
                                                ushort* __restrict__ wqkvh,
                                                ushort* __restrict__ woh) {
    const int i = blockIdx.x * 256 + threadIdx.x;
    const float* src; ushort* dst; int off;
    if (i < NX)               { src = x;  dst = xh;                        off = i; }
    else if (i < NX + NW)     { src = Wq; dst = wqkvh;                     off = i - NX; }
    else if (i < NX + 2 * NW) { src = Wk; dst = wqkvh + WW;                off = i - NX - NW; }
    else if (i < NX + 3 * NW) { src = Wv; dst = wqkvh + 2 * (size_t)WW;    off = i - NX - 2 * NW; }
    else                      { src = Wo; dst = woh;                       off = i - NX - 3 * NW; }
    float4 a = ((const float4*)src)[2 * (size_t)off];
    float4 b = ((const float4*)src)[2 * (size_t)off + 1];
    float v[8] = {a.x, a.y, a.z, a.w, b.x, b.y, b.z, b.w};
    ushort h8[8];
    #pragma unroll
    for (int j = 0; j < 8; ++j) h8[j] = f2h(v[j]);
    *(s8v*)&dst[(size_t)off * 8] = *(s8v*)&h8[0];
}

// ---------------- MFMA GEMM NT, m97 structure (global_load_lds staging) ----------------
// C[i,j] = sum_k A[i,k]*B[j,k] (+bias). A:[M x K], B:[N x K] fp16 row-major. BN=128, BK=32.
template<int BM>
__global__ __launch_bounds__(256) void gemm_nt_lds(const ushort* __restrict__ A,
                                                   const ushort* __restrict__ B,
                                                   float* __restrict__ C,
                                                   const float* __restrict__ bias,
                                                   int M, int N, int K) {
    constexpr int MF = BM / 32;       // wave M-fragments (wave tile = BM/2 x 64)
    constexpr int AI = BM / 64;       // A stage issues per wave
    __shared__ __attribute__((aligned(16))) ushort lA[BM][32];
    __shared__ __attribute__((aligned(16))) ushort lB[128][32];
    const int tid = threadIdx.x;
    const int w = tid >> 6, l = tid & 63, lr = l & 15, lg = l >> 4;
    const int wm = (w >> 1) * (BM / 2), wn = (w & 1) * 64;
    const int bi = blockIdx.x * BM, bj = blockIdx.y * 128;
    const int srow = l >> 2, scol = (l & 3) * 8;   // lane's slot within a 16-row stage issue

    f4v acc[MF][4] = {};
    for (int k0 = 0; k0 < K; k0 += 32) {
        #pragma unroll
        for (int i = 0; i < AI; ++i) {
            const int r0 = w * (16 * AI) + i * 16;
            gload16(&A[(size_t)(bi + r0 + srow) * K + k0 + scol], &lA[r0][0]);
        }
        #pragma unroll
        for (int i = 0; i < 2; ++i) {
            const int r0 = w * 32 + i * 16;
            gload16(&B[(size_t)(bj + r0 + srow) * K + k0 + scol], &lB[r0][0]);
        }
        __syncthreads();
        h8v b_[4];
        #pragma unroll
        for (int j = 0; j < 4; ++j) b_[j] = *(h8v*)&lB[wn + j * 16 + lr][lg * 8];
        #pragma unroll
        for (int i = 0; i < MF; ++i) {
            h8v a_ = *(h8v*)&lA[wm + i * 16 + lr][lg * 8];
            #pragma unroll
            for (int j = 0; j < 4; ++j)
                acc[i][j] = __builtin_amdgcn_mfma_f32_16x16x32_f16(a_, b_[j], acc[i][j], 0, 0, 0);
        }
        __syncthreads();
    }
    #pragma unroll
    for (int i = 0; i < MF; ++i)
        #pragma unroll
        for (int j = 0; j < 4; ++j)
            #pragma unroll
            for (int rg = 0; rg < 4; ++rg) {
                const int row = bi + wm + i * 16 + lg * 4 + rg;
                const int col = bj + wn + j * 16 + lr;
                float r = acc[i][j][rg];
                if (bias) r += bias[col];
                C[(size_t)row * N + col] = r;
            }
}

// ---------------- phi (q and k fused via blockIdx.z) ----------------
#define PTILE 64
#define OMS (NFEAT + 4)
#define QS  (HDIM + 4)

__global__ __launch_bounds__(256) void phi_gemm(const float* __restrict__ qkv,
                                                const float* __restrict__ omega,
                                                ushort* __restrict__ out_h16,
                                                float* __restrict__ out_f32,
                                                float* __restrict__ blockmax) {
    __shared__ float omT[HDIM][OMS];
    __shared__ float qT[HDIM][QS];
    __shared__ float wred[4];
    const int tid = threadIdx.x;
    const int tx = tid & 15, ty = tid >> 4;
    const int h = blockIdx.y;
    const int bn0 = blockIdx.x * PTILE;
    const int is_query = (blockIdx.z == 0);
    const float* qsrc = qkv + (size_t)blockIdx.z * DIMS;

    #pragma unroll
    for (int i = 0; i < 8; ++i) {
        const int f = tid + 256 * i;
        const int m = f >> 4;
        const int d0 = (f & 15) << 2;
        float4 o = *(const float4*)&omega[m * HDIM + d0];
        omT[d0 + 0][m] = o.x; omT[d0 + 1][m] = o.y;
        omT[d0 + 2][m] = o.z; omT[d0 + 3][m] = o.w;
    }
    #pragma unroll
    for (int i = 0; i < 4; ++i) {
        const int f = tid + 256 * i;
        const int r = f >> 4;
        const int d0 = (f & 15) << 2;
        float4 qv = *(const float4*)&qsrc[(size_t)(bn0 + r) * QKVN + h * HDIM + d0];
        qT[d0 + 0][r] = qv.x * SCALE; qT[d0 + 1][r] = qv.y * SCALE;
        qT[d0 + 2][r] = qv.z * SCALE; qT[d0 + 3][r] = qv.w * SCALE;
    }
    __syncthreads();

    float c[4][8] = {};
    float nrm[4] = {};
    #pragma unroll 4
    for (int kd = 0; kd < HDIM; ++kd) {
        float4 qv = *(const float4*)&qT[kd][ty << 2];
        float4 o1 = *(const float4*)&omT[kd][tx << 3];
        float4 o2 = *(const float4*)&omT[kd][(tx << 3) + 4];
        float a_[4] = {qv.x, qv.y, qv.z, qv.w};
        float b_[8] = {o1.x, o1.y, o1.z, o1.w, o2.x, o2.y, o2.z, o2.w};
        #pragma unroll
        for (int i = 0; i < 4; ++i) {
            nrm[i] += a_[i] * a_[i];
            #pragma unroll
            for (int j = 0; j < 8; ++j) c[i][j] += a_[i] * b_[j];
        }
    }
    #pragma unroll
    for (int i = 0; i < 4; ++i) {
        const float nh = 0.5f * nrm[i];
        #pragma unroll
        for (int j = 0; j < 8; ++j) c[i][j] -= nh;
    }

    if (is_query) {
        #pragma unroll
        for (int i = 0; i < 4; ++i) {
            float mx = c[i][0];
            #pragma unroll
            for (int j = 1; j < 8; ++j) mx = fmaxf(mx, c[i][j]);
            #pragma unroll
            for (int o = 8; o >= 1; o >>= 1) mx = fmaxf(mx, __shfl_xor(mx, o));
            const int br = bn0 + (ty << 2) + i;
            const int b = br >> 10, n = br & (NN - 1);
            const size_t orow = ((size_t)(b * NHEADS + h) * NN + n) * NFEAT;
            ushort pk[8];
            #pragma unroll
            for (int j = 0; j < 8; ++j)
                pk[j] = f2h(expf(c[i][j] - mx) * INV_SQRT_M + 1e-4f);
            *(s8v*)&out_h16[orow + (tx << 3)] = *(s8v*)&pk[0];
        }
    } else {
        float mx = -3.4e38f;
        #pragma unroll
        for (int i = 0; i < 4; ++i) {
            const int br = bn0 + (ty << 2) + i;
            const int b = br >> 10, n = br & (NN - 1);
            const size_t orow = ((size_t)(b * NHEADS + h) * NN + n) * NFEAT;
            float4 r0 = {c[i][0], c[i][1], c[i][2], c[i][3]};
            float4 r1 = {c[i][4], c[i][5], c[i][6], c[i][7]};
            *(float4*)&out_f32[orow + (tx << 3)] = r0;
            *(float4*)&out_f32[orow + (tx << 3) + 4] = r1;
            #pragma unroll
            for (int j = 0; j < 8; ++j) mx = fmaxf(mx, c[i][j]);
        }
        #pragma unroll
        for (int o = 32; o >= 1; o >>= 1) mx = fmaxf(mx, __shfl_xor(mx, o));
        if ((tid & 63) == 0) wred[tid >> 6] = mx;
        __syncthreads();
        if (tid == 0)
            blockmax[blockIdx.y * gridDim.x + blockIdx.x] =
                fmaxf(fmaxf(wred[0], wred[1]), fmaxf(wred[2], wred[3]));
    }
}

__global__ __launch_bounds__(256) void reduce_max_kernel(const float* __restrict__ in,
                                                         int n, float* __restrict__ out) {
    float mx = -3.4e38f;
    for (int i = threadIdx.x; i < n; i += 256) mx = fmaxf(mx, in[i]);
    #pragma unroll
    for (int o = 32; o >= 1; o >>= 1) mx = fmaxf(mx, __shfl_xor(mx, o));
    __shared__ float r[4];
    if ((threadIdx.x & 63) == 0) r[threadIdx.x >> 6] = mx;
    __syncthreads();
    if (threadIdx.x == 0) out[0] = fmaxf(fmaxf(r[0], r[1]), fmaxf(r[2], r[3]));
}

// ---------------- phik exp + transpose, fused with V transpose+cast ----------------
__global__ __launch_bounds__(256) void phik_exp_vt(const float* __restrict__ logits,
                                                   const float* __restrict__ gmax,
                                                   const float* __restrict__ qkv,
                                                   ushort* __restrict__ phik,
                                                   ushort* __restrict__ phikT,
                                                   ushort* __restrict__ vt) {
    const int bh = blockIdx.y, n0 = blockIdx.x * CSZ;
    const int b = bh >> 4, h = bh & 15;
    const int tid = threadIdx.x;
    __shared__ __attribute__((aligned(16))) ushort lt[64][136];
    __shared__ float lv[64][65];
    const float gm = gmax[0];
    // phik logits -> exp
    {
        const int r = tid >> 2, c0 = (tid & 3) * 32;
        const size_t gbase = ((size_t)bh * NN + n0 + r) * NFEAT + c0;
        ushort tmp[32];
        #pragma unroll
        for (int i = 0; i < 8; ++i) {
            float4 v = *(const float4*)&logits[gbase + i * 4];
            tmp[i * 4 + 0] = f2h(expf(v.x - gm) * INV_SQRT_M + 1e-4f);
            tmp[i * 4 + 1] = f2h(expf(v.y - gm) * INV_SQRT_M + 1e-4f);
            tmp[i * 4 + 2] = f2h(expf(v.z - gm) * INV_SQRT_M + 1e-4f);
            tmp[i * 4 + 3] = f2h(expf(v.w - gm) * INV_SQRT_M + 1e-4f);
        }
        #pragma unroll
        for (int i = 0; i < 4; ++i) {
            *(s8v*)&phik[gbase + i * 8] = *(s8v*)&tmp[i * 8];
            *(s8v*)&lt[r][c0 + i * 8] = *(s8v*)&tmp[i * 8];
        }
    }
    // V rows -> LDS
    {
        const int r = tid >> 2, c0 = (tid & 3) * 16;
        #pragma unroll
        for (int i = 0; i < 4; ++i) {
            float4 q = *(const float4*)&qkv[((size_t)(b * NN + n0 + r)) * QKVN + 2 * DIMS + h * HDIM + c0 + i * 4];
            lv[r][c0 + i * 4 + 0] = q.x; lv[r][c0 + i * 4 + 1] = q.y;
            lv[r][c0 + i * 4 + 2] = q.z; lv[r][c0 + i * 4 + 3] = q.w;
        }
    }
    __syncthreads();
    // phikT
    {
        const int m = tid >> 1, nh = (tid & 1) * 32;
        ushort tp[32];
        #pragma unroll
        for (int i = 0; i < 32; ++i) tp[i] = lt[nh + i][m];
        const size_t tbase = ((size_t)bh * NFEAT + m) * NN + n0 + nh;
        #pragma unroll
        for (int i = 0; i < 4; ++i) *(s8v*)&phikT[tbase + i * 8] = *(s8v*)&tp[i * 8];
    }
    // vt
    {
        const int d = tid >> 2, s0 = (tid & 3) * 16;
        ushort tp[16];
        #pragma unroll
        for (int i = 0; i < 16; ++i) tp[i] = f2h(lv[s0 + i][d]);
        const size_t tb = ((size_t)bh * HDIM + d) * NN + n0 + s0;
        *(s8v*)&vt[tb] = *(s8v*)&tp[0];
        *(s8v*)&vt[tb + 8] = *(s8v*)&tp[8];
    }
}

// ---------------- per-chunk sums: SsumT[bh][c][d][m] = sum_n V[n,d]*phik[n,m] ----------------
__global__ __launch_bounds__(256) void chunk_sums(const ushort* __restrict__ phikT,
                                                  const ushort* __restrict__ vt,
                                                  float* __restrict__ ssum,
                                                  float* __restrict__ kcsum) {
    const int c = blockIdx.x, bh = blockIdx.y, n0 = c * CSZ;
    __shared__ __attribute__((aligned(16))) ushort lvt[64][72];
    __shared__ __attribute__((aligned(16))) ushort lkt[128][72];
    const int tid = threadIdx.x;
    {
        const int d = tid >> 2, s = (tid & 3) * 16;
        const size_t g = ((size_t)bh * HDIM + d) * NN + n0 + s;
        *(s8v*)&lvt[d][s]     = *(const s8v*)&vt[g];
        *(s8v*)&lvt[d][s + 8] = *(const s8v*)&vt[g + 8];
    }
    {
        const int m = tid >> 1, s = (tid & 1) * 32;
        const size_t g = ((size_t)bh * NFEAT + m) * NN + n0 + s;
        #pragma unroll
        for (int i = 0; i < 4; ++i) *(s8v*)&lkt[m][s + i * 8] = *(const s8v*)&phikT[g + i * 8];
    }
    __syncthreads();
    const int w = tid >> 6, l = tid & 63, lr = l & 15, lg = l >> 4;
    f4v acc[8] = {};
    #pragma unroll
    for (int k0 = 0; k0 < 64; k0 += 32) {
        h8v a = *(h8v*)&lvt[w * 16 + lr][k0 + lg * 8];
        #pragma unroll
        for (int ct = 0; ct < 8; ++ct) {
            h8v bf = *(h8v*)&lkt[ct * 16 + lr][k0 + lg * 8];
            acc[ct] = __builtin_amdgcn_mfma_f32_16x16x32_f16(a, bf, acc[ct], 0, 0, 0);
        }
    }
    const size_t obase = ((size_t)bh * NCH + c) * (HDIM * NFEAT);
    #pragma unroll
    for (int ct = 0; ct < 8; ++ct)
        #pragma unroll
        for (int rg = 0; rg < 4; ++rg) {
            const int d = w * 16 + lg * 4 + rg, m = ct * 16 + lr;
            ssum[obase + (size_t)d * NFEAT + m] = acc[ct][rg];
        }
    if (tid < 128) {
        float s = 0.f;
        #pragma unroll 8
        for (int i = 0; i < 64; ++i) s += h2f(lkt[tid][i]);
        kcsum[((size_t)bh * NCH + c) * NFEAT + tid] = s;
    }
}

// ---------------- prefix over chunks (Spre) + fused kc prefix ----------------
__global__ __launch_bounds__(256) void chunk_prefix(const float* __restrict__ ssum,
                                                    ushort* __restrict__ spre,
                                                    const float* __restrict__ kcsum,
                                                    float* __restrict__ kcpre) {
    const int bh = blockIdx.y, sl = blockIdx.x;
    const int tid = threadIdx.x;
    if (sl == 0 && tid < NFEAT) {
        float a = 0.f;
        for (int c = 0; c < NCH; ++c) {
            kcpre[((size_t)bh * NCH + c) * NFEAT + tid] = a;
            a += kcsum[((size_t)bh * NCH + c) * NFEAT + tid];
        }
    }
    const int base_e = sl * 2048 + tid;
    float acc[8] = {};
    const size_t bb = (size_t)bh * NCH * (HDIM * NFEAT);
    for (int c = 0; c < NCH; ++c) {
        const size_t cb = bb + (size_t)c * (HDIM * NFEAT);
        #pragma unroll
        for (int e = 0; e < 8; ++e) {
            spre[cb + base_e + e * 256] = f2h(acc[e]);
            acc[e] += ssum[cb + base_e + e * 256];
        }
    }
}

// ---------------- chunked causal attention via MFMA (att out fp16) ----------------
__global__ __launch_bounds__(256) void scan_final(const ushort* __restrict__ phiq,
                                                  const ushort* __restrict__ phik,
                                                  const ushort* __restrict__ vt,
                                                  const ushort* __restrict__ spre,
                                                  const float* __restrict__ kcpre,
                                                  ushort* __restrict__ att_h) {
    const int c = blockIdx.x, bh = blockIdx.y;
    const int b = bh >> 4, h = bh & 15;
    const int n0 = c * CSZ;
    __shared__ __attribute__((aligned(16))) ushort lq[64][136];
    __shared__ __attribute__((aligned(16))) ushort lk[64][136];
    __shared__ __attribute__((aligned(16))) ushort lvt[64][72];
    __shared__ __attribute__((aligned(16))) ushort lsp[64][136];
    __shared__ __attribute__((aligned(16))) ushort lA[64][72];
    __shared__ float kc[NFEAT];
    __shared__ float zin[64];
    __shared__ float zp[4][64];
    const int tid = threadIdx.x;

    const size_t qb = ((size_t)bh * NN + n0) * NFEAT;
    #pragma unroll
    for (int i = 0; i < 4; ++i) {
        const int idx = tid + 256 * i;
        const int r = idx >> 4, cs = (idx & 15) * 8;
        *(s8v*)&lq[r][cs] = *(const s8v*)&phiq[qb + (size_t)r * NFEAT + cs];
        *(s8v*)&lk[r][cs] = *(const s8v*)&phik[qb + (size_t)r * NFEAT + cs];
    }
    const size_t sb = ((size_t)bh * NCH + c) * (HDIM * NFEAT);
    #pragma unroll
    for (int i = 0; i < 4; ++i) {
        const int idx = tid + 256 * i;
        const int r = idx >> 4, cs = (idx & 15) * 8;
        *(s8v*)&lsp[r][cs] = *(const s8v*)&spre[sb + (size_t)r * NFEAT + cs];
    }
    {
        const int d = tid >> 2, s = (tid & 3) * 16;
        const size_t g = ((size_t)bh * HDIM + d) * NN + n0 + s;
        *(s8v*)&lvt[d][s]     = *(const s8v*)&vt[g];
        *(s8v*)&lvt[d][s + 8] = *(const s8v*)&vt[g + 8];
    }
    if (tid < NFEAT) kc[tid] = kcpre[((size_t)bh * NCH + c) * NFEAT + tid];
    __syncthreads();

    const int w = tid >> 6, l = tid & 63, lr = l & 15, lg = l >> 4;

    // Phase 1: A = phiq @ phik^T
    f4v a4[4] = {};
    #pragma unroll
    for (int k0 = 0; k0 < 128; k0 += 32) {
        h8v av = *(h8v*)&lq[w * 16 + lr][k0 + lg * 8];
        #pragma unroll
        for (int ct = 0; ct < 4; ++ct) {
            h8v bv = *(h8v*)&lk[ct * 16 + lr][k0 + lg * 8];
            a4[ct] = __builtin_amdgcn_mfma_f32_16x16x32_f16(av, bv, a4[ct], 0, 0, 0);
        }
    }
    float zi[4] = {0.f, 0.f, 0.f, 0.f};
    #pragma unroll
    for (int ct = 0; ct < 4; ++ct) {
        #pragma unroll
        for (int rg = 0; rg < 4; ++rg) {
            const int row = w * 16 + lg * 4 + rg;
            const int col = ct * 16 + lr;
            const float val = (col <= row) ? a4[ct][rg] : 0.f;
            const ushort hq = f2h(val);
            zi[rg] += h2f(hq);
            lA[row][col] = hq;
        }
    }
    #pragma unroll
    for (int rg = 0; rg < 4; ++rg) {
        float z = zi[rg];
        z += __shfl_xor(z, 1); z += __shfl_xor(z, 2);
        z += __shfl_xor(z, 4); z += __shfl_xor(z, 8);
        if (lr == 0) zin[w * 16 + lg * 4 + rg] = z;
    }
    {
        const int row = tid & 63, qq = tid >> 6;
        float s = 0.f;
        #pragma unroll 8
        for (int m = 0; m < 32; ++m) s += h2f(lq[row][qq * 32 + m]) * kc[qq * 32 + m];
        zp[qq][row] = s;
    }
    __syncthreads();

    // Phase 2: out = Amask @ V + phiq @ Spre
    f4v o4[4] = {};
    #pragma unroll
    for (int k0 = 0; k0 < 64; k0 += 32) {
        h8v av = *(h8v*)&lA[w * 16 + lr][k0 + lg * 8];
        #pragma unroll
        for (int ct = 0; ct < 4; ++ct) {
            h8v bv = *(h8v*)&lvt[ct * 16 + lr][k0 + lg * 8];
            o4[ct] = __builtin_amdgcn_mfma_f32_16x16x32_f16(av, bv, o4[ct], 0, 0, 0);
        }
    }
    #pragma unroll
    for (int k0 = 0; k0 < 128; k0 += 32) {
        h8v av = *(h8v*)&lq[w * 16 + lr][k0 + lg * 8];
        #pragma unroll
        for (int ct = 0; ct < 4; ++ct) {
            h8v bv = *(h8v*)&lsp[ct * 16 + lr][k0 + lg * 8];
            o4[ct] = __builtin_amdgcn_mfma_f32_16x16x32_f16(av, bv, o4[ct], 0, 0, 0);
        }
    }
    #pragma unroll
    for (int rg = 0; rg < 4; ++rg) {
        const int row = w * 16 + lg * 4 + rg;
        const float z = zin[row] + zp[0][row] + zp[1][row] + zp[2][row] + zp[3][row] + 1e-6f;
        const float rz = 1.f / z;
        #pragma unroll
        for (int ct = 0; ct < 4; ++ct) {
            const int d = ct * 16 + lr;
            att_h[((size_t)(b * NN + n0 + row)) * DIMS + h * HDIM + d] = f2h(o4[ct][rg] * rz);
        }
    }
}

extern "C" void kernel_launch(void* const* d_in, const int* in_sizes, int n_in,
                              void* d_out, int out_size, void* d_ws, size_t ws_size,
                              hipStream_t stream) {
    const float* x     = (const float*)d_in[0];
    const float* omega = (const float*)d_in[1];
    const float* Wq    = (const float*)d_in[2];
    const float* Wk    = (const float*)d_in[3];
    const float* Wv    = (const float*)d_in[4];
    const float* Wo    = (const float*)d_in[5];
    const float* bo    = (const float*)d_in[6];
    float* out = (float*)d_out;

    float* ws = (float*)d_ws;
    const size_t PROJ = (size_t)BN * DIMS;                 // 2M elems
    const size_t PHI  = (size_t)BB * NHEADS * NN * NFEAT;  // 4M elems
    float*  qkv     = ws;                                  // 6M f32  (24 MB)
    float*  logits  = qkv + (size_t)BN * QKVN;             // 4M f32  (16 MB), reused as ssum
    ushort* xh      = (ushort*)(logits + PHI);             // 4 MB
    ushort* wqkvh   = xh + PROJ;                           // 6 MB
    ushort* woh     = wqkvh + (size_t)QKVN * DIMS;         // 2 MB
    ushort* phiq_h  = woh + WW;                            // 8 MB
    ushort* phik_h  = phiq_h + PHI;                        // 8 MB
    ushort* phikT_h = phik_h + PHI;                        // 8 MB
    ushort* vt_h    = phikT_h + PHI;                       // 4 MB
    ushort* spre_h  = vt_h + PROJ;                         // 8 MB
    ushort* att_hb  = spre_h + PHI;                        // 4 MB
    float*  kcsum   = (float*)(att_hb + PROJ);
    float*  kcpre   = kcsum + 32 * NCH * NFEAT;
    float*  blockmax= kcpre + 32 * NCH * NFEAT;
    float*  gmax    = blockmax + 512;
    float*  ssum    = logits;   // logits dead after phik_exp_vt

    // 1: fused casts
    cast_all<<<(NX + 4 * NW) / 256, 256, 0, stream>>>(x, Wq, Wk, Wv, Wo, xh, wqkvh, woh);

    // 2: fused QKV projection C[2048 x 3072]
    dim3 gq(BN / 128, QKVN / 128);   // (16, 24)
    gemm_nt_lds<128><<<gq, 256, 0, stream>>>(xh, wqkvh, qkv, nullptr, BN, QKVN, DIMS);

    // 3: phi for q (z=0) and k (z=1)
    dim3 pg(BN / PTILE, NHEADS, 2);
    phi_gemm<<<pg, 256, 0, stream>>>(qkv, omega, phiq_h, logits, blockmax);

    // 4: global key max
    reduce_max_kernel<<<1, 256, 0, stream>>>(blockmax, 512, gmax);

    dim3 cg(NCH, BB * NHEADS);
    // 5: phik exp + transpose, fused V transpose+cast
    phik_exp_vt<<<cg, 256, 0, stream>>>(logits, gmax, qkv, phik_h, phikT_h, vt_h);
    // 6: per-chunk sums
    chunk_sums<<<cg, 256, 0, stream>>>(phikT_h, vt_h, ssum, kcsum);
    // 7: prefixes (Spre + kc)
    chunk_prefix<<<dim3(4, BB * NHEADS), 256, 0, stream>>>(ssum, spre_h, kcsum, kcpre);
    // 8: causal attention
    scan_final<<<cg, 256, 0, stream>>>(phiq_h, phik_h, vt_h, spre_h, kcpre, att_hb);

    // 9: output projection straight to d_out
    dim3 go(BN / 64, DIMS / 128);    // (32, 8)
    gemm_nt_lds<64><<<go, 256, 0, stream>>>(att_hb, woh, out, bo, BN, DIMS, DIMS);
}

// Round 8
// 105.805 us; speedup vs baseline: 6.3137x; 1.1659x over previous
//
#include <hip/hip_runtime.h>
#include <hip/hip_bf16.h>
#include <math.h>

#define DIMS 1024
#define NHEADS 16
#define HDIM 64
#define NFEAT 128
#define BB 2
#define NN 1024
#define BN (BB*NN)   // 2048
#define NCH 16       // chunks per (b,h)
#define CSZ 64       // chunk size
#define WW (DIMS*DIMS)
#define QKVN (3*DIMS) // 3072

#define SCALE 0.3535533905932738f       // 64^-0.25
#define INV_SQRT_M 0.08838834764831845f // 1/sqrt(128)

typedef __attribute__((ext_vector_type(8))) _Float16 h8v;  // 8 fp16 (4 VGPRs)
typedef __attribute__((ext_vector_type(8))) short s8v;     // raw 16B
typedef __attribute__((ext_vector_type(4))) float f4v;     // mfma accumulator

__device__ __forceinline__ ushort f2h(float x) {
    _Float16 h = (_Float16)x;
    return *(ushort*)&h;
}
__device__ __forceinline__ float h2f(ushort u) {
    _Float16 h = *(_Float16*)&u;
    return (float)h;
}
__device__ __forceinline__ void gload16(const void* g, void* l) {
    __builtin_amdgcn_global_load_lds(
        (const __attribute__((address_space(1))) unsigned int*)g,
        (__attribute__((address_space(3))) unsigned int*)l,
        16, 0, 0);
}

// ---------------- fused cast f32 -> fp16 for x, Wq,k,v, Wo, omega ----------------
#define NX (BN*DIMS/8)   // 262144
#define NW (WW/8)        // 131072
#define NOM (NFEAT*HDIM/8) // 1024
__global__ __launch_bounds__(256) void cast_all(const float* __restrict__ x,
                                                const float* __restrict__ Wq,
                                                const float* __restrict__ Wk,
                                                const float* __restrict__ Wv,
                                                const float* __restrict__ Wo,
                                                const float* __restrict__ omega,
                                                ushort* __restrict__ xh,
                                                ushort* __restrict__ wqkvh,
                                                ushort* __restrict__ woh,
                                                ushort* __restrict__ omh) {
    const int i = blockIdx.x * 256 + threadIdx.x;
    const float* src; ushort* dst; int off;
    if (i < NX)               { src = x;     dst = xh;                     off = i; }
    else if (i < NX + NW)     { src = Wq;    dst = wqkvh;                  off = i - NX; }
    else if (i < NX + 2 * NW) { src = Wk;    dst = wqkvh + WW;             off = i - NX - NW; }
    else if (i < NX + 3 * NW) { src = Wv;    dst = wqkvh + 2 * (size_t)WW; off = i - NX - 2 * NW; }
    else if (i < NX + 4 * NW) { src = Wo;    dst = woh;                    off = i - NX - 3 * NW; }
    else                      { src = omega; dst = omh;                    off = i - NX - 4 * NW; }
    float4 a = ((const float4*)src)[2 * (size_t)off];
    float4 b = ((const float4*)src)[2 * (size_t)off + 1];
    float v[8] = {a.x, a.y, a.z, a.w, b.x, b.y, b.z, b.w};
    ushort h8[8];
    #pragma unroll
    for (int j = 0; j < 8; ++j) h8[j] = f2h(v[j]);
    *(s8v*)&dst[(size_t)off * 8] = *(s8v*)&h8[0];
}

// ---------------- MFMA GEMM NT, m97 structure; HOUT: write fp16, else f32+bias ----------------
template<int BM, bool HOUT>
__global__ __launch_bounds__(256) void gemm_nt_lds(const ushort* __restrict__ A,
                                                   const ushort* __restrict__ B,
                                                   float* __restrict__ C,
                                                   ushort* __restrict__ C16,
                                                   const float* __restrict__ bias,
                                                   int M, int N, int K) {
    constexpr int MF = BM / 32;
    constexpr int AI = BM / 64;
    __shared__ __attribute__((aligned(16))) ushort lA[BM][32];
    __shared__ __attribute__((aligned(16))) ushort lB[128][32];
    const int tid = threadIdx.x;
    const int w = tid >> 6, l = tid & 63, lr = l & 15, lg = l >> 4;
    const int wm = (w >> 1) * (BM / 2), wn = (w & 1) * 64;
    const int bi = blockIdx.x * BM, bj = blockIdx.y * 128;
    const int srow = l >> 2, scol = (l & 3) * 8;

    f4v acc[MF][4] = {};
    for (int k0 = 0; k0 < K; k0 += 32) {
        #pragma unroll
        for (int i = 0; i < AI; ++i) {
            const int r0 = w * (16 * AI) + i * 16;
            gload16(&A[(size_t)(bi + r0 + srow) * K + k0 + scol], &lA[r0][0]);
        }
        #pragma unroll
        for (int i = 0; i < 2; ++i) {
            const int r0 = w * 32 + i * 16;
            gload16(&B[(size_t)(bj + r0 + srow) * K + k0 + scol], &lB[r0][0]);
        }
        __syncthreads();
        h8v b_[4];
        #pragma unroll
        for (int j = 0; j < 4; ++j) b_[j] = *(h8v*)&lB[wn + j * 16 + lr][lg * 8];
        #pragma unroll
        for (int i = 0; i < MF; ++i) {
            h8v a_ = *(h8v*)&lA[wm + i * 16 + lr][lg * 8];
            #pragma unroll
            for (int j = 0; j < 4; ++j)
                acc[i][j] = __builtin_amdgcn_mfma_f32_16x16x32_f16(a_, b_[j], acc[i][j], 0, 0, 0);
        }
        __syncthreads();
    }
    #pragma unroll
    for (int i = 0; i < MF; ++i)
        #pragma unroll
        for (int j = 0; j < 4; ++j)
            #pragma unroll
            for (int rg = 0; rg < 4; ++rg) {
                const int row = bi + wm + i * 16 + lg * 4 + rg;
                const int col = bj + wn + j * 16 + lr;
                if (HOUT) {
                    C16[(size_t)row * N + col] = f2h(acc[i][j][rg]);
                } else {
                    float r = acc[i][j][rg] + bias[col];
                    C[(size_t)row * N + col] = r;
                }
            }
}

// ---------------- phi via MFMA: grid (BN/64, NHEADS, 2{q,k}) ----------------
// logit = SCALE*(q.w) - 0.5*SCALE^2*|q|^2 ; q path: rowmax+exp -> phiq fp16
// k path: f32 logits + blockmax.
__global__ __launch_bounds__(256) void phi_mfma(const ushort* __restrict__ qkvh,
                                                const ushort* __restrict__ omh,
                                                ushort* __restrict__ phiq,
                                                float* __restrict__ logits,
                                                float* __restrict__ blockmax) {
    __shared__ __attribute__((aligned(16))) ushort lq[64][72];
    __shared__ __attribute__((aligned(16))) ushort lbuf[128 * 72]; // omega; reused as out staging [64][136]
    __shared__ float lnorm[64];
    __shared__ float wred[4];
    const int tid = threadIdx.x;
    const int z = blockIdx.z, h = blockIdx.y;
    const int bn0 = blockIdx.x * 64;
    const int w = tid >> 6, l = tid & 63, lr = l & 15, lg = l >> 4;

    // q tile load + per-row |q|^2
    {
        const int r = tid >> 2, c0 = (tid & 3) * 16;
        const size_t g = (size_t)(bn0 + r) * QKVN + (size_t)z * DIMS + h * HDIM + c0;
        s8v v0 = *(const s8v*)&qkvh[g];
        s8v v1 = *(const s8v*)&qkvh[g + 8];
        *(s8v*)&lq[r][c0] = v0;
        *(s8v*)&lq[r][c0 + 8] = v1;
        float p = 0.f;
        #pragma unroll
        for (int j = 0; j < 8; ++j) {
            float a = h2f(((ushort*)&v0)[j]); p += a * a;
            float b = h2f(((ushort*)&v1)[j]); p += b * b;
        }
        p += __shfl_xor(p, 1); p += __shfl_xor(p, 2);
        if ((tid & 3) == 0) lnorm[r] = p;
    }
    // omega load [128][64] -> lbuf stride 72
    {
        const int m = tid >> 1, c0 = (tid & 1) * 32;
        #pragma unroll
        for (int i = 0; i < 4; ++i)
            *(s8v*)&lbuf[m * 72 + c0 + i * 8] = *(const s8v*)&omh[m * HDIM + c0 + i * 8];
    }
    __syncthreads();

    f4v acc[8] = {};
    #pragma unroll
    for (int k0 = 0; k0 < 64; k0 += 32) {
        h8v a = *(h8v*)&lq[w * 16 + lr][k0 + lg * 8];
        #pragma unroll
        for (int ct = 0; ct < 8; ++ct) {
            h8v b = *(h8v*)&lbuf[(ct * 16 + lr) * 72 + k0 + lg * 8];
            acc[ct] = __builtin_amdgcn_mfma_f32_16x16x32_f16(a, b, acc[ct], 0, 0, 0);
        }
    }
    __syncthreads();   // all waves done reading lbuf (omega)

    const float hs2 = 0.5f * SCALE * SCALE;
    if (z == 0) {
        // query: row max over 128 cols, exp, stage to lbuf[64][136], coalesced store
        #pragma unroll
        for (int rg = 0; rg < 4; ++rg) {
            const int row = w * 16 + lg * 4 + rg;
            const float nh = hs2 * lnorm[row];
            float lv[8];
            float mx = -3.4e38f;
            #pragma unroll
            for (int ct = 0; ct < 8; ++ct) {
                lv[ct] = SCALE * acc[ct][rg] - nh;
                mx = fmaxf(mx, lv[ct]);
            }
            #pragma unroll
            for (int o = 8; o >= 1; o >>= 1) mx = fmaxf(mx, __shfl_xor(mx, o));
            #pragma unroll
            for (int ct = 0; ct < 8; ++ct)
                lbuf[row * 136 + ct * 16 + lr] = f2h(expf(lv[ct] - mx) * INV_SQRT_M + 1e-4f);
        }
        __syncthreads();
        const int r = tid >> 2, c0 = (tid & 3) * 32;
        const int br = bn0 + r;
        const int b = br >> 10, n = br & (NN - 1);
        const size_t orow = ((size_t)(b * NHEADS + h) * NN + n) * NFEAT;
        #pragma unroll
        for (int i = 0; i < 4; ++i)
            *(s8v*)&phiq[orow + c0 + i * 8] = *(s8v*)&lbuf[r * 136 + c0 + i * 8];
    } else {
        // key: f32 logits + block max
        float bmax = -3.4e38f;
        #pragma unroll
        for (int rg = 0; rg < 4; ++rg) {
            const int row = w * 16 + lg * 4 + rg;
            const float nh = hs2 * lnorm[row];
            const int br = bn0 + row;
            const int b = br >> 10, n = br & (NN - 1);
            const size_t orow = ((size_t)(b * NHEADS + h) * NN + n) * NFEAT;
            #pragma unroll
            for (int ct = 0; ct < 8; ++ct) {
                const float v = SCALE * acc[ct][rg] - nh;
                logits[orow + ct * 16 + lr] = v;
                bmax = fmaxf(bmax, v);
            }
        }
        #pragma unroll
        for (int o = 32; o >= 1; o >>= 1) bmax = fmaxf(bmax, __shfl_xor(bmax, o));
        if (l == 0) wred[w] = bmax;
        __syncthreads();
        if (tid == 0)
            blockmax[h * gridDim.x + blockIdx.x] =
                fmaxf(fmaxf(wred[0], wred[1]), fmaxf(wred[2], wred[3]));
    }
}

// ---------------- phik exp + transpose + V transpose; gmax reduced inline ----------------
__global__ __launch_bounds__(256) void phik_exp_vt(const float* __restrict__ logits,
                                                   const float* __restrict__ blockmax,
                                                   const ushort* __restrict__ qkvh,
                                                   ushort* __restrict__ phik,
                                                   ushort* __restrict__ phikT,
                                                   ushort* __restrict__ vt) {
    const int bh = blockIdx.y, n0 = blockIdx.x * CSZ;
    const int b = bh >> 4, h = bh & 15;
    const int tid = threadIdx.x;
    const int w = tid >> 6, l = tid & 63;
    __shared__ __attribute__((aligned(16))) ushort lt[64][136];
    __shared__ __attribute__((aligned(16))) ushort lv[64][72];
    __shared__ float gred[4];
    // inline global max over 512 block maxes
    float mx = fmaxf(blockmax[tid], blockmax[tid + 256]);
    #pragma unroll
    for (int o = 32; o >= 1; o >>= 1) mx = fmaxf(mx, __shfl_xor(mx, o));
    if (l == 0) gred[w] = mx;
    // V rows -> LDS (fp16 passthrough)
    {
        const int r = tid >> 2, c0 = (tid & 3) * 16;
        const size_t g = (size_t)(b * NN + n0 + r) * QKVN + 2 * DIMS + h * HDIM + c0;
        *(s8v*)&lv[r][c0]     = *(const s8v*)&qkvh[g];
        *(s8v*)&lv[r][c0 + 8] = *(const s8v*)&qkvh[g + 8];
    }
    __syncthreads();
    const float gm = fmaxf(fmaxf(gred[0], gred[1]), fmaxf(gred[2], gred[3]));
    // phik logits -> exp
    {
        const int r = tid >> 2, c0 = (tid & 3) * 32;
        const size_t gbase = ((size_t)bh * NN + n0 + r) * NFEAT + c0;
        ushort tmp[32];
        #pragma unroll
        for (int i = 0; i < 8; ++i) {
            float4 v = *(const float4*)&logits[gbase + i * 4];
            tmp[i * 4 + 0] = f2h(expf(v.x - gm) * INV_SQRT_M + 1e-4f);
            tmp[i * 4 + 1] = f2h(expf(v.y - gm) * INV_SQRT_M + 1e-4f);
            tmp[i * 4 + 2] = f2h(expf(v.z - gm) * INV_SQRT_M + 1e-4f);
            tmp[i * 4 + 3] = f2h(expf(v.w - gm) * INV_SQRT_M + 1e-4f);
        }
        #pragma unroll
        for (int i = 0; i < 4; ++i) {
            *(s8v*)&phik[gbase + i * 8] = *(s8v*)&tmp[i * 8];
            *(s8v*)&lt[r][c0 + i * 8] = *(s8v*)&tmp[i * 8];
        }
    }
    __syncthreads();
    // phikT
    {
        const int m = tid >> 1, nh = (tid & 1) * 32;
        ushort tp[32];
        #pragma unroll
        for (int i = 0; i < 32; ++i) tp[i] = lt[nh + i][m];
        const size_t tbase = ((size_t)bh * NFEAT + m) * NN + n0 + nh;
        #pragma unroll
        for (int i = 0; i < 4; ++i) *(s8v*)&phikT[tbase + i * 8] = *(s8v*)&tp[i * 8];
    }
    // vt
    {
        const int d = tid >> 2, s0 = (tid & 3) * 16;
        ushort tp[16];
        #pragma unroll
        for (int i = 0; i < 16; ++i) tp[i] = lv[s0 + i][d];
        const size_t tb = ((size_t)bh * HDIM + d) * NN + n0 + s0;
        *(s8v*)&vt[tb] = *(s8v*)&tp[0];
        *(s8v*)&vt[tb + 8] = *(s8v*)&tp[8];
    }
}

// ---------------- per-chunk sums ----------------
__global__ __launch_bounds__(256) void chunk_sums(const ushort* __restrict__ phikT,
                                                  const ushort* __restrict__ vt,
                                                  float* __restrict__ ssum,
                                                  float* __restrict__ kcsum) {
    const int c = blockIdx.x, bh = blockIdx.y, n0 = c * CSZ;
    __shared__ __attribute__((aligned(16))) ushort lvt[64][72];
    __shared__ __attribute__((aligned(16))) ushort lkt[128][72];
    const int tid = threadIdx.x;
    {
        const int d = tid >> 2, s = (tid & 3) * 16;
        const size_t g = ((size_t)bh * HDIM + d) * NN + n0 + s;
        *(s8v*)&lvt[d][s]     = *(const s8v*)&vt[g];
        *(s8v*)&lvt[d][s + 8] = *(const s8v*)&vt[g + 8];
    }
    {
        const int m = tid >> 1, s = (tid & 1) * 32;
        const size_t g = ((size_t)bh * NFEAT + m) * NN + n0 + s;
        #pragma unroll
        for (int i = 0; i < 4; ++i) *(s8v*)&lkt[m][s + i * 8] = *(const s8v*)&phikT[g + i * 8];
    }
    __syncthreads();
    const int w = tid >> 6, l = tid & 63, lr = l & 15, lg = l >> 4;
    f4v acc[8] = {};
    #pragma unroll
    for (int k0 = 0; k0 < 64; k0 += 32) {
        h8v a = *(h8v*)&lvt[w * 16 + lr][k0 + lg * 8];
        #pragma unroll
        for (int ct = 0; ct < 8; ++ct) {
            h8v bf = *(h8v*)&lkt[ct * 16 + lr][k0 + lg * 8];
            acc[ct] = __builtin_amdgcn_mfma_f32_16x16x32_f16(a, bf, acc[ct], 0, 0, 0);
        }
    }
    const size_t obase = ((size_t)bh * NCH + c) * (HDIM * NFEAT);
    #pragma unroll
    for (int ct = 0; ct < 8; ++ct)
        #pragma unroll
        for (int rg = 0; rg < 4; ++rg) {
            const int d = w * 16 + lg * 4 + rg, m = ct * 16 + lr;
            ssum[obase + (size_t)d * NFEAT + m] = acc[ct][rg];
        }
    if (tid < 128) {
        float s = 0.f;
        #pragma unroll 8
        for (int i = 0; i < 64; ++i) s += h2f(lkt[tid][i]);
        kcsum[((size_t)bh * NCH + c) * NFEAT + tid] = s;
    }
}

// ---------------- prefix over chunks (Spre) + fused kc prefix ----------------
__global__ __launch_bounds__(256) void chunk_prefix(const float* __restrict__ ssum,
                                                    ushort* __restrict__ spre,
                                                    const float* __restrict__ kcsum,
                                                    float* __restrict__ kcpre) {
    const int bh = blockIdx.y, sl = blockIdx.x;
    const int tid = threadIdx.x;
    if (sl == 0 && tid < NFEAT) {
        float a = 0.f;
        for (int c = 0; c < NCH; ++c) {
            kcpre[((size_t)bh * NCH + c) * NFEAT + tid] = a;
            a += kcsum[((size_t)bh * NCH + c) * NFEAT + tid];
        }
    }
    const int base_e = sl * 2048 + tid;
    float acc[8] = {};
    const size_t bb = (size_t)bh * NCH * (HDIM * NFEAT);
    for (int c = 0; c < NCH; ++c) {
        const size_t cb = bb + (size_t)c * (HDIM * NFEAT);
        #pragma unroll
        for (int e = 0; e < 8; ++e) {
            spre[cb + base_e + e * 256] = f2h(acc[e]);
            acc[e] += ssum[cb + base_e + e * 256];
        }
    }
}

// ---------------- chunked causal attention via MFMA (att out fp16) ----------------
__global__ __launch_bounds__(256) void scan_final(const ushort* __restrict__ phiq,
                                                  const ushort* __restrict__ phik,
                                                  const ushort* __restrict__ vt,
                                                  const ushort* __restrict__ spre,
                                                  const float* __restrict__ kcpre,
                                                  ushort* __restrict__ att_h) {
    const int c = blockIdx.x, bh = blockIdx.y;
    const int b = bh >> 4, h = bh & 15;
    const int n0 = c * CSZ;
    __shared__ __attribute__((aligned(16))) ushort lq[64][136];
    __shared__ __attribute__((aligned(16))) ushort lk[64][136];
    __shared__ __attribute__((aligned(16))) ushort lvt[64][72];
    __shared__ __attribute__((aligned(16))) ushort lsp[64][136];
    __shared__ __attribute__((aligned(16))) ushort lA[64][72];
    __shared__ float kc[NFEAT];
    __shared__ float zin[64];
    __shared__ float zp[4][64];
    const int tid = threadIdx.x;

    const size_t qb = ((size_t)bh * NN + n0) * NFEAT;
    #pragma unroll
    for (int i = 0; i < 4; ++i) {
        const int idx = tid + 256 * i;
        const int r = idx >> 4, cs = (idx & 15) * 8;
        *(s8v*)&lq[r][cs] = *(const s8v*)&phiq[qb + (size_t)r * NFEAT + cs];
        *(s8v*)&lk[r][cs] = *(const s8v*)&phik[qb + (size_t)r * NFEAT + cs];
    }
    const size_t sb = ((size_t)bh * NCH + c) * (HDIM * NFEAT);
    #pragma unroll
    for (int i = 0; i < 4; ++i) {
        const int idx = tid + 256 * i;
        const int r = idx >> 4, cs = (idx & 15) * 8;
        *(s8v*)&lsp[r][cs] = *(const s8v*)&spre[sb + (size_t)r * NFEAT + cs];
    }
    {
        const int d = tid >> 2, s = (tid & 3) * 16;
        const size_t g = ((size_t)bh * HDIM + d) * NN + n0 + s;
        *(s8v*)&lvt[d][s]     = *(const s8v*)&vt[g];
        *(s8v*)&lvt[d][s + 8] = *(const s8v*)&vt[g + 8];
    }
    if (tid < NFEAT) kc[tid] = kcpre[((size_t)bh * NCH + c) * NFEAT + tid];
    __syncthreads();

    const int w = tid >> 6, l = tid & 63, lr = l & 15, lg = l >> 4;

    // Phase 1: A = phiq @ phik^T
    f4v a4[4] = {};
    #pragma unroll
    for (int k0 = 0; k0 < 128; k0 += 32) {
        h8v av = *(h8v*)&lq[w * 16 + lr][k0 + lg * 8];
        #pragma unroll
        for (int ct = 0; ct < 4; ++ct) {
            h8v bv = *(h8v*)&lk[ct * 16 + lr][k0 + lg * 8];
            a4[ct] = __builtin_amdgcn_mfma_f32_16x16x32_f16(av, bv, a4[ct], 0, 0, 0);
        }
    }
    float zi[4] = {0.f, 0.f, 0.f, 0.f};
    #pragma unroll
    for (int ct = 0; ct < 4; ++ct) {
        #pragma unroll
        for (int rg = 0; rg < 4; ++rg) {
            const int row = w * 16 + lg * 4 + rg;
            const int col = ct * 16 + lr;
            const float val = (col <= row) ? a4[ct][rg] : 0.f;
            const ushort hq = f2h(val);
            zi[rg] += h2f(hq);
            lA[row][col] = hq;
        }
    }
    #pragma unroll
    for (int rg = 0; rg < 4; ++rg) {
        float z = zi[rg];
        z += __shfl_xor(z, 1); z += __shfl_xor(z, 2);
        z += __shfl_xor(z, 4); z += __shfl_xor(z, 8);
        if (lr == 0) zin[w * 16 + lg * 4 + rg] = z;
    }
    {
        const int row = tid & 63, qq = tid >> 6;
        float s = 0.f;
        #pragma unroll 8
        for (int m = 0; m < 32; ++m) s += h2f(lq[row][qq * 32 + m]) * kc[qq * 32 + m];
        zp[qq][row] = s;
    }
    __syncthreads();

    // Phase 2: out = Amask @ V + phiq @ Spre
    f4v o4[4] = {};
    #pragma unroll
    for (int k0 = 0; k0 < 64; k0 += 32) {
        h8v av = *(h8v*)&lA[w * 16 + lr][k0 + lg * 8];
        #pragma unroll
        for (int ct = 0; ct < 4; ++ct) {
            h8v bv = *(h8v*)&lvt[ct * 16 + lr][k0 + lg * 8];
            o4[ct] = __builtin_amdgcn_mfma_f32_16x16x32_f16(av, bv, o4[ct], 0, 0, 0);
        }
    }
    #pragma unroll
    for (int k0 = 0; k0 < 128; k0 += 32) {
        h8v av = *(h8v*)&lq[w * 16 + lr][k0 + lg * 8];
        #pragma unroll
        for (int ct = 0; ct < 4; ++ct) {
            h8v bv = *(h8v*)&lsp[ct * 16 + lr][k0 + lg * 8];
            o4[ct] = __builtin_amdgcn_mfma_f32_16x16x32_f16(av, bv, o4[ct], 0, 0, 0);
        }
    }
    #pragma unroll
    for (int rg = 0; rg < 4; ++rg) {
        const int row = w * 16 + lg * 4 + rg;
        const float z = zin[row] + zp[0][row] + zp[1][row] + zp[2][row] + zp[3][row] + 1e-6f;
        const float rz = 1.f / z;
        #pragma unroll
        for (int ct = 0; ct < 4; ++ct) {
            const int d = ct * 16 + lr;
            att_h[((size_t)(b * NN + n0 + row)) * DIMS + h * HDIM + d] = f2h(o4[ct][rg] * rz);
        }
    }
}

extern "C" void kernel_launch(void* const* d_in, const int* in_sizes, int n_in,
                              void* d_out, int out_size, void* d_ws, size_t ws_size,
                              hipStream_t stream) {
    const float* x     = (const float*)d_in[0];
    const float* omega = (const float*)d_in[1];
    const float* Wq    = (const float*)d_in[2];
    const float* Wk    = (const float*)d_in[3];
    const float* Wv    = (const float*)d_in[4];
    const float* Wo    = (const float*)d_in[5];
    const float* bo    = (const float*)d_in[6];
    float* out = (float*)d_out;

    float* ws = (float*)d_ws;
    const size_t PROJ = (size_t)BN * DIMS;                 // 2M elems
    const size_t PHI  = (size_t)BB * NHEADS * NN * NFEAT;  // 4M elems
    ushort* qkvh    = (ushort*)ws;                         // 6M u16 (12 MB)
    float*  logits  = (float*)(qkvh + (size_t)BN * QKVN);  // 4M f32 (16 MB), reused as ssum
    ushort* xh      = (ushort*)(logits + PHI);             // 4 MB
    ushort* wqkvh   = xh + PROJ;                           // 6 MB
    ushort* woh     = wqkvh + (size_t)QKVN * DIMS;         // 2 MB
    ushort* omh     = woh + WW;                            // 16 KB
    ushort* phiq_h  = omh + NFEAT * HDIM;                  // 8 MB
    ushort* phik_h  = phiq_h + PHI;                        // 8 MB
    ushort* phikT_h = phik_h + PHI;                        // 8 MB
    ushort* vt_h    = phikT_h + PHI;                       // 4 MB
    ushort* spre_h  = vt_h + PROJ;                         // 8 MB
    ushort* att_hb  = spre_h + PHI;                        // 4 MB
    float*  kcsum   = (float*)(att_hb + PROJ);
    float*  kcpre   = kcsum + 32 * NCH * NFEAT;
    float*  blockmax= kcpre + 32 * NCH * NFEAT;
    float*  ssum    = logits;   // logits dead after phik_exp_vt

    // 1: fused casts (x, Wq,k,v, Wo, omega)
    cast_all<<<(NX + 4 * NW + NOM) / 256, 256, 0, stream>>>(x, Wq, Wk, Wv, Wo, omega,
                                                            xh, wqkvh, woh, omh);

    // 2: fused QKV projection -> fp16 [2048 x 3072]
    dim3 gq(BN / 128, QKVN / 128);   // (16, 24)
    gemm_nt_lds<128, true><<<gq, 256, 0, stream>>>(xh, wqkvh, nullptr, qkvh, nullptr,
                                                   BN, QKVN, DIMS);

    // 3: phi via MFMA, q (z=0) and k (z=1)
    dim3 pg(BN / 64, NHEADS, 2);     // (32, 16, 2)
    phi_mfma<<<pg, 256, 0, stream>>>(qkvh, omh, phiq_h, logits, blockmax);

    dim3 cg(NCH, BB * NHEADS);
    // 4: phik exp + transposes (gmax inline)
    phik_exp_vt<<<cg, 256, 0, stream>>>(logits, blockmax, qkvh, phik_h, phikT_h, vt_h);
    // 5: per-chunk sums
    chunk_sums<<<cg, 256, 0, stream>>>(phikT_h, vt_h, ssum, kcsum);
    // 6: prefixes (Spre + kc)
    chunk_prefix<<<dim3(4, BB * NHEADS), 256, 0, stream>>>(ssum, spre_h, kcsum, kcpre);
    // 7: causal attention
    scan_final<<<cg, 256, 0, stream>>>(phiq_h, phik_h, vt_h, spre_h, kcpre, att_hb);

    // 8: output projection straight to d_out
    dim3 go(BN / 64, DIMS / 128);    // (32, 8)
    gemm_nt_lds<64, false><<<go, 256, 0, stream>>>(att_hb, woh, out, nullptr, bo,
                                                   BN, DIMS, DIMS);
}

// Round 9
// 96.708 us; speedup vs baseline: 6.9076x; 1.0941x over previous
//
#include <hip/hip_runtime.h>
#include <hip/hip_bf16.h>
#include <math.h>

#define DIMS 1024
#define NHEADS 16
#define HDIM 64
#define NFEAT 128
#define BB 2
#define NN 1024
#define BN (BB*NN)   // 2048
#define NCH 16       // chunks per (b,h)
#define CSZ 64       // chunk size
#define WW (DIMS*DIMS)
#define QKVN (3*DIMS) // 3072

#define SCALE 0.3535533905932738f       // 64^-0.25
#define INV_SQRT_M 0.08838834764831845f // 1/sqrt(128)

typedef __attribute__((ext_vector_type(8))) _Float16 h8v;  // 8 fp16 (4 VGPRs)
typedef __attribute__((ext_vector_type(8))) short s8v;     // raw 16B
typedef __attribute__((ext_vector_type(4))) float f4v;     // mfma accumulator

__device__ __forceinline__ ushort f2h(float x) {
    _Float16 h = (_Float16)x;
    return *(ushort*)&h;
}
__device__ __forceinline__ float h2f(ushort u) {
    _Float16 h = *(_Float16*)&u;
    return (float)h;
}
__device__ __forceinline__ void gload16(const void* g, void* l) {
    __builtin_amdgcn_global_load_lds(
        (const __attribute__((address_space(1))) unsigned int*)g,
        (__attribute__((address_space(3))) unsigned int*)l,
        16, 0, 0);
}

// ---------------- fused cast f32 -> fp16 for x, Wq,k,v, Wo, omega ----------------
#define NX (BN*DIMS/8)   // 262144
#define NW (WW/8)        // 131072
#define NOM (NFEAT*HDIM/8) // 1024
__global__ __launch_bounds__(256) void cast_all(const float* __restrict__ x,
                                                const float* __restrict__ Wq,
                                                const float* __restrict__ Wk,
                                                const float* __restrict__ Wv,
                                                const float* __restrict__ Wo,
                                                const float* __restrict__ omega,
                                                ushort* __restrict__ xh,
                                                ushort* __restrict__ wqkvh,
                                                ushort* __restrict__ woh,
                                                ushort* __restrict__ omh) {
    const int i = blockIdx.x * 256 + threadIdx.x;
    const float* src; ushort* dst; int off;
    if (i < NX)               { src = x;     dst = xh;                     off = i; }
    else if (i < NX + NW)     { src = Wq;    dst = wqkvh;                  off = i - NX; }
    else if (i < NX + 2 * NW) { src = Wk;    dst = wqkvh + WW;             off = i - NX - NW; }
    else if (i < NX + 3 * NW) { src = Wv;    dst = wqkvh + 2 * (size_t)WW; off = i - NX - 2 * NW; }
    else if (i < NX + 4 * NW) { src = Wo;    dst = woh;                    off = i - NX - 3 * NW; }
    else                      { src = omega; dst = omh;                    off = i - NX - 4 * NW; }
    float4 a = ((const float4*)src)[2 * (size_t)off];
    float4 b = ((const float4*)src)[2 * (size_t)off + 1];
    float v[8] = {a.x, a.y, a.z, a.w, b.x, b.y, b.z, b.w};
    ushort h8[8];
    #pragma unroll
    for (int j = 0; j < 8; ++j) h8[j] = f2h(v[j]);
    *(s8v*)&dst[(size_t)off * 8] = *(s8v*)&h8[0];
}

// ---------------- MFMA GEMM NT, m97 structure; HOUT: write fp16, else f32+bias ----------------
template<int BM, bool HOUT>
__global__ __launch_bounds__(256) void gemm_nt_lds(const ushort* __restrict__ A,
                                                   const ushort* __restrict__ B,
                                                   float* __restrict__ C,
                                                   ushort* __restrict__ C16,
                                                   const float* __restrict__ bias,
                                                   int M, int N, int K) {
    constexpr int MF = BM / 32;
    constexpr int AI = BM / 64;
    __shared__ __attribute__((aligned(16))) ushort lA[BM][32];
    __shared__ __attribute__((aligned(16))) ushort lB[128][32];
    const int tid = threadIdx.x;
    const int w = tid >> 6, l = tid & 63, lr = l & 15, lg = l >> 4;
    const int wm = (w >> 1) * (BM / 2), wn = (w & 1) * 64;
    const int bi = blockIdx.x * BM, bj = blockIdx.y * 128;
    const int srow = l >> 2, scol = (l & 3) * 8;

    f4v acc[MF][4] = {};
    for (int k0 = 0; k0 < K; k0 += 32) {
        #pragma unroll
        for (int i = 0; i < AI; ++i) {
            const int r0 = w * (16 * AI) + i * 16;
            gload16(&A[(size_t)(bi + r0 + srow) * K + k0 + scol], &lA[r0][0]);
        }
        #pragma unroll
        for (int i = 0; i < 2; ++i) {
            const int r0 = w * 32 + i * 16;
            gload16(&B[(size_t)(bj + r0 + srow) * K + k0 + scol], &lB[r0][0]);
        }
        __syncthreads();
        h8v b_[4];
        #pragma unroll
        for (int j = 0; j < 4; ++j) b_[j] = *(h8v*)&lB[wn + j * 16 + lr][lg * 8];
        #pragma unroll
        for (int i = 0; i < MF; ++i) {
            h8v a_ = *(h8v*)&lA[wm + i * 16 + lr][lg * 8];
            #pragma unroll
            for (int j = 0; j < 4; ++j)
                acc[i][j] = __builtin_amdgcn_mfma_f32_16x16x32_f16(a_, b_[j], acc[i][j], 0, 0, 0);
        }
        __syncthreads();
    }
    #pragma unroll
    for (int i = 0; i < MF; ++i)
        #pragma unroll
        for (int j = 0; j < 4; ++j)
            #pragma unroll
            for (int rg = 0; rg < 4; ++rg) {
                const int row = bi + wm + i * 16 + lg * 4 + rg;
                const int col = bj + wn + j * 16 + lr;
                if (HOUT) {
                    C16[(size_t)row * N + col] = f2h(acc[i][j][rg]);
                } else {
                    float r = acc[i][j][rg] + bias[col];
                    C[(size_t)row * N + col] = r;
                }
            }
}

// ---------------- phi via MFMA: grid (BN/64, NHEADS, 2{q,k}) ----------------
// logit = SCALE*(q.w) - 0.5*SCALE^2*|q|^2
// q path: rowmax+exp -> phiq fp16.  k path: p_local = exp(logit - blockmax) fp16.
__global__ __launch_bounds__(256) void phi_mfma(const ushort* __restrict__ qkvh,
                                                const ushort* __restrict__ omh,
                                                ushort* __restrict__ phiq,
                                                ushort* __restrict__ plocal,
                                                float* __restrict__ blockmax) {
    __shared__ __attribute__((aligned(16))) ushort lq[64][72];
    __shared__ __attribute__((aligned(16))) ushort lbuf[128 * 72]; // omega; reused as staging [64][136]
    __shared__ float lnorm[64];
    __shared__ float wred[4];
    const int tid = threadIdx.x;
    const int z = blockIdx.z, h = blockIdx.y;
    const int bn0 = blockIdx.x * 64;
    const int w = tid >> 6, l = tid & 63, lr = l & 15, lg = l >> 4;

    // q/k tile load + per-row |q|^2
    {
        const int r = tid >> 2, c0 = (tid & 3) * 16;
        const size_t g = (size_t)(bn0 + r) * QKVN + (size_t)z * DIMS + h * HDIM + c0;
        s8v v0 = *(const s8v*)&qkvh[g];
        s8v v1 = *(const s8v*)&qkvh[g + 8];
        *(s8v*)&lq[r][c0] = v0;
        *(s8v*)&lq[r][c0 + 8] = v1;
        float p = 0.f;
        #pragma unroll
        for (int j = 0; j < 8; ++j) {
            float a = h2f(((ushort*)&v0)[j]); p += a * a;
            float b = h2f(((ushort*)&v1)[j]); p += b * b;
        }
        p += __shfl_xor(p, 1); p += __shfl_xor(p, 2);
        if ((tid & 3) == 0) lnorm[r] = p;
    }
    // omega load [128][64] -> lbuf stride 72
    {
        const int m = tid >> 1, c0 = (tid & 1) * 32;
        #pragma unroll
        for (int i = 0; i < 4; ++i)
            *(s8v*)&lbuf[m * 72 + c0 + i * 8] = *(const s8v*)&omh[m * HDIM + c0 + i * 8];
    }
    __syncthreads();

    f4v acc[8] = {};
    #pragma unroll
    for (int k0 = 0; k0 < 64; k0 += 32) {
        h8v a = *(h8v*)&lq[w * 16 + lr][k0 + lg * 8];
        #pragma unroll
        for (int ct = 0; ct < 8; ++ct) {
            h8v b = *(h8v*)&lbuf[(ct * 16 + lr) * 72 + k0 + lg * 8];
            acc[ct] = __builtin_amdgcn_mfma_f32_16x16x32_f16(a, b, acc[ct], 0, 0, 0);
        }
    }

    // logits in registers
    const float hs2 = 0.5f * SCALE * SCALE;
    float lvv[4][8];
    #pragma unroll
    for (int rg = 0; rg < 4; ++rg) {
        const int row = w * 16 + lg * 4 + rg;
        const float nh = hs2 * lnorm[row];
        #pragma unroll
        for (int ct = 0; ct < 8; ++ct) lvv[rg][ct] = SCALE * acc[ct][rg] - nh;
    }
    if (z == 1) {
        float bmax = -3.4e38f;
        #pragma unroll
        for (int rg = 0; rg < 4; ++rg)
            #pragma unroll
            for (int ct = 0; ct < 8; ++ct) bmax = fmaxf(bmax, lvv[rg][ct]);
        #pragma unroll
        for (int o = 32; o >= 1; o >>= 1) bmax = fmaxf(bmax, __shfl_xor(bmax, o));
        if (l == 0) wred[w] = bmax;
    }
    __syncthreads();   // lbuf (omega) free + wred ready

    if (z == 0) {
        // query: per-row max over 128 cols, exp
        #pragma unroll
        for (int rg = 0; rg < 4; ++rg) {
            const int row = w * 16 + lg * 4 + rg;
            float mx = -3.4e38f;
            #pragma unroll
            for (int ct = 0; ct < 8; ++ct) mx = fmaxf(mx, lvv[rg][ct]);
            #pragma unroll
            for (int o = 8; o >= 1; o >>= 1) mx = fmaxf(mx, __shfl_xor(mx, o));
            #pragma unroll
            for (int ct = 0; ct < 8; ++ct)
                lbuf[row * 136 + ct * 16 + lr] = f2h(expf(lvv[rg][ct] - mx) * INV_SQRT_M + 1e-4f);
        }
    } else {
        const float bm = fmaxf(fmaxf(wred[0], wred[1]), fmaxf(wred[2], wred[3]));
        if (tid == 0) blockmax[h * gridDim.x + blockIdx.x] = bm;
        #pragma unroll
        for (int rg = 0; rg < 4; ++rg) {
            const int row = w * 16 + lg * 4 + rg;
            #pragma unroll
            for (int ct = 0; ct < 8; ++ct)
                lbuf[row * 136 + ct * 16 + lr] = f2h(expf(lvv[rg][ct] - bm));
        }
    }
    __syncthreads();
    // coalesced store
    ushort* dst = (z == 0) ? phiq : plocal;
    const int r = tid >> 2, c0 = (tid & 3) * 32;
    const int br = bn0 + r;
    const int b = br >> 10, n = br & (NN - 1);
    const size_t orow = ((size_t)(b * NHEADS + h) * NN + n) * NFEAT;
    #pragma unroll
    for (int i = 0; i < 4; ++i)
        *(s8v*)&dst[orow + c0 + i * 8] = *(s8v*)&lbuf[r * 136 + c0 + i * 8];
}

// ---------------- fused: phik finalize + V transpose + per-chunk sums ----------------
// grid (NCH, 32bh). Produces phik (global), vt (global), ssum16 (fp16), kcsum.
__global__ __launch_bounds__(256) void phik_vt_sums(const ushort* __restrict__ plocal,
                                                    const float* __restrict__ blockmax,
                                                    const ushort* __restrict__ qkvh,
                                                    ushort* __restrict__ phik,
                                                    ushort* __restrict__ vt,
                                                    ushort* __restrict__ ssum16,
                                                    float* __restrict__ kcsum) {
    const int c = blockIdx.x, bh = blockIdx.y, n0 = c * CSZ;
    const int b = bh >> 4, h = bh & 15;
    const int tid = threadIdx.x;
    const int w = tid >> 6, l = tid & 63, lr = l & 15, lg = l >> 4;
    __shared__ __attribute__((aligned(16))) ushort lt[64][136];   // phik rows
    __shared__ __attribute__((aligned(16))) ushort lv[64][72];    // V rows
    __shared__ __attribute__((aligned(16))) ushort lvt[64][72];   // V^T [d][n]
    __shared__ __attribute__((aligned(16))) ushort lktT[128][72]; // phik^T [m][n]
    __shared__ float gred[4];

    // inline global max over 512 block maxes
    float mx = fmaxf(blockmax[tid], blockmax[tid + 256]);
    #pragma unroll
    for (int o = 32; o >= 1; o >>= 1) mx = fmaxf(mx, __shfl_xor(mx, o));
    if (l == 0) gred[w] = mx;
    // V rows -> LDS
    {
        const int r = tid >> 2, c0 = (tid & 3) * 16;
        const size_t g = (size_t)(b * NN + n0 + r) * QKVN + 2 * DIMS + h * HDIM + c0;
        *(s8v*)&lv[r][c0]     = *(const s8v*)&qkvh[g];
        *(s8v*)&lv[r][c0 + 8] = *(const s8v*)&qkvh[g + 8];
    }
    __syncthreads();
    const float gm = fmaxf(fmaxf(gred[0], gred[1]), fmaxf(gred[2], gred[3]));
    const float bm = blockmax[h * 32 + b * 16 + c];   // this chunk's phi_mfma block
    const float fac = expf(bm - gm) * INV_SQRT_M;
    // p_local -> phik (finalize)
    {
        const int r = tid >> 2, c0 = (tid & 3) * 32;
        const size_t gbase = ((size_t)bh * NN + n0 + r) * NFEAT + c0;
        ushort tmp[32];
        #pragma unroll
        for (int i = 0; i < 4; ++i) {
            s8v pv = *(const s8v*)&plocal[gbase + i * 8];
            #pragma unroll
            for (int j = 0; j < 8; ++j)
                tmp[i * 8 + j] = f2h(h2f(((ushort*)&pv)[j]) * fac + 1e-4f);
        }
        #pragma unroll
        for (int i = 0; i < 4; ++i) {
            *(s8v*)&phik[gbase + i * 8] = *(s8v*)&tmp[i * 8];
            *(s8v*)&lt[r][c0 + i * 8] = *(s8v*)&tmp[i * 8];
        }
    }
    __syncthreads();
    // phik^T -> LDS only
    {
        const int m = tid >> 1, nh2 = (tid & 1) * 32;
        ushort tp[32];
        #pragma unroll
        for (int i = 0; i < 32; ++i) tp[i] = lt[nh2 + i][m];
        #pragma unroll
        for (int i = 0; i < 4; ++i) *(s8v*)&lktT[m][nh2 + i * 8] = *(s8v*)&tp[i * 8];
    }
    // V^T -> global + LDS
    {
        const int d = tid >> 2, s0 = (tid & 3) * 16;
        ushort tp[16];
        #pragma unroll
        for (int i = 0; i < 16; ++i) tp[i] = lv[s0 + i][d];
        const size_t tb = ((size_t)bh * HDIM + d) * NN + n0 + s0;
        *(s8v*)&vt[tb] = *(s8v*)&tp[0];
        *(s8v*)&vt[tb + 8] = *(s8v*)&tp[8];
        *(s8v*)&lvt[d][s0] = *(s8v*)&tp[0];
        *(s8v*)&lvt[d][s0 + 8] = *(s8v*)&tp[8];
    }
    __syncthreads();
    // MFMA: ssum[d][m] = sum_n V[n,d]*phik[n,m]
    f4v acc[8] = {};
    #pragma unroll
    for (int k0 = 0; k0 < 64; k0 += 32) {
        h8v a = *(h8v*)&lvt[w * 16 + lr][k0 + lg * 8];
        #pragma unroll
        for (int ct = 0; ct < 8; ++ct) {
            h8v bf = *(h8v*)&lktT[ct * 16 + lr][k0 + lg * 8];
            acc[ct] = __builtin_amdgcn_mfma_f32_16x16x32_f16(a, bf, acc[ct], 0, 0, 0);
        }
    }
    const size_t obase = ((size_t)bh * NCH + c) * (HDIM * NFEAT);
    #pragma unroll
    for (int ct = 0; ct < 8; ++ct)
        #pragma unroll
        for (int rg = 0; rg < 4; ++rg) {
            const int d = w * 16 + lg * 4 + rg, m = ct * 16 + lr;
            ssum16[obase + (size_t)d * NFEAT + m] = f2h(acc[ct][rg]);
        }
    if (tid < 128) {
        float s = 0.f;
        #pragma unroll 8
        for (int i = 0; i < 64; ++i) s += h2f(lktT[tid][i]);
        kcsum[((size_t)bh * NCH + c) * NFEAT + tid] = s;
    }
}

// ---------------- prefix over chunks (Spre fp16) + fused kc prefix ----------------
__global__ __launch_bounds__(256) void chunk_prefix(const ushort* __restrict__ ssum16,
                                                    ushort* __restrict__ spre,
                                                    const float* __restrict__ kcsum,
                                                    float* __restrict__ kcpre) {
    const int bh = blockIdx.y, sl = blockIdx.x;
    const int tid = threadIdx.x;
    if (sl == 0 && tid < NFEAT) {
        float a = 0.f;
        for (int c = 0; c < NCH; ++c) {
            kcpre[((size_t)bh * NCH + c) * NFEAT + tid] = a;
            a += kcsum[((size_t)bh * NCH + c) * NFEAT + tid];
        }
    }
    const int base_e = (sl * 256 + tid) * 8;
    float acc[8] = {};
    const size_t bb = (size_t)bh * NCH * (HDIM * NFEAT);
    for (int c = 0; c < NCH; ++c) {
        const size_t cb = bb + (size_t)c * (HDIM * NFEAT);
        s8v v = *(const s8v*)&ssum16[cb + base_e];
        ushort o[8];
        #pragma unroll
        for (int j = 0; j < 8; ++j) o[j] = f2h(acc[j]);
        *(s8v*)&spre[cb + base_e] = *(s8v*)&o[0];
        #pragma unroll
        for (int j = 0; j < 8; ++j) acc[j] += h2f(((ushort*)&v)[j]);
    }
}

// ---------------- chunked causal attention via MFMA (att out fp16) ----------------
__global__ __launch_bounds__(256) void scan_final(const ushort* __restrict__ phiq,
                                                  const ushort* __restrict__ phik,
                                                  const ushort* __restrict__ vt,
                                                  const ushort* __restrict__ spre,
                                                  const float* __restrict__ kcpre,
                                                  ushort* __restrict__ att_h) {
    const int c = blockIdx.x, bh = blockIdx.y;
    const int b = bh >> 4, h = bh & 15;
    const int n0 = c * CSZ;
    __shared__ __attribute__((aligned(16))) ushort lq[64][136];
    __shared__ __attribute__((aligned(16))) ushort lk[64][136];
    __shared__ __attribute__((aligned(16))) ushort lvt[64][72];
    __shared__ __attribute__((aligned(16))) ushort lsp[64][136];
    __shared__ __attribute__((aligned(16))) ushort lA[64][72];
    __shared__ float kc[NFEAT];
    __shared__ float zin[64];
    __shared__ float zp[4][64];
    const int tid = threadIdx.x;

    const size_t qb = ((size_t)bh * NN + n0) * NFEAT;
    #pragma unroll
    for (int i = 0; i < 4; ++i) {
        const int idx = tid + 256 * i;
        const int r = idx >> 4, cs = (idx & 15) * 8;
        *(s8v*)&lq[r][cs] = *(const s8v*)&phiq[qb + (size_t)r * NFEAT + cs];
        *(s8v*)&lk[r][cs] = *(const s8v*)&phik[qb + (size_t)r * NFEAT + cs];
    }
    const size_t sb = ((size_t)bh * NCH + c) * (HDIM * NFEAT);
    #pragma unroll
    for (int i = 0; i < 4; ++i) {
        const int idx = tid + 256 * i;
        const int r = idx >> 4, cs = (idx & 15) * 8;
        *(s8v*)&lsp[r][cs] = *(const s8v*)&spre[sb + (size_t)r * NFEAT + cs];
    }
    {
        const int d = tid >> 2, s = (tid & 3) * 16;
        const size_t g = ((size_t)bh * HDIM + d) * NN + n0 + s;
        *(s8v*)&lvt[d][s]     = *(const s8v*)&vt[g];
        *(s8v*)&lvt[d][s + 8] = *(const s8v*)&vt[g + 8];
    }
    if (tid < NFEAT) kc[tid] = kcpre[((size_t)bh * NCH + c) * NFEAT + tid];
    __syncthreads();

    const int w = tid >> 6, l = tid & 63, lr = l & 15, lg = l >> 4;

    // Phase 1: A = phiq @ phik^T
    f4v a4[4] = {};
    #pragma unroll
    for (int k0 = 0; k0 < 128; k0 += 32) {
        h8v av = *(h8v*)&lq[w * 16 + lr][k0 + lg * 8];
        #pragma unroll
        for (int ct = 0; ct < 4; ++ct) {
            h8v bv = *(h8v*)&lk[ct * 16 + lr][k0 + lg * 8];
            a4[ct] = __builtin_amdgcn_mfma_f32_16x16x32_f16(av, bv, a4[ct], 0, 0, 0);
        }
    }
    float zi[4] = {0.f, 0.f, 0.f, 0.f};
    #pragma unroll
    for (int ct = 0; ct < 4; ++ct) {
        #pragma unroll
        for (int rg = 0; rg < 4; ++rg) {
            const int row = w * 16 + lg * 4 + rg;
            const int col = ct * 16 + lr;
            const float val = (col <= row) ? a4[ct][rg] : 0.f;
            const ushort hq = f2h(val);
            zi[rg] += h2f(hq);
            lA[row][col] = hq;
        }
    }
    #pragma unroll
    for (int rg = 0; rg < 4; ++rg) {
        float z = zi[rg];
        z += __shfl_xor(z, 1); z += __shfl_xor(z, 2);
        z += __shfl_xor(z, 4); z += __shfl_xor(z, 8);
        if (lr == 0) zin[w * 16 + lg * 4 + rg] = z;
    }
    {
        const int row = tid & 63, qq = tid >> 6;
        float s = 0.f;
        #pragma unroll 8
        for (int m = 0; m < 32; ++m) s += h2f(lq[row][qq * 32 + m]) * kc[qq * 32 + m];
        zp[qq][row] = s;
    }
    __syncthreads();

    // Phase 2: out = Amask @ V + phiq @ Spre
    f4v o4[4] = {};
    #pragma unroll
    for (int k0 = 0; k0 < 64; k0 += 32) {
        h8v av = *(h8v*)&lA[w * 16 + lr][k0 + lg * 8];
        #pragma unroll
        for (int ct = 0; ct < 4; ++ct) {
            h8v bv = *(h8v*)&lvt[ct * 16 + lr][k0 + lg * 8];
            o4[ct] = __builtin_amdgcn_mfma_f32_16x16x32_f16(av, bv, o4[ct], 0, 0, 0);
        }
    }
    #pragma unroll
    for (int k0 = 0; k0 < 128; k0 += 32) {
        h8v av = *(h8v*)&lq[w * 16 + lr][k0 + lg * 8];
        #pragma unroll
        for (int ct = 0; ct < 4; ++ct) {
            h8v bv = *(h8v*)&lsp[ct * 16 + lr][k0 + lg * 8];
            o4[ct] = __builtin_amdgcn_mfma_f32_16x16x32_f16(av, bv, o4[ct], 0, 0, 0);
        }
    }
    #pragma unroll
    for (int rg = 0; rg < 4; ++rg) {
        const int row = w * 16 + lg * 4 + rg;
        const float z = zin[row] + zp[0][row] + zp[1][row] + zp[2][row] + zp[3][row] + 1e-6f;
        const float rz = 1.f / z;
        #pragma unroll
        for (int ct = 0; ct < 4; ++ct) {
            const int d = ct * 16 + lr;
            att_h[((size_t)(b * NN + n0 + row)) * DIMS + h * HDIM + d] = f2h(o4[ct][rg] * rz);
        }
    }
}

extern "C" void kernel_launch(void* const* d_in, const int* in_sizes, int n_in,
                              void* d_out, int out_size, void* d_ws, size_t ws_size,
                              hipStream_t stream) {
    const float* x     = (const float*)d_in[0];
    const float* omega = (const float*)d_in[1];
    const float* Wq    = (const float*)d_in[2];
    const float* Wk    = (const float*)d_in[3];
    const float* Wv    = (const float*)d_in[4];
    const float* Wo    = (const float*)d_in[5];
    const float* bo    = (const float*)d_in[6];
    float* out = (float*)d_out;

    const size_t PROJ = (size_t)BN * DIMS;                 // 2M elems
    const size_t PHI  = (size_t)BB * NHEADS * NN * NFEAT;  // 4M elems
    ushort* qkvh    = (ushort*)d_ws;                       // 12 MB
    ushort* xh      = qkvh + (size_t)BN * QKVN;            // 4 MB
    ushort* wqkvh   = xh + PROJ;                           // 6 MB
    ushort* woh     = wqkvh + (size_t)QKVN * DIMS;         // 2 MB
    ushort* omh     = woh + WW;                            // 16 KB
    ushort* phiq_h  = omh + NFEAT * HDIM;                  // 8 MB
    ushort* phik_h  = phiq_h + PHI;                        // 8 MB
    ushort* plocal  = phik_h + PHI;                        // 8 MB
    ushort* vt_h    = plocal + PHI;                        // 4 MB
    ushort* ssum16  = vt_h + PROJ;                         // 8 MB
    ushort* spre_h  = ssum16 + PHI;                        // 8 MB
    ushort* att_hb  = spre_h + PHI;                        // 4 MB
    float*  kcsum   = (float*)(att_hb + PROJ);
    float*  kcpre   = kcsum + 32 * NCH * NFEAT;
    float*  blockmax= kcpre + 32 * NCH * NFEAT;

    // 1: fused casts (x, Wq,k,v, Wo, omega)
    cast_all<<<(NX + 4 * NW + NOM) / 256, 256, 0, stream>>>(x, Wq, Wk, Wv, Wo, omega,
                                                            xh, wqkvh, woh, omh);

    // 2: fused QKV projection -> fp16 [2048 x 3072]
    dim3 gq(BN / 128, QKVN / 128);   // (16, 24)
    gemm_nt_lds<128, true><<<gq, 256, 0, stream>>>(xh, wqkvh, nullptr, qkvh, nullptr,
                                                   BN, QKVN, DIMS);

    // 3: phi via MFMA, q (z=0) and k (z=1; writes p_local + blockmax)
    dim3 pg(BN / 64, NHEADS, 2);     // (32, 16, 2)
    phi_mfma<<<pg, 256, 0, stream>>>(qkvh, omh, phiq_h, plocal, blockmax);

    dim3 cg(NCH, BB * NHEADS);
    // 4: fused phik finalize + V transpose + chunk sums (gmax inline)
    phik_vt_sums<<<cg, 256, 0, stream>>>(plocal, blockmax, qkvh, phik_h, vt_h,
                                         ssum16, kcsum);
    // 5: prefixes (Spre + kc)
    chunk_prefix<<<dim3(4, BB * NHEADS), 256, 0, stream>>>(ssum16, spre_h, kcsum, kcpre);
    // 6: causal attention
    scan_final<<<cg, 256, 0, stream>>>(phiq_h, phik_h, vt_h, spre_h, kcpre, att_hb);

    // 7: output projection straight to d_out
    dim3 go(BN / 64, DIMS / 128);    // (32, 8)
    gemm_nt_lds<64, false><<<go, 256, 0, stream>>>(att_hb, woh, out, nullptr, bo,
                                                   BN, DIMS, DIMS);
}

// Round 10
// 91.666 us; speedup vs baseline: 7.2875x; 1.0550x over previous
//
#include <hip/hip_runtime.h>
#include <hip/hip_bf16.h>
#include <math.h>

#define DIMS 1024
#define NHEADS 16
#define HDIM 64
#define NFEAT 128
#define BB 2
#define NN 1024
#define BN (BB*NN)   // 2048
#define NCH 16       // chunks per (b,h)
#define CSZ 64       // chunk size
#define WW (DIMS*DIMS)
#define QKVN (3*DIMS) // 3072

#define SCALE 0.3535533905932738f       // 64^-0.25
#define INV_SQRT_M 0.08838834764831845f // 1/sqrt(128)

typedef __attribute__((ext_vector_type(8))) _Float16 h8v;  // 8 fp16 (4 VGPRs)
typedef __attribute__((ext_vector_type(8))) short s8v;     // raw 16B
typedef __attribute__((ext_vector_type(4))) float f4v;     // mfma accumulator

__device__ __forceinline__ ushort f2h(float x) {
    _Float16 h = (_Float16)x;
    return *(ushort*)&h;
}
__device__ __forceinline__ float h2f(ushort u) {
    _Float16 h = *(_Float16*)&u;
    return (float)h;
}
__device__ __forceinline__ void gload16(const void* g, void* l) {
    __builtin_amdgcn_global_load_lds(
        (const __attribute__((address_space(1))) unsigned int*)g,
        (__attribute__((address_space(3))) unsigned int*)l,
        16, 0, 0);
}

// ---------------- fused cast f32 -> fp16 for x, Wq,k,v, Wo, omega ----------------
#define NX (BN*DIMS/8)   // 262144
#define NW (WW/8)        // 131072
#define NOM (NFEAT*HDIM/8) // 1024
__global__ __launch_bounds__(256) void cast_all(const float* __restrict__ x,
                                                const float* __restrict__ Wq,
                                                const float* __restrict__ Wk,
                                                const float* __restrict__ Wv,
                                                const float* __restrict__ Wo,
                                                const float* __restrict__ omega,
                                                ushort* __restrict__ xh,
                                                ushort* __restrict__ wqkvh,
                                                ushort* __restrict__ woh,
                                                ushort* __restrict__ omh) {
    const int i = blockIdx.x * 256 + threadIdx.x;
    const float* src; ushort* dst; int off;
    if (i < NX)               { src = x;     dst = xh;                     off = i; }
    else if (i < NX + NW)     { src = Wq;    dst = wqkvh;                  off = i - NX; }
    else if (i < NX + 2 * NW) { src = Wk;    dst = wqkvh + WW;             off = i - NX - NW; }
    else if (i < NX + 3 * NW) { src = Wv;    dst = wqkvh + 2 * (size_t)WW; off = i - NX - 2 * NW; }
    else if (i < NX + 4 * NW) { src = Wo;    dst = woh;                    off = i - NX - 3 * NW; }
    else                      { src = omega; dst = omh;                    off = i - NX - 4 * NW; }
    float4 a = ((const float4*)src)[2 * (size_t)off];
    float4 b = ((const float4*)src)[2 * (size_t)off + 1];
    float v[8] = {a.x, a.y, a.z, a.w, b.x, b.y, b.z, b.w};
    ushort h8[8];
    #pragma unroll
    for (int j = 0; j < 8; ++j) h8[j] = f2h(v[j]);
    *(s8v*)&dst[(size_t)off * 8] = *(s8v*)&h8[0];
}

// ---------------- MFMA GEMM NT, m97 structure; 1D grid + bijective XCD swizzle ----------------
// nwg must be divisible by 8; consecutive remapped ids share the same N-panel (by).
template<int BM, bool HOUT>
__global__ __launch_bounds__(256) void gemm_nt_lds(const ushort* __restrict__ A,
                                                   const ushort* __restrict__ B,
                                                   float* __restrict__ C,
                                                   ushort* __restrict__ C16,
                                                   const float* __restrict__ bias,
                                                   int M, int N, int K, int nbx) {
    constexpr int MF = BM / 32;
    constexpr int AI = BM / 64;
    __shared__ __attribute__((aligned(16))) ushort lA[BM][32];
    __shared__ __attribute__((aligned(16))) ushort lB[128][32];
    const int tid = threadIdx.x;
    const int w = tid >> 6, l = tid & 63, lr = l & 15, lg = l >> 4;
    const int wm = (w >> 1) * (BM / 2), wn = (w & 1) * 64;
    // XCD swizzle: flat -> (xcd, idx) -> contiguous span per XCD
    const int nwg = gridDim.x;
    const int q8 = nwg >> 3;
    const int neu = (blockIdx.x & 7) * q8 + (blockIdx.x >> 3);
    const int bx = neu % nbx, by = neu / nbx;
    const int bi = bx * BM, bj = by * 128;
    const int srow = l >> 2, scol = (l & 3) * 8;

    f4v acc[MF][4] = {};
    for (int k0 = 0; k0 < K; k0 += 32) {
        #pragma unroll
        for (int i = 0; i < AI; ++i) {
            const int r0 = w * (16 * AI) + i * 16;
            gload16(&A[(size_t)(bi + r0 + srow) * K + k0 + scol], &lA[r0][0]);
        }
        #pragma unroll
        for (int i = 0; i < 2; ++i) {
            const int r0 = w * 32 + i * 16;
            gload16(&B[(size_t)(bj + r0 + srow) * K + k0 + scol], &lB[r0][0]);
        }
        __syncthreads();
        h8v b_[4];
        #pragma unroll
        for (int j = 0; j < 4; ++j) b_[j] = *(h8v*)&lB[wn + j * 16 + lr][lg * 8];
        #pragma unroll
        for (int i = 0; i < MF; ++i) {
            h8v a_ = *(h8v*)&lA[wm + i * 16 + lr][lg * 8];
            #pragma unroll
            for (int j = 0; j < 4; ++j)
                acc[i][j] = __builtin_amdgcn_mfma_f32_16x16x32_f16(a_, b_[j], acc[i][j], 0, 0, 0);
        }
        __syncthreads();
    }
    #pragma unroll
    for (int i = 0; i < MF; ++i)
        #pragma unroll
        for (int j = 0; j < 4; ++j)
            #pragma unroll
            for (int rg = 0; rg < 4; ++rg) {
                const int row = bi + wm + i * 16 + lg * 4 + rg;
                const int col = bj + wn + j * 16 + lr;
                if (HOUT) {
                    C16[(size_t)row * N + col] = f2h(acc[i][j][rg]);
                } else {
                    float r = acc[i][j][rg] + bias[col];
                    C[(size_t)row * N + col] = r;
                }
            }
}

// ---------------- phi via MFMA: grid (BN/64, NHEADS, 2{q,k}) ----------------
// logit = SCALE*(q.w) - 0.5*SCALE^2*|q|^2
// q path: rowmax+exp -> phiq fp16.  k path: p_local = exp(logit - blockmax) fp16.
__global__ __launch_bounds__(256) void phi_mfma(const ushort* __restrict__ qkvh,
                                                const ushort* __restrict__ omh,
                                                ushort* __restrict__ phiq,
                                                ushort* __restrict__ plocal,
                                                float* __restrict__ blockmax) {
    __shared__ __attribute__((aligned(16))) ushort lq[64][72];
    __shared__ __attribute__((aligned(16))) ushort lbuf[128 * 72]; // omega; reused as staging [64][136]
    __shared__ float lnorm[64];
    __shared__ float wred[4];
    const int tid = threadIdx.x;
    const int z = blockIdx.z, h = blockIdx.y;
    const int bn0 = blockIdx.x * 64;
    const int w = tid >> 6, l = tid & 63, lr = l & 15, lg = l >> 4;

    // q/k tile load + per-row |q|^2
    {
        const int r = tid >> 2, c0 = (tid & 3) * 16;
        const size_t g = (size_t)(bn0 + r) * QKVN + (size_t)z * DIMS + h * HDIM + c0;
        s8v v0 = *(const s8v*)&qkvh[g];
        s8v v1 = *(const s8v*)&qkvh[g + 8];
        *(s8v*)&lq[r][c0] = v0;
        *(s8v*)&lq[r][c0 + 8] = v1;
        float p = 0.f;
        #pragma unroll
        for (int j = 0; j < 8; ++j) {
            float a = h2f(((ushort*)&v0)[j]); p += a * a;
            float b = h2f(((ushort*)&v1)[j]); p += b * b;
        }
        p += __shfl_xor(p, 1); p += __shfl_xor(p, 2);
        if ((tid & 3) == 0) lnorm[r] = p;
    }
    // omega load [128][64] -> lbuf stride 72
    {
        const int m = tid >> 1, c0 = (tid & 1) * 32;
        #pragma unroll
        for (int i = 0; i < 4; ++i)
            *(s8v*)&lbuf[m * 72 + c0 + i * 8] = *(const s8v*)&omh[m * HDIM + c0 + i * 8];
    }
    __syncthreads();

    f4v acc[8] = {};
    #pragma unroll
    for (int k0 = 0; k0 < 64; k0 += 32) {
        h8v a = *(h8v*)&lq[w * 16 + lr][k0 + lg * 8];
        #pragma unroll
        for (int ct = 0; ct < 8; ++ct) {
            h8v b = *(h8v*)&lbuf[(ct * 16 + lr) * 72 + k0 + lg * 8];
            acc[ct] = __builtin_amdgcn_mfma_f32_16x16x32_f16(a, b, acc[ct], 0, 0, 0);
        }
    }

    // logits in registers
    const float hs2 = 0.5f * SCALE * SCALE;
    float lvv[4][8];
    #pragma unroll
    for (int rg = 0; rg < 4; ++rg) {
        const int row = w * 16 + lg * 4 + rg;
        const float nh = hs2 * lnorm[row];
        #pragma unroll
        for (int ct = 0; ct < 8; ++ct) lvv[rg][ct] = SCALE * acc[ct][rg] - nh;
    }
    if (z == 1) {
        float bmax = -3.4e38f;
        #pragma unroll
        for (int rg = 0; rg < 4; ++rg)
            #pragma unroll
            for (int ct = 0; ct < 8; ++ct) bmax = fmaxf(bmax, lvv[rg][ct]);
        #pragma unroll
        for (int o = 32; o >= 1; o >>= 1) bmax = fmaxf(bmax, __shfl_xor(bmax, o));
        if (l == 0) wred[w] = bmax;
    }
    __syncthreads();   // lbuf (omega) free + wred ready

    if (z == 0) {
        // query: per-row max over 128 cols, exp
        #pragma unroll
        for (int rg = 0; rg < 4; ++rg) {
            const int row = w * 16 + lg * 4 + rg;
            float mx = -3.4e38f;
            #pragma unroll
            for (int ct = 0; ct < 8; ++ct) mx = fmaxf(mx, lvv[rg][ct]);
            #pragma unroll
            for (int o = 8; o >= 1; o >>= 1) mx = fmaxf(mx, __shfl_xor(mx, o));
            #pragma unroll
            for (int ct = 0; ct < 8; ++ct)
                lbuf[row * 136 + ct * 16 + lr] = f2h(expf(lvv[rg][ct] - mx) * INV_SQRT_M + 1e-4f);
        }
    } else {
        const float bm = fmaxf(fmaxf(wred[0], wred[1]), fmaxf(wred[2], wred[3]));
        if (tid == 0) blockmax[h * gridDim.x + blockIdx.x] = bm;
        #pragma unroll
        for (int rg = 0; rg < 4; ++rg) {
            const int row = w * 16 + lg * 4 + rg;
            #pragma unroll
            for (int ct = 0; ct < 8; ++ct)
                lbuf[row * 136 + ct * 16 + lr] = f2h(expf(lvv[rg][ct] - bm));
        }
    }
    __syncthreads();
    // coalesced store
    ushort* dst = (z == 0) ? phiq : plocal;
    const int r = tid >> 2, c0 = (tid & 3) * 32;
    const int br = bn0 + r;
    const int b = br >> 10, n = br & (NN - 1);
    const size_t orow = ((size_t)(b * NHEADS + h) * NN + n) * NFEAT;
    #pragma unroll
    for (int i = 0; i < 4; ++i)
        *(s8v*)&dst[orow + c0 + i * 8] = *(s8v*)&lbuf[r * 136 + c0 + i * 8];
}

// ---------------- fused: phik finalize + V transpose + per-chunk sums ----------------
// grid (NCH, 32bh). Produces phik (global), vt (global), ssum16 (fp16), kcsum.
__global__ __launch_bounds__(256) void phik_vt_sums(const ushort* __restrict__ plocal,
                                                    const float* __restrict__ blockmax,
                                                    const ushort* __restrict__ qkvh,
                                                    ushort* __restrict__ phik,
                                                    ushort* __restrict__ vt,
                                                    ushort* __restrict__ ssum16,
                                                    float* __restrict__ kcsum) {
    const int c = blockIdx.x, bh = blockIdx.y, n0 = c * CSZ;
    const int b = bh >> 4, h = bh & 15;
    const int tid = threadIdx.x;
    const int w = tid >> 6, l = tid & 63, lr = l & 15, lg = l >> 4;
    __shared__ __attribute__((aligned(16))) ushort lt[64][136];   // phik rows
    __shared__ __attribute__((aligned(16))) ushort lv[64][72];    // V rows
    __shared__ __attribute__((aligned(16))) ushort lvt[64][72];   // V^T [d][n]
    __shared__ __attribute__((aligned(16))) ushort lktT[128][72]; // phik^T [m][n]
    __shared__ float gred[4];

    // inline global max over 512 block maxes
    float mx = fmaxf(blockmax[tid], blockmax[tid + 256]);
    #pragma unroll
    for (int o = 32; o >= 1; o >>= 1) mx = fmaxf(mx, __shfl_xor(mx, o));
    if (l == 0) gred[w] = mx;
    // V rows -> LDS
    {
        const int r = tid >> 2, c0 = (tid & 3) * 16;
        const size_t g = (size_t)(b * NN + n0 + r) * QKVN + 2 * DIMS + h * HDIM + c0;
        *(s8v*)&lv[r][c0]     = *(const s8v*)&qkvh[g];
        *(s8v*)&lv[r][c0 + 8] = *(const s8v*)&qkvh[g + 8];
    }
    __syncthreads();
    const float gm = fmaxf(fmaxf(gred[0], gred[1]), fmaxf(gred[2], gred[3]));
    const float bm = blockmax[h * 32 + b * 16 + c];   // this chunk's phi_mfma block
    const float fac = expf(bm - gm) * INV_SQRT_M;
    // p_local -> phik (finalize)
    {
        const int r = tid >> 2, c0 = (tid & 3) * 32;
        const size_t gbase = ((size_t)bh * NN + n0 + r) * NFEAT + c0;
        ushort tmp[32];
        #pragma unroll
        for (int i = 0; i < 4; ++i) {
            s8v pv = *(const s8v*)&plocal[gbase + i * 8];
            #pragma unroll
            for (int j = 0; j < 8; ++j)
                tmp[i * 8 + j] = f2h(h2f(((ushort*)&pv)[j]) * fac + 1e-4f);
        }
        #pragma unroll
        for (int i = 0; i < 4; ++i) {
            *(s8v*)&phik[gbase + i * 8] = *(s8v*)&tmp[i * 8];
            *(s8v*)&lt[r][c0 + i * 8] = *(s8v*)&tmp[i * 8];
        }
    }
    __syncthreads();
    // phik^T -> LDS only
    {
        const int m = tid >> 1, nh2 = (tid & 1) * 32;
        ushort tp[32];
        #pragma unroll
        for (int i = 0; i < 32; ++i) tp[i] = lt[nh2 + i][m];
        #pragma unroll
        for (int i = 0; i < 4; ++i) *(s8v*)&lktT[m][nh2 + i * 8] = *(s8v*)&tp[i * 8];
    }
    // V^T -> global + LDS
    {
        const int d = tid >> 2, s0 = (tid & 3) * 16;
        ushort tp[16];
        #pragma unroll
        for (int i = 0; i < 16; ++i) tp[i] = lv[s0 + i][d];
        const size_t tb = ((size_t)bh * HDIM + d) * NN + n0 + s0;
        *(s8v*)&vt[tb] = *(s8v*)&tp[0];
        *(s8v*)&vt[tb + 8] = *(s8v*)&tp[8];
        *(s8v*)&lvt[d][s0] = *(s8v*)&tp[0];
        *(s8v*)&lvt[d][s0 + 8] = *(s8v*)&tp[8];
    }
    __syncthreads();
    // MFMA: ssum[d][m] = sum_n V[n,d]*phik[n,m]
    f4v acc[8] = {};
    #pragma unroll
    for (int k0 = 0; k0 < 64; k0 += 32) {
        h8v a = *(h8v*)&lvt[w * 16 + lr][k0 + lg * 8];
        #pragma unroll
        for (int ct = 0; ct < 8; ++ct) {
            h8v bf = *(h8v*)&lktT[ct * 16 + lr][k0 + lg * 8];
            acc[ct] = __builtin_amdgcn_mfma_f32_16x16x32_f16(a, bf, acc[ct], 0, 0, 0);
        }
    }
    const size_t obase = ((size_t)bh * NCH + c) * (HDIM * NFEAT);
    #pragma unroll
    for (int ct = 0; ct < 8; ++ct)
        #pragma unroll
        for (int rg = 0; rg < 4; ++rg) {
            const int d = w * 16 + lg * 4 + rg, m = ct * 16 + lr;
            ssum16[obase + (size_t)d * NFEAT + m] = f2h(acc[ct][rg]);
        }
    if (tid < 128) {
        float s = 0.f;
        #pragma unroll 8
        for (int i = 0; i < 64; ++i) s += h2f(lktT[tid][i]);
        kcsum[((size_t)bh * NCH + c) * NFEAT + tid] = s;
    }
}

// ---------------- prefix over chunks (Spre fp16) + fused kc prefix ----------------
__global__ __launch_bounds__(256) void chunk_prefix(const ushort* __restrict__ ssum16,
                                                    ushort* __restrict__ spre,
                                                    const float* __restrict__ kcsum,
                                                    float* __restrict__ kcpre) {
    const int bh = blockIdx.y, sl = blockIdx.x;
    const int tid = threadIdx.x;
    if (sl == 0 && tid < NFEAT) {
        float a = 0.f;
        for (int c = 0; c < NCH; ++c) {
            kcpre[((size_t)bh * NCH + c) * NFEAT + tid] = a;
            a += kcsum[((size_t)bh * NCH + c) * NFEAT + tid];
        }
    }
    const int base_e = (sl * 256 + tid) * 8;
    float acc[8] = {};
    const size_t bb = (size_t)bh * NCH * (HDIM * NFEAT);
    for (int c = 0; c < NCH; ++c) {
        const size_t cb = bb + (size_t)c * (HDIM * NFEAT);
        s8v v = *(const s8v*)&ssum16[cb + base_e];
        ushort o[8];
        #pragma unroll
        for (int j = 0; j < 8; ++j) o[j] = f2h(acc[j]);
        *(s8v*)&spre[cb + base_e] = *(s8v*)&o[0];
        #pragma unroll
        for (int j = 0; j < 8; ++j) acc[j] += h2f(((ushort*)&v)[j]);
    }
}

// ---------------- chunked causal attention via MFMA (att out fp16) ----------------
__global__ __launch_bounds__(256) void scan_final(const ushort* __restrict__ phiq,
                                                  const ushort* __restrict__ phik,
                                                  const ushort* __restrict__ vt,
                                                  const ushort* __restrict__ spre,
                                                  const float* __restrict__ kcpre,
                                                  ushort* __restrict__ att_h) {
    const int c = blockIdx.x, bh = blockIdx.y;
    const int b = bh >> 4, h = bh & 15;
    const int n0 = c * CSZ;
    __shared__ __attribute__((aligned(16))) ushort lq[64][136];
    __shared__ __attribute__((aligned(16))) ushort lk[64][136];
    __shared__ __attribute__((aligned(16))) ushort lvt[64][72];
    __shared__ __attribute__((aligned(16))) ushort lsp[64][136];
    __shared__ __attribute__((aligned(16))) ushort lA[64][72];
    __shared__ float kc[NFEAT];
    __shared__ float zin[64];
    __shared__ float zp[4][64];
    const int tid = threadIdx.x;

    const size_t qb = ((size_t)bh * NN + n0) * NFEAT;
    #pragma unroll
    for (int i = 0; i < 4; ++i) {
        const int idx = tid + 256 * i;
        const int r = idx >> 4, cs = (idx & 15) * 8;
        *(s8v*)&lq[r][cs] = *(const s8v*)&phiq[qb + (size_t)r * NFEAT + cs];
        *(s8v*)&lk[r][cs] = *(const s8v*)&phik[qb + (size_t)r * NFEAT + cs];
    }
    const size_t sb = ((size_t)bh * NCH + c) * (HDIM * NFEAT);
    #pragma unroll
    for (int i = 0; i < 4; ++i) {
        const int idx = tid + 256 * i;
        const int r = idx >> 4, cs = (idx & 15) * 8;
        *(s8v*)&lsp[r][cs] = *(const s8v*)&spre[sb + (size_t)r * NFEAT + cs];
    }
    {
        const int d = tid >> 2, s = (tid & 3) * 16;
        const size_t g = ((size_t)bh * HDIM + d) * NN + n0 + s;
        *(s8v*)&lvt[d][s]     = *(const s8v*)&vt[g];
        *(s8v*)&lvt[d][s + 8] = *(const s8v*)&vt[g + 8];
    }
    if (tid < NFEAT) kc[tid] = kcpre[((size_t)bh * NCH + c) * NFEAT + tid];
    __syncthreads();

    const int w = tid >> 6, l = tid & 63, lr = l & 15, lg = l >> 4;

    // Phase 1: A = phiq @ phik^T
    f4v a4[4] = {};
    #pragma unroll
    for (int k0 = 0; k0 < 128; k0 += 32) {
        h8v av = *(h8v*)&lq[w * 16 + lr][k0 + lg * 8];
        #pragma unroll
        for (int ct = 0; ct < 4; ++ct) {
            h8v bv = *(h8v*)&lk[ct * 16 + lr][k0 + lg * 8];
            a4[ct] = __builtin_amdgcn_mfma_f32_16x16x32_f16(av, bv, a4[ct], 0, 0, 0);
        }
    }
    float zi[4] = {0.f, 0.f, 0.f, 0.f};
    #pragma unroll
    for (int ct = 0; ct < 4; ++ct) {
        #pragma unroll
        for (int rg = 0; rg < 4; ++rg) {
            const int row = w * 16 + lg * 4 + rg;
            const int col = ct * 16 + lr;
            const float val = (col <= row) ? a4[ct][rg] : 0.f;
            const ushort hq = f2h(val);
            zi[rg] += h2f(hq);
            lA[row][col] = hq;
        }
    }
    #pragma unroll
    for (int rg = 0; rg < 4; ++rg) {
        float z = zi[rg];
        z += __shfl_xor(z, 1); z += __shfl_xor(z, 2);
        z += __shfl_xor(z, 4); z += __shfl_xor(z, 8);
        if (lr == 0) zin[w * 16 + lg * 4 + rg] = z;
    }
    {
        const int row = tid & 63, qq = tid >> 6;
        float s = 0.f;
        #pragma unroll 8
        for (int m = 0; m < 32; ++m) s += h2f(lq[row][qq * 32 + m]) * kc[qq * 32 + m];
        zp[qq][row] = s;
    }
    __syncthreads();

    // Phase 2: out = Amask @ V + phiq @ Spre
    f4v o4[4] = {};
    #pragma unroll
    for (int k0 = 0; k0 < 64; k0 += 32) {
        h8v av = *(h8v*)&lA[w * 16 + lr][k0 + lg * 8];
        #pragma unroll
        for (int ct = 0; ct < 4; ++ct) {
            h8v bv = *(h8v*)&lvt[ct * 16 + lr][k0 + lg * 8];
            o4[ct] = __builtin_amdgcn_mfma_f32_16x16x32_f16(av, bv, o4[ct], 0, 0, 0);
        }
    }
    #pragma unroll
    for (int k0 = 0; k0 < 128; k0 += 32) {
        h8v av = *(h8v*)&lq[w * 16 + lr][k0 + lg * 8];
        #pragma unroll
        for (int ct = 0; ct < 4; ++ct) {
            h8v bv = *(h8v*)&lsp[ct * 16 + lr][k0 + lg * 8];
            o4[ct] = __builtin_amdgcn_mfma_f32_16x16x32_f16(av, bv, o4[ct], 0, 0, 0);
        }
    }
    #pragma unroll
    for (int rg = 0; rg < 4; ++rg) {
        const int row = w * 16 + lg * 4 + rg;
        const float z = zin[row] + zp[0][row] + zp[1][row] + zp[2][row] + zp[3][row] + 1e-6f;
        const float rz = 1.f / z;
        #pragma unroll
        for (int ct = 0; ct < 4; ++ct) {
            const int d = ct * 16 + lr;
            att_h[((size_t)(b * NN + n0 + row)) * DIMS + h * HDIM + d] = f2h(o4[ct][rg] * rz);
        }
    }
}

extern "C" void kernel_launch(void* const* d_in, const int* in_sizes, int n_in,
                              void* d_out, int out_size, void* d_ws, size_t ws_size,
                              hipStream_t stream) {
    const float* x     = (const float*)d_in[0];
    const float* omega = (const float*)d_in[1];
    const float* Wq    = (const float*)d_in[2];
    const float* Wk    = (const float*)d_in[3];
    const float* Wv    = (const float*)d_in[4];
    const float* Wo    = (const float*)d_in[5];
    const float* bo    = (const float*)d_in[6];
    float* out = (float*)d_out;

    const size_t PROJ = (size_t)BN * DIMS;                 // 2M elems
    const size_t PHI  = (size_t)BB * NHEADS * NN * NFEAT;  // 4M elems
    ushort* qkvh    = (ushort*)d_ws;                       // 12 MB
    ushort* xh      = qkvh + (size_t)BN * QKVN;            // 4 MB
    ushort* wqkvh   = xh + PROJ;                           // 6 MB
    ushort* woh     = wqkvh + (size_t)QKVN * DIMS;         // 2 MB
    ushort* omh     = woh + WW;                            // 16 KB
    ushort* phiq_h  = omh + NFEAT * HDIM;                  // 8 MB
    ushort* phik_h  = phiq_h + PHI;                        // 8 MB
    ushort* plocal  = phik_h + PHI;                        // 8 MB
    ushort* vt_h    = plocal + PHI;                        // 4 MB
    ushort* ssum16  = vt_h + PROJ;                         // 8 MB
    ushort* spre_h  = ssum16 + PHI;                        // 8 MB
    ushort* att_hb  = spre_h + PHI;                        // 4 MB
    float*  kcsum   = (float*)(att_hb + PROJ);
    float*  kcpre   = kcsum + 32 * NCH * NFEAT;
    float*  blockmax= kcpre + 32 * NCH * NFEAT;

    // 1: fused casts (x, Wq,k,v, Wo, omega)
    cast_all<<<(NX + 4 * NW + NOM) / 256, 256, 0, stream>>>(x, Wq, Wk, Wv, Wo, omega,
                                                            xh, wqkvh, woh, omh);

    // 2: fused QKV projection -> fp16 [2048 x 3072]; BM=64: 768 blocks = 3/CU
    gemm_nt_lds<64, true><<<(BN / 64) * (QKVN / 128), 256, 0, stream>>>(
        xh, wqkvh, nullptr, qkvh, nullptr, BN, QKVN, DIMS, BN / 64);

    // 3: phi via MFMA, q (z=0) and k (z=1; writes p_local + blockmax)
    dim3 pg(BN / 64, NHEADS, 2);     // (32, 16, 2)
    phi_mfma<<<pg, 256, 0, stream>>>(qkvh, omh, phiq_h, plocal, blockmax);

    dim3 cg(NCH, BB * NHEADS);
    // 4: fused phik finalize + V transpose + chunk sums (gmax inline)
    phik_vt_sums<<<cg, 256, 0, stream>>>(plocal, blockmax, qkvh, phik_h, vt_h,
                                         ssum16, kcsum);
    // 5: prefixes (Spre + kc)
    chunk_prefix<<<dim3(4, BB * NHEADS), 256, 0, stream>>>(ssum16, spre_h, kcsum, kcpre);
    // 6: causal attention
    scan_final<<<cg, 256, 0, stream>>>(phiq_h, phik_h, vt_h, spre_h, kcpre, att_hb);

    // 7: output projection straight to d_out; 256 blocks = 1/CU
    gemm_nt_lds<64, false><<<(BN / 64) * (DIMS / 128), 256, 0, stream>>>(
        att_hb, woh, out, nullptr, bo, BN, DIMS, DIMS, BN / 64);
}

// Round 11
// 89.018 us; speedup vs baseline: 7.5043x; 1.0298x over previous
//
#include <hip/hip_runtime.h>
#include <hip/hip_bf16.h>
#include <math.h>

#define DIMS 1024
#define NHEADS 16
#define HDIM 64
#define NFEAT 128
#define BB 2
#define NN 1024
#define BN (BB*NN)   // 2048
#define NCH 16       // chunks per (b,h)
#define CSZ 64       // chunk size
#define WW (DIMS*DIMS)
#define QKVN (3*DIMS) // 3072

#define SCALE 0.3535533905932738f       // 64^-0.25
#define INV_SQRT_M 0.08838834764831845f // 1/sqrt(128)

typedef __attribute__((ext_vector_type(8))) _Float16 h8v;  // 8 fp16 (4 VGPRs)
typedef __attribute__((ext_vector_type(8))) short s8v;     // raw 16B
typedef __attribute__((ext_vector_type(4))) float f4v;     // mfma accumulator

__device__ __forceinline__ ushort f2h(float x) {
    _Float16 h = (_Float16)x;
    return *(ushort*)&h;
}
__device__ __forceinline__ float h2f(ushort u) {
    _Float16 h = *(_Float16*)&u;
    return (float)h;
}
__device__ __forceinline__ void gload16(const void* g, void* l) {
    __builtin_amdgcn_global_load_lds(
        (const __attribute__((address_space(1))) unsigned int*)g,
        (__attribute__((address_space(3))) unsigned int*)l,
        16, 0, 0);
}

// ---------------- fused cast f32 -> fp16 for x, Wq,k,v, Wo, omega ----------------
#define NX (BN*DIMS/8)   // 262144
#define NW (WW/8)        // 131072
#define NOM (NFEAT*HDIM/8) // 1024
__global__ __launch_bounds__(256) void cast_all(const float* __restrict__ x,
                                                const float* __restrict__ Wq,
                                                const float* __restrict__ Wk,
                                                const float* __restrict__ Wv,
                                                const float* __restrict__ Wo,
                                                const float* __restrict__ omega,
                                                ushort* __restrict__ xh,
                                                ushort* __restrict__ wqkvh,
                                                ushort* __restrict__ woh,
                                                ushort* __restrict__ omh) {
    const int i = blockIdx.x * 256 + threadIdx.x;
    const float* src; ushort* dst; int off;
    if (i < NX)               { src = x;     dst = xh;                     off = i; }
    else if (i < NX + NW)     { src = Wq;    dst = wqkvh;                  off = i - NX; }
    else if (i < NX + 2 * NW) { src = Wk;    dst = wqkvh + WW;             off = i - NX - NW; }
    else if (i < NX + 3 * NW) { src = Wv;    dst = wqkvh + 2 * (size_t)WW; off = i - NX - 2 * NW; }
    else if (i < NX + 4 * NW) { src = Wo;    dst = woh;                    off = i - NX - 3 * NW; }
    else                      { src = omega; dst = omh;                    off = i - NX - 4 * NW; }
    float4 a = ((const float4*)src)[2 * (size_t)off];
    float4 b = ((const float4*)src)[2 * (size_t)off + 1];
    float v[8] = {a.x, a.y, a.z, a.w, b.x, b.y, b.z, b.w};
    ushort h8[8];
    #pragma unroll
    for (int j = 0; j < 8; ++j) h8[j] = f2h(v[j]);
    *(s8v*)&dst[(size_t)off * 8] = *(s8v*)&h8[0];
}

// ---------------- MFMA GEMM NT, m97 structure; 1D grid + bijective XCD swizzle ----------------
template<int BM, bool HOUT>
__global__ __launch_bounds__(256) void gemm_nt_lds(const ushort* __restrict__ A,
                                                   const ushort* __restrict__ B,
                                                   float* __restrict__ C,
                                                   ushort* __restrict__ C16,
                                                   const float* __restrict__ bias,
                                                   int M, int N, int K, int nbx) {
    constexpr int MF = BM / 32;
    constexpr int AI = BM / 64;
    __shared__ __attribute__((aligned(16))) ushort lA[BM][32];
    __shared__ __attribute__((aligned(16))) ushort lB[128][32];
    const int tid = threadIdx.x;
    const int w = tid >> 6, l = tid & 63, lr = l & 15, lg = l >> 4;
    const int wm = (w >> 1) * (BM / 2), wn = (w & 1) * 64;
    const int nwg = gridDim.x;
    const int q8 = nwg >> 3;
    const int neu = (blockIdx.x & 7) * q8 + (blockIdx.x >> 3);
    const int bx = neu % nbx, by = neu / nbx;
    const int bi = bx * BM, bj = by * 128;
    const int srow = l >> 2, scol = (l & 3) * 8;

    f4v acc[MF][4] = {};
    for (int k0 = 0; k0 < K; k0 += 32) {
        #pragma unroll
        for (int i = 0; i < AI; ++i) {
            const int r0 = w * (16 * AI) + i * 16;
            gload16(&A[(size_t)(bi + r0 + srow) * K + k0 + scol], &lA[r0][0]);
        }
        #pragma unroll
        for (int i = 0; i < 2; ++i) {
            const int r0 = w * 32 + i * 16;
            gload16(&B[(size_t)(bj + r0 + srow) * K + k0 + scol], &lB[r0][0]);
        }
        __syncthreads();
        h8v b_[4];
        #pragma unroll
        for (int j = 0; j < 4; ++j) b_[j] = *(h8v*)&lB[wn + j * 16 + lr][lg * 8];
        #pragma unroll
        for (int i = 0; i < MF; ++i) {
            h8v a_ = *(h8v*)&lA[wm + i * 16 + lr][lg * 8];
            #pragma unroll
            for (int j = 0; j < 4; ++j)
                acc[i][j] = __builtin_amdgcn_mfma_f32_16x16x32_f16(a_, b_[j], acc[i][j], 0, 0, 0);
        }
        __syncthreads();
    }
    #pragma unroll
    for (int i = 0; i < MF; ++i)
        #pragma unroll
        for (int j = 0; j < 4; ++j)
            #pragma unroll
            for (int rg = 0; rg < 4; ++rg) {
                const int row = bi + wm + i * 16 + lg * 4 + rg;
                const int col = bj + wn + j * 16 + lr;
                if (HOUT) {
                    C16[(size_t)row * N + col] = f2h(acc[i][j][rg]);
                } else {
                    float r = acc[i][j][rg] + bias[col];
                    C[(size_t)row * N + col] = r;
                }
            }
}

// ---------------- fused phi + (key path) chunk sums ----------------
// grid (BN/64, NHEADS, 2). logit = SCALE*(q.w) - 0.5*SCALE^2*|q|^2.
// z=0: phiq = exp(logit - rowmax)*INV_SQRT_M + 1e-4.
// z=1: plocal = exp(logit - blockmax); V^T; ssum_raw[d][m] = sum_n V[n,d]*plocal[n,m];
//      kcsum_raw[m] = sum_n plocal[n,m]; vsum[d] = sum_n V[n,d].
__global__ __launch_bounds__(256) void phi_mfma(const ushort* __restrict__ qkvh,
                                                const ushort* __restrict__ omh,
                                                ushort* __restrict__ phiq,
                                                ushort* __restrict__ plocal,
                                                float* __restrict__ blockmax,
                                                ushort* __restrict__ vt,
                                                ushort* __restrict__ ssum16,
                                                float* __restrict__ kcsum,
                                                float* __restrict__ vsum) {
    __shared__ __attribute__((aligned(16))) ushort lq[64][72];
    __shared__ __attribute__((aligned(16))) ushort lom[128 * 72]; // omega; reused as staging [64][136]
    __shared__ __attribute__((aligned(16))) ushort lktT[128][72]; // plocal^T (z=1)
    __shared__ __attribute__((aligned(16))) ushort lv[64][72];    // V rows (z=1)
    __shared__ __attribute__((aligned(16))) ushort lvt[64][72];   // V^T (z=1)
    __shared__ float lnorm[64];
    __shared__ float wred[4];
    const int tid = threadIdx.x;
    const int z = blockIdx.z, h = blockIdx.y;
    const int bn0 = blockIdx.x * 64;
    const int w = tid >> 6, l = tid & 63, lr = l & 15, lg = l >> 4;
    const int b = blockIdx.x >> 4, c = blockIdx.x & 15;
    const int bh = b * NHEADS + h;

    // q/k tile load + per-row |q|^2
    {
        const int r = tid >> 2, c0 = (tid & 3) * 16;
        const size_t g = (size_t)(bn0 + r) * QKVN + (size_t)z * DIMS + h * HDIM + c0;
        s8v v0 = *(const s8v*)&qkvh[g];
        s8v v1 = *(const s8v*)&qkvh[g + 8];
        *(s8v*)&lq[r][c0] = v0;
        *(s8v*)&lq[r][c0 + 8] = v1;
        float p = 0.f;
        #pragma unroll
        for (int j = 0; j < 8; ++j) {
            float a = h2f(((ushort*)&v0)[j]); p += a * a;
            float bb2 = h2f(((ushort*)&v1)[j]); p += bb2 * bb2;
        }
        p += __shfl_xor(p, 1); p += __shfl_xor(p, 2);
        if ((tid & 3) == 0) lnorm[r] = p;
    }
    // omega load [128][64] -> lom stride 72
    {
        const int m = tid >> 1, c0 = (tid & 1) * 32;
        #pragma unroll
        for (int i = 0; i < 4; ++i)
            *(s8v*)&lom[m * 72 + c0 + i * 8] = *(const s8v*)&omh[m * HDIM + c0 + i * 8];
    }
    // V rows -> LDS (key path only)
    if (z == 1) {
        const int r = tid >> 2, c0 = (tid & 3) * 16;
        const size_t g = (size_t)(bn0 + r) * QKVN + 2 * DIMS + h * HDIM + c0;
        *(s8v*)&lv[r][c0]     = *(const s8v*)&qkvh[g];
        *(s8v*)&lv[r][c0 + 8] = *(const s8v*)&qkvh[g + 8];
    }
    __syncthreads();

    f4v acc[8] = {};
    #pragma unroll
    for (int k0 = 0; k0 < 64; k0 += 32) {
        h8v a = *(h8v*)&lq[w * 16 + lr][k0 + lg * 8];
        #pragma unroll
        for (int ct = 0; ct < 8; ++ct) {
            h8v bo = *(h8v*)&lom[(ct * 16 + lr) * 72 + k0 + lg * 8];
            acc[ct] = __builtin_amdgcn_mfma_f32_16x16x32_f16(a, bo, acc[ct], 0, 0, 0);
        }
    }

    const float hs2 = 0.5f * SCALE * SCALE;
    float lvv[4][8];
    #pragma unroll
    for (int rg = 0; rg < 4; ++rg) {
        const int row = w * 16 + lg * 4 + rg;
        const float nh = hs2 * lnorm[row];
        #pragma unroll
        for (int ct = 0; ct < 8; ++ct) lvv[rg][ct] = SCALE * acc[ct][rg] - nh;
    }
    if (z == 1) {
        float bmax = -3.4e38f;
        #pragma unroll
        for (int rg = 0; rg < 4; ++rg)
            #pragma unroll
            for (int ct = 0; ct < 8; ++ct) bmax = fmaxf(bmax, lvv[rg][ct]);
        #pragma unroll
        for (int o = 32; o >= 1; o >>= 1) bmax = fmaxf(bmax, __shfl_xor(bmax, o));
        if (l == 0) wred[w] = bmax;
    }
    __syncthreads();   // lom (omega) free + wred ready

    if (z == 0) {
        #pragma unroll
        for (int rg = 0; rg < 4; ++rg) {
            const int row = w * 16 + lg * 4 + rg;
            float mx = -3.4e38f;
            #pragma unroll
            for (int ct = 0; ct < 8; ++ct) mx = fmaxf(mx, lvv[rg][ct]);
            #pragma unroll
            for (int o = 8; o >= 1; o >>= 1) mx = fmaxf(mx, __shfl_xor(mx, o));
            #pragma unroll
            for (int ct = 0; ct < 8; ++ct)
                lom[row * 136 + ct * 16 + lr] = f2h(expf(lvv[rg][ct] - mx) * INV_SQRT_M + 1e-4f);
        }
    } else {
        const float bm = fmaxf(fmaxf(wred[0], wred[1]), fmaxf(wred[2], wred[3]));
        if (tid == 0) blockmax[h * 32 + blockIdx.x] = bm;
        #pragma unroll
        for (int rg = 0; rg < 4; ++rg) {
            const int row = w * 16 + lg * 4 + rg;
            #pragma unroll
            for (int ct = 0; ct < 8; ++ct)
                lom[row * 136 + ct * 16 + lr] = f2h(expf(lvv[rg][ct] - bm));
        }
    }
    __syncthreads();   // staging complete

    // coalesced store phiq / plocal
    {
        ushort* dst = (z == 0) ? phiq : plocal;
        const int r = tid >> 2, c0 = (tid & 3) * 32;
        const size_t orow = ((size_t)bh * NN + (blockIdx.x & 15) * 64 + ((bn0 >> 10) ? 0 : 0)
                             + ((size_t)0)) * 0; // placeholder avoided below
        const int br = bn0 + r;
        const int bb2 = br >> 10, n = br & (NN - 1);
        const size_t og = ((size_t)(bb2 * NHEADS + h) * NN + n) * NFEAT;
        #pragma unroll
        for (int i = 0; i < 4; ++i)
            *(s8v*)&dst[og + c0 + i * 8] = *(s8v*)&lom[r * 136 + c0 + i * 8];
        (void)orow;
    }
    if (z == 0) return;

    // plocal^T -> lktT
    {
        const int m = tid >> 1, nh2 = (tid & 1) * 32;
        ushort tp[32];
        #pragma unroll
        for (int i = 0; i < 32; ++i) tp[i] = lom[(nh2 + i) * 136 + m];
        #pragma unroll
        for (int i = 0; i < 4; ++i) *(s8v*)&lktT[m][nh2 + i * 8] = *(s8v*)&tp[i * 8];
    }
    // V^T -> global + LDS
    {
        const int d = tid >> 2, s0 = (tid & 3) * 16;
        ushort tp[16];
        #pragma unroll
        for (int i = 0; i < 16; ++i) tp[i] = lv[s0 + i][d];
        const size_t tb = ((size_t)bh * HDIM + d) * NN + c * CSZ + (b ? 0 : 0) + s0;
        // NOTE: vt index must use chunk-within-(b,h): rows bn0..bn0+63 are chunk c of (b,h)
        *(s8v*)&vt[((size_t)bh * HDIM + d) * NN + c * CSZ + s0] = *(s8v*)&tp[0];
        *(s8v*)&vt[((size_t)bh * HDIM + d) * NN + c * CSZ + s0 + 8] = *(s8v*)&tp[8];
        *(s8v*)&lvt[d][s0] = *(s8v*)&tp[0];
        *(s8v*)&lvt[d][s0 + 8] = *(s8v*)&tp[8];
        (void)tb;
    }
    __syncthreads();   // lktT, lvt ready

    // ssum_raw[d][m] = sum_n V[n,d]*plocal[n,m]
    f4v ac2[8] = {};
    #pragma unroll
    for (int k0 = 0; k0 < 64; k0 += 32) {
        h8v a = *(h8v*)&lvt[w * 16 + lr][k0 + lg * 8];
        #pragma unroll
        for (int ct = 0; ct < 8; ++ct) {
            h8v bf = *(h8v*)&lktT[ct * 16 + lr][k0 + lg * 8];
            ac2[ct] = __builtin_amdgcn_mfma_f32_16x16x32_f16(a, bf, ac2[ct], 0, 0, 0);
        }
    }
    const size_t obase = ((size_t)bh * NCH + c) * (HDIM * NFEAT);
    #pragma unroll
    for (int ct = 0; ct < 8; ++ct)
        #pragma unroll
        for (int rg = 0; rg < 4; ++rg) {
            const int d = w * 16 + lg * 4 + rg, m = ct * 16 + lr;
            ssum16[obase + (size_t)d * NFEAT + m] = f2h(ac2[ct][rg]);
        }
    if (tid < 128) {
        float s = 0.f;
        #pragma unroll 8
        for (int i = 0; i < 64; ++i) s += h2f(lktT[tid][i]);
        kcsum[((size_t)bh * NCH + c) * NFEAT + tid] = s;
    }
    if (tid < 64) {
        float s = 0.f;
        #pragma unroll 8
        for (int i = 0; i < 64; ++i) s += h2f(lvt[tid][i]);
        vsum[((size_t)bh * NCH + c) * HDIM + tid] = s;
    }
}

// ---------------- prefix over chunks: applies fac_c; Spre fp16 + kc prefix ----------------
__global__ __launch_bounds__(256) void chunk_prefix(const ushort* __restrict__ ssum16,
                                                    ushort* __restrict__ spre,
                                                    const float* __restrict__ kcsum,
                                                    float* __restrict__ kcpre,
                                                    const float* __restrict__ blockmax,
                                                    const float* __restrict__ vsum) {
    const int bh = blockIdx.y, sl = blockIdx.x;
    const int tid = threadIdx.x;
    const int b = bh >> 4, h = bh & 15;
    __shared__ float gred[4];
    float mx = fmaxf(blockmax[tid], blockmax[tid + 256]);
    #pragma unroll
    for (int o = 32; o >= 1; o >>= 1) mx = fmaxf(mx, __shfl_xor(mx, o));
    if ((tid & 63) == 0) gred[tid >> 6] = mx;
    __syncthreads();
    const float gm = fmaxf(fmaxf(gred[0], gred[1]), fmaxf(gred[2], gred[3]));

    if (sl == 0 && tid < NFEAT) {
        float a = 0.f;
        for (int c = 0; c < NCH; ++c) {
            kcpre[((size_t)bh * NCH + c) * NFEAT + tid] = a;
            const float fac = expf(blockmax[h * 32 + b * 16 + c] - gm) * INV_SQRT_M;
            a += fac * kcsum[((size_t)bh * NCH + c) * NFEAT + tid] + 64.0f * 1e-4f;
        }
    }
    const int base_e = (sl * 256 + tid) * 8;
    const int d = base_e >> 7;
    float acc[8] = {};
    const size_t bb = (size_t)bh * NCH * (HDIM * NFEAT);
    for (int c = 0; c < NCH; ++c) {
        const size_t cb = bb + (size_t)c * (HDIM * NFEAT);
        const float fac = expf(blockmax[h * 32 + b * 16 + c] - gm) * INV_SQRT_M;
        const float vs = vsum[((size_t)bh * NCH + c) * HDIM + d];
        s8v v = *(const s8v*)&ssum16[cb + base_e];
        ushort o[8];
        #pragma unroll
        for (int j = 0; j < 8; ++j) o[j] = f2h(acc[j]);
        *(s8v*)&spre[cb + base_e] = *(s8v*)&o[0];
        #pragma unroll
        for (int j = 0; j < 8; ++j) acc[j] += fac * h2f(((ushort*)&v)[j]) + 1e-4f * vs;
    }
}

// ---------------- chunked causal attention via MFMA (att out fp16) ----------------
__global__ __launch_bounds__(256) void scan_final(const ushort* __restrict__ phiq,
                                                  const ushort* __restrict__ plocal,
                                                  const ushort* __restrict__ vt,
                                                  const ushort* __restrict__ spre,
                                                  const float* __restrict__ kcpre,
                                                  const float* __restrict__ blockmax,
                                                  ushort* __restrict__ att_h) {
    const int c = blockIdx.x, bh = blockIdx.y;
    const int b = bh >> 4, h = bh & 15;
    const int n0 = c * CSZ;
    __shared__ __attribute__((aligned(16))) ushort lq[64][136];
    __shared__ __attribute__((aligned(16))) ushort lk[64][136];
    __shared__ __attribute__((aligned(16))) ushort lvt[64][72];
    __shared__ __attribute__((aligned(16))) ushort lsp[64][136];
    __shared__ __attribute__((aligned(16))) ushort lA[64][72];
    __shared__ float kc[NFEAT];
    __shared__ float zin[64];
    __shared__ float zp[4][64];
    __shared__ float gred[4];
    const int tid = threadIdx.x;

    // inline gmax + this chunk's fac
    float mxv = fmaxf(blockmax[tid], blockmax[tid + 256]);
    #pragma unroll
    for (int o = 32; o >= 1; o >>= 1) mxv = fmaxf(mxv, __shfl_xor(mxv, o));
    if ((tid & 63) == 0) gred[tid >> 6] = mxv;
    __syncthreads();
    const float gm = fmaxf(fmaxf(gred[0], gred[1]), fmaxf(gred[2], gred[3]));
    const float fac = expf(blockmax[h * 32 + b * 16 + c] - gm) * INV_SQRT_M;

    const size_t qb = ((size_t)bh * NN + n0) * NFEAT;
    #pragma unroll
    for (int i = 0; i < 4; ++i) {
        const int idx = tid + 256 * i;
        const int r = idx >> 4, cs = (idx & 15) * 8;
        *(s8v*)&lq[r][cs] = *(const s8v*)&phiq[qb + (size_t)r * NFEAT + cs];
        s8v pv = *(const s8v*)&plocal[qb + (size_t)r * NFEAT + cs];
        ushort t[8];
        #pragma unroll
        for (int j = 0; j < 8; ++j) t[j] = f2h(h2f(((ushort*)&pv)[j]) * fac + 1e-4f);
        *(s8v*)&lk[r][cs] = *(s8v*)&t[0];
    }
    const size_t sb = ((size_t)bh * NCH + c) * (HDIM * NFEAT);
    #pragma unroll
    for (int i = 0; i < 4; ++i) {
        const int idx = tid + 256 * i;
        const int r = idx >> 4, cs = (idx & 15) * 8;
        *(s8v*)&lsp[r][cs] = *(const s8v*)&spre[sb + (size_t)r * NFEAT + cs];
    }
    {
        const int d = tid >> 2, s = (tid & 3) * 16;
        const size_t g = ((size_t)bh * HDIM + d) * NN + n0 + s;
        *(s8v*)&lvt[d][s]     = *(const s8v*)&vt[g];
        *(s8v*)&lvt[d][s + 8] = *(const s8v*)&vt[g + 8];
    }
    if (tid < NFEAT) kc[tid] = kcpre[((size_t)bh * NCH + c) * NFEAT + tid];
    __syncthreads();

    const int w = tid >> 6, l = tid & 63, lr = l & 15, lg = l >> 4;

    // Phase 1: A = phiq @ phik^T
    f4v a4[4] = {};
    #pragma unroll
    for (int k0 = 0; k0 < 128; k0 += 32) {
        h8v av = *(h8v*)&lq[w * 16 + lr][k0 + lg * 8];
        #pragma unroll
        for (int ct = 0; ct < 4; ++ct) {
            h8v bv = *(h8v*)&lk[ct * 16 + lr][k0 + lg * 8];
            a4[ct] = __builtin_amdgcn_mfma_f32_16x16x32_f16(av, bv, a4[ct], 0, 0, 0);
        }
    }
    float zi[4] = {0.f, 0.f, 0.f, 0.f};
    #pragma unroll
    for (int ct = 0; ct < 4; ++ct) {
        #pragma unroll
        for (int rg = 0; rg < 4; ++rg) {
            const int row = w * 16 + lg * 4 + rg;
            const int col = ct * 16 + lr;
            const float val = (col <= row) ? a4[ct][rg] : 0.f;
            const ushort hq = f2h(val);
            zi[rg] += h2f(hq);
            lA[row][col] = hq;
        }
    }
    #pragma unroll
    for (int rg = 0; rg < 4; ++rg) {
        float z = zi[rg];
        z += __shfl_xor(z, 1); z += __shfl_xor(z, 2);
        z += __shfl_xor(z, 4); z += __shfl_xor(z, 8);
        if (lr == 0) zin[w * 16 + lg * 4 + rg] = z;
    }
    {
        const int row = tid & 63, qq = tid >> 6;
        float s = 0.f;
        #pragma unroll 8
        for (int m = 0; m < 32; ++m) s += h2f(lq[row][qq * 32 + m]) * kc[qq * 32 + m];
        zp[qq][row] = s;
    }
    __syncthreads();

    // Phase 2: out = Amask @ V + phiq @ Spre
    f4v o4[4] = {};
    #pragma unroll
    for (int k0 = 0; k0 < 64; k0 += 32) {
        h8v av = *(h8v*)&lA[w * 16 + lr][k0 + lg * 8];
        #pragma unroll
        for (int ct = 0; ct < 4; ++ct) {
            h8v bv = *(h8v*)&lvt[ct * 16 + lr][k0 + lg * 8];
            o4[ct] = __builtin_amdgcn_mfma_f32_16x16x32_f16(av, bv, o4[ct], 0, 0, 0);
        }
    }
    #pragma unroll
    for (int k0 = 0; k0 < 128; k0 += 32) {
        h8v av = *(h8v*)&lq[w * 16 + lr][k0 + lg * 8];
        #pragma unroll
        for (int ct = 0; ct < 4; ++ct) {
            h8v bv = *(h8v*)&lsp[ct * 16 + lr][k0 + lg * 8];
            o4[ct] = __builtin_amdgcn_mfma_f32_16x16x32_f16(av, bv, o4[ct], 0, 0, 0);
        }
    }
    #pragma unroll
    for (int rg = 0; rg < 4; ++rg) {
        const int row = w * 16 + lg * 4 + rg;
        const float z = zin[row] + zp[0][row] + zp[1][row] + zp[2][row] + zp[3][row] + 1e-6f;
        const float rz = 1.f / z;
        #pragma unroll
        for (int ct = 0; ct < 4; ++ct) {
            const int d = ct * 16 + lr;
            att_h[((size_t)(b * NN + n0 + row)) * DIMS + h * HDIM + d] = f2h(o4[ct][rg] * rz);
        }
    }
}

extern "C" void kernel_launch(void* const* d_in, const int* in_sizes, int n_in,
                              void* d_out, int out_size, void* d_ws, size_t ws_size,
                              hipStream_t stream) {
    const float* x     = (const float*)d_in[0];
    const float* omega = (const float*)d_in[1];
    const float* Wq    = (const float*)d_in[2];
    const float* Wk    = (const float*)d_in[3];
    const float* Wv    = (const float*)d_in[4];
    const float* Wo    = (const float*)d_in[5];
    const float* bo    = (const float*)d_in[6];
    float* out = (float*)d_out;

    const size_t PROJ = (size_t)BN * DIMS;                 // 2M elems
    const size_t PHI  = (size_t)BB * NHEADS * NN * NFEAT;  // 4M elems
    ushort* qkvh    = (ushort*)d_ws;                       // 12 MB
    ushort* xh      = qkvh + (size_t)BN * QKVN;            // 4 MB
    ushort* wqkvh   = xh + PROJ;                           // 6 MB
    ushort* woh     = wqkvh + (size_t)QKVN * DIMS;         // 2 MB
    ushort* omh     = woh + WW;                            // 16 KB
    ushort* phiq_h  = omh + NFEAT * HDIM;                  // 8 MB
    ushort* plocal  = phiq_h + PHI;                        // 8 MB
    ushort* vt_h    = plocal + PHI;                        // 4 MB
    ushort* ssum16  = vt_h + PROJ;                         // 8 MB
    ushort* spre_h  = ssum16 + PHI;                        // 8 MB
    ushort* att_hb  = spre_h + PHI;                        // 4 MB
    float*  kcsum   = (float*)(att_hb + PROJ);
    float*  kcpre   = kcsum + 32 * NCH * NFEAT;
    float*  blockmax= kcpre + 32 * NCH * NFEAT;            // 512
    float*  vsum    = blockmax + 512;                      // 32*16*64

    // 1: fused casts (x, Wq,k,v, Wo, omega)
    cast_all<<<(NX + 4 * NW + NOM) / 256, 256, 0, stream>>>(x, Wq, Wk, Wv, Wo, omega,
                                                            xh, wqkvh, woh, omh);

    // 2: fused QKV projection -> fp16 [2048 x 3072]; 768 blocks = 3/CU
    gemm_nt_lds<64, true><<<(BN / 64) * (QKVN / 128), 256, 0, stream>>>(
        xh, wqkvh, nullptr, qkvh, nullptr, BN, QKVN, DIMS, BN / 64);

    // 3: fused phi (q) + phi/V-transpose/chunk-sums (k)
    dim3 pg(BN / 64, NHEADS, 2);     // (32, 16, 2)
    phi_mfma<<<pg, 256, 0, stream>>>(qkvh, omh, phiq_h, plocal, blockmax,
                                     vt_h, ssum16, kcsum, vsum);

    // 4: prefixes (applies fac_c; Spre + kc)
    chunk_prefix<<<dim3(4, BB * NHEADS), 256, 0, stream>>>(ssum16, spre_h, kcsum, kcpre,
                                                           blockmax, vsum);
    // 5: causal attention
    dim3 cg(NCH, BB * NHEADS);
    scan_final<<<cg, 256, 0, stream>>>(phiq_h, plocal, vt_h, spre_h, kcpre,
                                       blockmax, att_hb);

    // 6: output projection straight to d_out
    gemm_nt_lds<64, false><<<(BN / 64) * (DIMS / 128), 256, 0, stream>>>(
        att_hb, woh, out, nullptr, bo, BN, DIMS, DIMS, BN / 64);
}

// Round 12
// 86.262 us; speedup vs baseline: 7.7441x; 1.0319x over previous
//
#include <hip/hip_runtime.h>
#include <hip/hip_bf16.h>
#include <math.h>

#define DIMS 1024
#define NHEADS 16
#define HDIM 64
#define NFEAT 128
#define BB 2
#define NN 1024
#define BN (BB*NN)   // 2048
#define NCH 16       // chunks per (b,h)
#define CSZ 64       // chunk size
#define WW (DIMS*DIMS)
#define QKVN (3*DIMS) // 3072

#define SCALE 0.3535533905932738f       // 64^-0.25
#define INV_SQRT_M 0.08838834764831845f // 1/sqrt(128)

typedef __attribute__((ext_vector_type(8))) _Float16 h8v;  // 8 fp16 (4 VGPRs)
typedef __attribute__((ext_vector_type(8))) short s8v;     // raw 16B
typedef __attribute__((ext_vector_type(4))) float f4v;     // mfma accumulator

__device__ __forceinline__ ushort f2h(float x) {
    _Float16 h = (_Float16)x;
    return *(ushort*)&h;
}
__device__ __forceinline__ float h2f(ushort u) {
    _Float16 h = *(_Float16*)&u;
    return (float)h;
}
__device__ __forceinline__ void gload16(const void* g, void* l) {
    __builtin_amdgcn_global_load_lds(
        (const __attribute__((address_space(1))) unsigned int*)g,
        (__attribute__((address_space(3))) unsigned int*)l,
        16, 0, 0);
}

// ---------------- fused cast f32 -> fp16 for x, Wq,k,v, Wo, omega ----------------
#define NX (BN*DIMS/8)   // 262144
#define NW (WW/8)        // 131072
#define NOM (NFEAT*HDIM/8) // 1024
__global__ __launch_bounds__(256) void cast_all(const float* __restrict__ x,
                                                const float* __restrict__ Wq,
                                                const float* __restrict__ Wk,
                                                const float* __restrict__ Wv,
                                                const float* __restrict__ Wo,
                                                const float* __restrict__ omega,
                                                ushort* __restrict__ xh,
                                                ushort* __restrict__ wqkvh,
                                                ushort* __restrict__ woh,
                                                ushort* __restrict__ omh) {
    const int i = blockIdx.x * 256 + threadIdx.x;
    const float* src; ushort* dst; int off;
    if (i < NX)               { src = x;     dst = xh;                     off = i; }
    else if (i < NX + NW)     { src = Wq;    dst = wqkvh;                  off = i - NX; }
    else if (i < NX + 2 * NW) { src = Wk;    dst = wqkvh + WW;             off = i - NX - NW; }
    else if (i < NX + 3 * NW) { src = Wv;    dst = wqkvh + 2 * (size_t)WW; off = i - NX - 2 * NW; }
    else if (i < NX + 4 * NW) { src = Wo;    dst = woh;                    off = i - NX - 3 * NW; }
    else                      { src = omega; dst = omh;                    off = i - NX - 4 * NW; }
    float4 a = ((const float4*)src)[2 * (size_t)off];
    float4 b = ((const float4*)src)[2 * (size_t)off + 1];
    float v[8] = {a.x, a.y, a.z, a.w, b.x, b.y, b.z, b.w};
    ushort h8[8];
    #pragma unroll
    for (int j = 0; j < 8; ++j) h8[j] = f2h(v[j]);
    *(s8v*)&dst[(size_t)off * 8] = *(s8v*)&h8[0];
}

// ---------------- MFMA GEMM NT; BK=64, swizzled LDS (pre-swizzled source + XOR read) ----------------
// XCD-bijective 1D grid (nwg % 8 == 0). Swizzle: LDS (row, slot) holds global (row, slot^(row&7)).
template<int BM, bool HOUT>
__global__ __launch_bounds__(256) void gemm_nt_lds(const ushort* __restrict__ A,
                                                   const ushort* __restrict__ B,
                                                   float* __restrict__ C,
                                                   ushort* __restrict__ C16,
                                                   const float* __restrict__ bias,
                                                   int M, int N, int K, int nbx) {
    constexpr int MF = BM / 32;
    constexpr int AI = BM / 32;   // A stage issues per wave (8 rows each)
    __shared__ __attribute__((aligned(16))) ushort lA[BM][64];
    __shared__ __attribute__((aligned(16))) ushort lB[128][64];
    const int tid = threadIdx.x;
    const int w = tid >> 6, l = tid & 63, lr = l & 15, lg = l >> 4;
    const int wm = (w >> 1) * (BM / 2), wn = (w & 1) * 64;
    const int nwg = gridDim.x;
    const int q8 = nwg >> 3;
    const int neu = (blockIdx.x & 7) * q8 + (blockIdx.x >> 3);
    const int bx = neu % nbx, by = neu / nbx;
    const int bi = bx * BM, bj = by * 128;
    const int srow = l >> 3;                      // 0..7 within an 8-row issue
    const int scol = ((l & 7) ^ (l >> 3)) * 8;    // inverse-swizzled source slot

    f4v acc[MF][4] = {};
    for (int k0 = 0; k0 < K; k0 += 64) {
        #pragma unroll
        for (int i = 0; i < AI; ++i) {
            const int r0 = w * (8 * AI) + i * 8;
            gload16(&A[(size_t)(bi + r0 + srow) * K + k0 + scol], &lA[r0][0]);
        }
        #pragma unroll
        for (int i = 0; i < 4; ++i) {
            const int r0 = w * 32 + i * 8;
            gload16(&B[(size_t)(bj + r0 + srow) * K + k0 + scol], &lB[r0][0]);
        }
        __syncthreads();
        #pragma unroll
        for (int kk = 0; kk < 2; ++kk) {
            const int soff = ((kk * 4 + lg) ^ (lr & 7)) * 8;   // swizzled read slot
            h8v b_[4];
            #pragma unroll
            for (int j = 0; j < 4; ++j) b_[j] = *(h8v*)&lB[wn + j * 16 + lr][soff];
            #pragma unroll
            for (int i = 0; i < MF; ++i) {
                h8v a_ = *(h8v*)&lA[wm + i * 16 + lr][soff];
                #pragma unroll
                for (int j = 0; j < 4; ++j)
                    acc[i][j] = __builtin_amdgcn_mfma_f32_16x16x32_f16(a_, b_[j], acc[i][j], 0, 0, 0);
            }
        }
        __syncthreads();
    }
    #pragma unroll
    for (int i = 0; i < MF; ++i)
        #pragma unroll
        for (int j = 0; j < 4; ++j)
            #pragma unroll
            for (int rg = 0; rg < 4; ++rg) {
                const int row = bi + wm + i * 16 + lg * 4 + rg;
                const int col = bj + wn + j * 16 + lr;
                if (HOUT) {
                    C16[(size_t)row * N + col] = f2h(acc[i][j][rg]);
                } else {
                    float r = acc[i][j][rg] + bias[col];
                    C[(size_t)row * N + col] = r;
                }
            }
}

// ---------------- fused phi + (key path) chunk sums ----------------
__global__ __launch_bounds__(256) void phi_mfma(const ushort* __restrict__ qkvh,
                                                const ushort* __restrict__ omh,
                                                ushort* __restrict__ phiq,
                                                ushort* __restrict__ plocal,
                                                float* __restrict__ blockmax,
                                                ushort* __restrict__ vt,
                                                ushort* __restrict__ ssum16,
                                                float* __restrict__ kcsum,
                                                float* __restrict__ vsum) {
    __shared__ __attribute__((aligned(16))) ushort lq[64][72];
    __shared__ __attribute__((aligned(16))) ushort lom[128 * 72]; // omega; reused as staging [64][136]
    __shared__ __attribute__((aligned(16))) ushort lktT[128][72]; // plocal^T (z=1)
    __shared__ __attribute__((aligned(16))) ushort lv[64][72];    // V rows (z=1)
    __shared__ __attribute__((aligned(16))) ushort lvt[64][72];   // V^T (z=1)
    __shared__ float lnorm[64];
    __shared__ float wred[4];
    const int tid = threadIdx.x;
    const int z = blockIdx.z, h = blockIdx.y;
    const int bn0 = blockIdx.x * 64;
    const int w = tid >> 6, l = tid & 63, lr = l & 15, lg = l >> 4;
    const int b = blockIdx.x >> 4, c = blockIdx.x & 15;
    const int bh = b * NHEADS + h;

    {
        const int r = tid >> 2, c0 = (tid & 3) * 16;
        const size_t g = (size_t)(bn0 + r) * QKVN + (size_t)z * DIMS + h * HDIM + c0;
        s8v v0 = *(const s8v*)&qkvh[g];
        s8v v1 = *(const s8v*)&qkvh[g + 8];
        *(s8v*)&lq[r][c0] = v0;
        *(s8v*)&lq[r][c0 + 8] = v1;
        float p = 0.f;
        #pragma unroll
        for (int j = 0; j < 8; ++j) {
            float a = h2f(((ushort*)&v0)[j]); p += a * a;
            float bb2 = h2f(((ushort*)&v1)[j]); p += bb2 * bb2;
        }
        p += __shfl_xor(p, 1); p += __shfl_xor(p, 2);
        if ((tid & 3) == 0) lnorm[r] = p;
    }
    {
        const int m = tid >> 1, c0 = (tid & 1) * 32;
        #pragma unroll
        for (int i = 0; i < 4; ++i)
            *(s8v*)&lom[m * 72 + c0 + i * 8] = *(const s8v*)&omh[m * HDIM + c0 + i * 8];
    }
    if (z == 1) {
        const int r = tid >> 2, c0 = (tid & 3) * 16;
        const size_t g = (size_t)(bn0 + r) * QKVN + 2 * DIMS + h * HDIM + c0;
        *(s8v*)&lv[r][c0]     = *(const s8v*)&qkvh[g];
        *(s8v*)&lv[r][c0 + 8] = *(const s8v*)&qkvh[g + 8];
    }
    __syncthreads();

    f4v acc[8] = {};
    #pragma unroll
    for (int k0 = 0; k0 < 64; k0 += 32) {
        h8v a = *(h8v*)&lq[w * 16 + lr][k0 + lg * 8];
        #pragma unroll
        for (int ct = 0; ct < 8; ++ct) {
            h8v bo = *(h8v*)&lom[(ct * 16 + lr) * 72 + k0 + lg * 8];
            acc[ct] = __builtin_amdgcn_mfma_f32_16x16x32_f16(a, bo, acc[ct], 0, 0, 0);
        }
    }

    const float hs2 = 0.5f * SCALE * SCALE;
    float lvv[4][8];
    #pragma unroll
    for (int rg = 0; rg < 4; ++rg) {
        const int row = w * 16 + lg * 4 + rg;
        const float nh = hs2 * lnorm[row];
        #pragma unroll
        for (int ct = 0; ct < 8; ++ct) lvv[rg][ct] = SCALE * acc[ct][rg] - nh;
    }
    if (z == 1) {
        float bmax = -3.4e38f;
        #pragma unroll
        for (int rg = 0; rg < 4; ++rg)
            #pragma unroll
            for (int ct = 0; ct < 8; ++ct) bmax = fmaxf(bmax, lvv[rg][ct]);
        #pragma unroll
        for (int o = 32; o >= 1; o >>= 1) bmax = fmaxf(bmax, __shfl_xor(bmax, o));
        if (l == 0) wred[w] = bmax;
    }
    __syncthreads();   // lom (omega) free + wred ready

    if (z == 0) {
        #pragma unroll
        for (int rg = 0; rg < 4; ++rg) {
            const int row = w * 16 + lg * 4 + rg;
            float mx = -3.4e38f;
            #pragma unroll
            for (int ct = 0; ct < 8; ++ct) mx = fmaxf(mx, lvv[rg][ct]);
            #pragma unroll
            for (int o = 8; o >= 1; o >>= 1) mx = fmaxf(mx, __shfl_xor(mx, o));
            #pragma unroll
            for (int ct = 0; ct < 8; ++ct)
                lom[row * 136 + ct * 16 + lr] = f2h(expf(lvv[rg][ct] - mx) * INV_SQRT_M + 1e-4f);
        }
    } else {
        const float bm = fmaxf(fmaxf(wred[0], wred[1]), fmaxf(wred[2], wred[3]));
        if (tid == 0) blockmax[h * 32 + blockIdx.x] = bm;
        #pragma unroll
        for (int rg = 0; rg < 4; ++rg) {
            const int row = w * 16 + lg * 4 + rg;
            #pragma unroll
            for (int ct = 0; ct < 8; ++ct)
                lom[row * 136 + ct * 16 + lr] = f2h(expf(lvv[rg][ct] - bm));
        }
    }
    __syncthreads();

    {
        ushort* dst = (z == 0) ? phiq : plocal;
        const int r = tid >> 2, c0 = (tid & 3) * 32;
        const int br = bn0 + r;
        const int bb2 = br >> 10, n = br & (NN - 1);
        const size_t og = ((size_t)(bb2 * NHEADS + h) * NN + n) * NFEAT;
        #pragma unroll
        for (int i = 0; i < 4; ++i)
            *(s8v*)&dst[og + c0 + i * 8] = *(s8v*)&lom[r * 136 + c0 + i * 8];
    }
    if (z == 0) return;

    // plocal^T -> lktT
    {
        const int m = tid >> 1, nh2 = (tid & 1) * 32;
        ushort tp[32];
        #pragma unroll
        for (int i = 0; i < 32; ++i) tp[i] = lom[(nh2 + i) * 136 + m];
        #pragma unroll
        for (int i = 0; i < 4; ++i) *(s8v*)&lktT[m][nh2 + i * 8] = *(s8v*)&tp[i * 8];
    }
    // V^T -> global + LDS
    {
        const int d = tid >> 2, s0 = (tid & 3) * 16;
        ushort tp[16];
        #pragma unroll
        for (int i = 0; i < 16; ++i) tp[i] = lv[s0 + i][d];
        const size_t tb = ((size_t)bh * HDIM + d) * NN + c * CSZ + s0;
        *(s8v*)&vt[tb] = *(s8v*)&tp[0];
        *(s8v*)&vt[tb + 8] = *(s8v*)&tp[8];
        *(s8v*)&lvt[d][s0] = *(s8v*)&tp[0];
        *(s8v*)&lvt[d][s0 + 8] = *(s8v*)&tp[8];
    }
    __syncthreads();

    // ssum_raw[d][m] = sum_n V[n,d]*plocal[n,m]
    f4v ac2[8] = {};
    #pragma unroll
    for (int k0 = 0; k0 < 64; k0 += 32) {
        h8v a = *(h8v*)&lvt[w * 16 + lr][k0 + lg * 8];
        #pragma unroll
        for (int ct = 0; ct < 8; ++ct) {
            h8v bf = *(h8v*)&lktT[ct * 16 + lr][k0 + lg * 8];
            ac2[ct] = __builtin_amdgcn_mfma_f32_16x16x32_f16(a, bf, ac2[ct], 0, 0, 0);
        }
    }
    const size_t obase = ((size_t)bh * NCH + c) * (HDIM * NFEAT);
    #pragma unroll
    for (int ct = 0; ct < 8; ++ct)
        #pragma unroll
        for (int rg = 0; rg < 4; ++rg) {
            const int d = w * 16 + lg * 4 + rg, m = ct * 16 + lr;
            ssum16[obase + (size_t)d * NFEAT + m] = f2h(ac2[ct][rg]);
        }
    if (tid < 128) {
        float s = 0.f;
        #pragma unroll 8
        for (int i = 0; i < 64; ++i) s += h2f(lktT[tid][i]);
        kcsum[((size_t)bh * NCH + c) * NFEAT + tid] = s;
    }
    if (tid < 64) {
        float s = 0.f;
        #pragma unroll 8
        for (int i = 0; i < 64; ++i) s += h2f(lvt[tid][i]);
        vsum[((size_t)bh * NCH + c) * HDIM + tid] = s;
    }
}

// ---------------- chunked causal attention via MFMA; inline chunk prefix ----------------
__global__ __launch_bounds__(256) void scan_final(const ushort* __restrict__ phiq,
                                                  const ushort* __restrict__ plocal,
                                                  const ushort* __restrict__ vt,
                                                  const ushort* __restrict__ ssum16,
                                                  const float* __restrict__ kcsum,
                                                  const float* __restrict__ vsum,
                                                  const float* __restrict__ blockmax,
                                                  ushort* __restrict__ att_h) {
    const int c = blockIdx.x, bh = blockIdx.y;
    const int b = bh >> 4, h = bh & 15;
    const int n0 = c * CSZ;
    __shared__ __attribute__((aligned(16))) ushort lq[64][136];
    __shared__ __attribute__((aligned(16))) ushort lk[64][136];
    __shared__ __attribute__((aligned(16))) ushort lvt[64][72];
    __shared__ __attribute__((aligned(16))) ushort lsp[64][136];
    __shared__ __attribute__((aligned(16))) ushort lA[64][72];
    __shared__ float kc[NFEAT];
    __shared__ float zin[64];
    __shared__ float zp[4][64];
    __shared__ float gred[4];
    const int tid = threadIdx.x;

    // inline gmax
    float mxv = fmaxf(blockmax[tid], blockmax[tid + 256]);
    #pragma unroll
    for (int o = 32; o >= 1; o >>= 1) mxv = fmaxf(mxv, __shfl_xor(mxv, o));
    if ((tid & 63) == 0) gred[tid >> 6] = mxv;
    __syncthreads();
    const float gm = fmaxf(fmaxf(gred[0], gred[1]), fmaxf(gred[2], gred[3]));
    const float fac = expf(blockmax[h * 32 + b * 16 + c] - gm) * INV_SQRT_M;

    const size_t qb = ((size_t)bh * NN + n0) * NFEAT;
    #pragma unroll
    for (int i = 0; i < 4; ++i) {
        const int idx = tid + 256 * i;
        const int r = idx >> 4, cs = (idx & 15) * 8;
        *(s8v*)&lq[r][cs] = *(const s8v*)&phiq[qb + (size_t)r * NFEAT + cs];
        s8v pv = *(const s8v*)&plocal[qb + (size_t)r * NFEAT + cs];
        ushort t[8];
        #pragma unroll
        for (int j = 0; j < 8; ++j) t[j] = f2h(h2f(((ushort*)&pv)[j]) * fac + 1e-4f);
        *(s8v*)&lk[r][cs] = *(s8v*)&t[0];
    }
    // on-the-fly Spre: acc[d][m] = sum_{c'<c} fac_c'*ssum_raw + 1e-4*vsum
    {
        const int d = tid >> 2;            // 0..63
        const int m0 = (tid & 3) * 32;     // 32 cols per thread
        float acc[32] = {};
        float vs_tot = 0.f;
        for (int cp = 0; cp < c; ++cp) {
            const float facp = expf(blockmax[h * 32 + b * 16 + cp] - gm) * INV_SQRT_M;
            vs_tot += vsum[((size_t)bh * NCH + cp) * HDIM + d];
            const size_t cb = ((size_t)bh * NCH + cp) * (HDIM * NFEAT) + (size_t)d * NFEAT + m0;
            #pragma unroll
            for (int i = 0; i < 4; ++i) {
                s8v v = *(const s8v*)&ssum16[cb + i * 8];
                #pragma unroll
                for (int j = 0; j < 8; ++j) acc[i * 8 + j] += facp * h2f(((ushort*)&v)[j]);
            }
        }
        const float vadd = 1e-4f * vs_tot;
        ushort o[32];
        #pragma unroll
        for (int i = 0; i < 32; ++i) o[i] = f2h(acc[i] + vadd);
        #pragma unroll
        for (int i = 0; i < 4; ++i) *(s8v*)&lsp[d][m0 + i * 8] = *(s8v*)&o[i * 8];
    }
    // on-the-fly kc prefix
    if (tid < NFEAT) {
        float a = 0.f;
        for (int cp = 0; cp < c; ++cp) {
            const float facp = expf(blockmax[h * 32 + b * 16 + cp] - gm) * INV_SQRT_M;
            a += facp * kcsum[((size_t)bh * NCH + cp) * NFEAT + tid] + 64.0f * 1e-4f;
        }
        kc[tid] = a;
    }
    {
        const int d = tid >> 2, s = (tid & 3) * 16;
        const size_t g = ((size_t)bh * HDIM + d) * NN + n0 + s;
        *(s8v*)&lvt[d][s]     = *(const s8v*)&vt[g];
        *(s8v*)&lvt[d][s + 8] = *(const s8v*)&vt[g + 8];
    }
    __syncthreads();

    const int w = tid >> 6, l = tid & 63, lr = l & 15, lg = l >> 4;

    // Phase 1: A = phiq @ phik^T
    f4v a4[4] = {};
    #pragma unroll
    for (int k0 = 0; k0 < 128; k0 += 32) {
        h8v av = *(h8v*)&lq[w * 16 + lr][k0 + lg * 8];
        #pragma unroll
        for (int ct = 0; ct < 4; ++ct) {
            h8v bv = *(h8v*)&lk[ct * 16 + lr][k0 + lg * 8];
            a4[ct] = __builtin_amdgcn_mfma_f32_16x16x32_f16(av, bv, a4[ct], 0, 0, 0);
        }
    }
    float zi[4] = {0.f, 0.f, 0.f, 0.f};
    #pragma unroll
    for (int ct = 0; ct < 4; ++ct) {
        #pragma unroll
        for (int rg = 0; rg < 4; ++rg) {
            const int row = w * 16 + lg * 4 + rg;
            const int col = ct * 16 + lr;
            const float val = (col <= row) ? a4[ct][rg] : 0.f;
            const ushort hq = f2h(val);
            zi[rg] += h2f(hq);
            lA[row][col] = hq;
        }
    }
    #pragma unroll
    for (int rg = 0; rg < 4; ++rg) {
        float z = zi[rg];
        z += __shfl_xor(z, 1); z += __shfl_xor(z, 2);
        z += __shfl_xor(z, 4); z += __shfl_xor(z, 8);
        if (lr == 0) zin[w * 16 + lg * 4 + rg] = z;
    }
    {
        const int row = tid & 63, qq = tid >> 6;
        float s = 0.f;
        #pragma unroll 8
        for (int m = 0; m < 32; ++m) s += h2f(lq[row][qq * 32 + m]) * kc[qq * 32 + m];
        zp[qq][row] = s;
    }
    __syncthreads();

    // Phase 2: out = Amask @ V + phiq @ Spre
    f4v o4[4] = {};
    #pragma unroll
    for (int k0 = 0; k0 < 64; k0 += 32) {
        h8v av = *(h8v*)&lA[w * 16 + lr][k0 + lg * 8];
        #pragma unroll
        for (int ct = 0; ct < 4; ++ct) {
            h8v bv = *(h8v*)&lvt[ct * 16 + lr][k0 + lg * 8];
            o4[ct] = __builtin_amdgcn_mfma_f32_16x16x32_f16(av, bv, o4[ct], 0, 0, 0);
        }
    }
    #pragma unroll
    for (int k0 = 0; k0 < 128; k0 += 32) {
        h8v av = *(h8v*)&lq[w * 16 + lr][k0 + lg * 8];
        #pragma unroll
        for (int ct = 0; ct < 4; ++ct) {
            h8v bv = *(h8v*)&lsp[ct * 16 + lr][k0 + lg * 8];
            o4[ct] = __builtin_amdgcn_mfma_f32_16x16x32_f16(av, bv, o4[ct], 0, 0, 0);
        }
    }
    #pragma unroll
    for (int rg = 0; rg < 4; ++rg) {
        const int row = w * 16 + lg * 4 + rg;
        const float z = zin[row] + zp[0][row] + zp[1][row] + zp[2][row] + zp[3][row] + 1e-6f;
        const float rz = 1.f / z;
        #pragma unroll
        for (int ct = 0; ct < 4; ++ct) {
            const int d = ct * 16 + lr;
            att_h[((size_t)(b * NN + n0 + row)) * DIMS + h * HDIM + d] = f2h(o4[ct][rg] * rz);
        }
    }
}

extern "C" void kernel_launch(void* const* d_in, const int* in_sizes, int n_in,
                              void* d_out, int out_size, void* d_ws, size_t ws_size,
                              hipStream_t stream) {
    const float* x     = (const float*)d_in[0];
    const float* omega = (const float*)d_in[1];
    const float* Wq    = (const float*)d_in[2];
    const float* Wk    = (const float*)d_in[3];
    const float* Wv    = (const float*)d_in[4];
    const float* Wo    = (const float*)d_in[5];
    const float* bo    = (const float*)d_in[6];
    float* out = (float*)d_out;

    const size_t PROJ = (size_t)BN * DIMS;                 // 2M elems
    const size_t PHI  = (size_t)BB * NHEADS * NN * NFEAT;  // 4M elems
    ushort* qkvh    = (ushort*)d_ws;                       // 12 MB
    ushort* xh      = qkvh + (size_t)BN * QKVN;            // 4 MB
    ushort* wqkvh   = xh + PROJ;                           // 6 MB
    ushort* woh     = wqkvh + (size_t)QKVN * DIMS;         // 2 MB
    ushort* omh     = woh + WW;                            // 16 KB
    ushort* phiq_h  = omh + NFEAT * HDIM;                  // 8 MB
    ushort* plocal  = phiq_h + PHI;                        // 8 MB
    ushort* vt_h    = plocal + PHI;                        // 4 MB
    ushort* ssum16  = vt_h + PROJ;                         // 8 MB
    ushort* att_hb  = ssum16 + PHI;                        // 4 MB
    float*  kcsum   = (float*)(att_hb + PROJ);             // 256 KB
    float*  blockmax= kcsum + 32 * NCH * NFEAT;            // 512
    float*  vsum    = blockmax + 512;                      // 32*16*64

    // 1: fused casts (x, Wq,k,v, Wo, omega)
    cast_all<<<(NX + 4 * NW + NOM) / 256, 256, 0, stream>>>(x, Wq, Wk, Wv, Wo, omega,
                                                            xh, wqkvh, woh, omh);

    // 2: fused QKV projection -> fp16 [2048 x 3072]; BK=64, 768 blocks = 3/CU
    gemm_nt_lds<64, true><<<(BN / 64) * (QKVN / 128), 256, 0, stream>>>(
        xh, wqkvh, nullptr, qkvh, nullptr, BN, QKVN, DIMS, BN / 64);

    // 3: fused phi (q) + phi/V-transpose/chunk-sums (k)
    dim3 pg(BN / 64, NHEADS, 2);     // (32, 16, 2)
    phi_mfma<<<pg, 256, 0, stream>>>(qkvh, omh, phiq_h, plocal, blockmax,
                                     vt_h, ssum16, kcsum, vsum);

    // 4: causal attention with inline chunk prefix
    dim3 cg(NCH, BB * NHEADS);
    scan_final<<<cg, 256, 0, stream>>>(phiq_h, plocal, vt_h, ssum16, kcsum, vsum,
                                       blockmax, att_hb);

    // 5: output projection straight to d_out; BK=64
    gemm_nt_lds<64, false><<<(BN / 64) * (DIMS / 128), 256, 0, stream>>>(
        att_hb, woh, out, nullptr, bo, BN, DIMS, DIMS, BN / 64);
}

// Round 13
// 80.314 us; speedup vs baseline: 8.3176x; 1.0741x over previous
//
#include <hip/hip_runtime.h>
#include <hip/hip_bf16.h>
#include <math.h>

#define DIMS 1024
#define NHEADS 16
#define HDIM 64
#define NFEAT 128
#define BB 2
#define NN 1024
#define BN (BB*NN)   // 2048
#define NCH 16       // chunks per (b,h)
#define CSZ 64       // chunk size
#define WW (DIMS*DIMS)
#define QKVN (3*DIMS) // 3072

#define SCALE 0.3535533905932738f       // 64^-0.25
#define INV_SQRT_M 0.08838834764831845f // 1/sqrt(128)

typedef __attribute__((ext_vector_type(8))) _Float16 h8v;  // 8 fp16 (4 VGPRs)
typedef __attribute__((ext_vector_type(8))) short s8v;     // raw 16B
typedef __attribute__((ext_vector_type(4))) float f4v;     // mfma accumulator

__device__ __forceinline__ ushort f2h(float x) {
    _Float16 h = (_Float16)x;
    return *(ushort*)&h;
}
__device__ __forceinline__ float h2f(ushort u) {
    _Float16 h = *(_Float16*)&u;
    return (float)h;
}
__device__ __forceinline__ void gload16(const void* g, void* l) {
    __builtin_amdgcn_global_load_lds(
        (const __attribute__((address_space(1))) unsigned int*)g,
        (__attribute__((address_space(3))) unsigned int*)l,
        16, 0, 0);
}

// ---------------- fused cast f32 -> fp16 for x, Wq,k,v, Wo, omega ----------------
#define NX (BN*DIMS/8)   // 262144
#define NW (WW/8)        // 131072
#define NOM (NFEAT*HDIM/8) // 1024
__global__ __launch_bounds__(256) void cast_all(const float* __restrict__ x,
                                                const float* __restrict__ Wq,
                                                const float* __restrict__ Wk,
                                                const float* __restrict__ Wv,
                                                const float* __restrict__ Wo,
                                                const float* __restrict__ omega,
                                                ushort* __restrict__ xh,
                                                ushort* __restrict__ wqkvh,
                                                ushort* __restrict__ woh,
                                                ushort* __restrict__ omh) {
    const int i = blockIdx.x * 256 + threadIdx.x;
    const float* src; ushort* dst; int off;
    if (i < NX)               { src = x;     dst = xh;                     off = i; }
    else if (i < NX + NW)     { src = Wq;    dst = wqkvh;                  off = i - NX; }
    else if (i < NX + 2 * NW) { src = Wk;    dst = wqkvh + WW;             off = i - NX - NW; }
    else if (i < NX + 3 * NW) { src = Wv;    dst = wqkvh + 2 * (size_t)WW; off = i - NX - 2 * NW; }
    else if (i < NX + 4 * NW) { src = Wo;    dst = woh;                    off = i - NX - 3 * NW; }
    else                      { src = omega; dst = omh;                    off = i - NX - 4 * NW; }
    float4 a = ((const float4*)src)[2 * (size_t)off];
    float4 b = ((const float4*)src)[2 * (size_t)off + 1];
    float v[8] = {a.x, a.y, a.z, a.w, b.x, b.y, b.z, b.w};
    ushort h8[8];
    #pragma unroll
    for (int j = 0; j < 8; ++j) h8[j] = f2h(v[j]);
    *(s8v*)&dst[(size_t)off * 8] = *(s8v*)&h8[0];
}

// ---------------- MFMA GEMM NT; BK=64, swizzled LDS; XCD-bijective 1D grid ----------------
template<int BM, bool HOUT>
__global__ __launch_bounds__(256) void gemm_nt_lds(const ushort* __restrict__ A,
                                                   const ushort* __restrict__ B,
                                                   float* __restrict__ C,
                                                   ushort* __restrict__ C16,
                                                   const float* __restrict__ bias,
                                                   int M, int N, int K, int nbx) {
    constexpr int MF = BM / 32;
    constexpr int AI = BM / 32;
    __shared__ __attribute__((aligned(16))) ushort lA[BM][64];
    __shared__ __attribute__((aligned(16))) ushort lB[128][64];
    const int tid = threadIdx.x;
    const int w = tid >> 6, l = tid & 63, lr = l & 15, lg = l >> 4;
    const int wm = (w >> 1) * (BM / 2), wn = (w & 1) * 64;
    const int nwg = gridDim.x;
    const int q8 = nwg >> 3;
    const int neu = (blockIdx.x & 7) * q8 + (blockIdx.x >> 3);
    const int bx = neu % nbx, by = neu / nbx;
    const int bi = bx * BM, bj = by * 128;
    const int srow = l >> 3;
    const int scol = ((l & 7) ^ (l >> 3)) * 8;

    f4v acc[MF][4] = {};
    for (int k0 = 0; k0 < K; k0 += 64) {
        #pragma unroll
        for (int i = 0; i < AI; ++i) {
            const int r0 = w * (8 * AI) + i * 8;
            gload16(&A[(size_t)(bi + r0 + srow) * K + k0 + scol], &lA[r0][0]);
        }
        #pragma unroll
        for (int i = 0; i < 4; ++i) {
            const int r0 = w * 32 + i * 8;
            gload16(&B[(size_t)(bj + r0 + srow) * K + k0 + scol], &lB[r0][0]);
        }
        __syncthreads();
        #pragma unroll
        for (int kk = 0; kk < 2; ++kk) {
            const int soff = ((kk * 4 + lg) ^ (lr & 7)) * 8;
            h8v b_[4];
            #pragma unroll
            for (int j = 0; j < 4; ++j) b_[j] = *(h8v*)&lB[wn + j * 16 + lr][soff];
            #pragma unroll
            for (int i = 0; i < MF; ++i) {
                h8v a_ = *(h8v*)&lA[wm + i * 16 + lr][soff];
                #pragma unroll
                for (int j = 0; j < 4; ++j)
                    acc[i][j] = __builtin_amdgcn_mfma_f32_16x16x32_f16(a_, b_[j], acc[i][j], 0, 0, 0);
            }
        }
        __syncthreads();
    }
    #pragma unroll
    for (int i = 0; i < MF; ++i)
        #pragma unroll
        for (int j = 0; j < 4; ++j)
            #pragma unroll
            for (int rg = 0; rg < 4; ++rg) {
                const int row = bi + wm + i * 16 + lg * 4 + rg;
                const int col = bj + wn + j * 16 + lr;
                if (HOUT) {
                    C16[(size_t)row * N + col] = f2h(acc[i][j][rg]);
                } else {
                    float r = acc[i][j][rg] + bias[col];
                    C[(size_t)row * N + col] = r;
                }
            }
}

// ---------------- phik_stats: k-path phi + chunk stats (no phiq/plocal stores) ----------------
// grid (32 = b*16+c, NHEADS). Emits blockmax, vt, ssum_raw (fp16), kcsum_raw, vsum.
__global__ __launch_bounds__(256) void phik_stats(const ushort* __restrict__ qkvh,
                                                  const ushort* __restrict__ omh,
                                                  float* __restrict__ blockmax,
                                                  ushort* __restrict__ vt,
                                                  ushort* __restrict__ ssum16,
                                                  float* __restrict__ kcsum,
                                                  float* __restrict__ vsum) {
    __shared__ __attribute__((aligned(16))) ushort lq[64][72];
    __shared__ __attribute__((aligned(16))) ushort lom[128 * 72]; // omega; reused as staging [64][136]
    __shared__ __attribute__((aligned(16))) ushort lktT[128][72];
    __shared__ __attribute__((aligned(16))) ushort lv[64][72];
    __shared__ __attribute__((aligned(16))) ushort lvt[64][72];
    __shared__ float lnorm[64];
    __shared__ float wred[4];
    const int tid = threadIdx.x;
    const int h = blockIdx.y;
    const int bn0 = blockIdx.x * 64;
    const int w = tid >> 6, l = tid & 63, lr = l & 15, lg = l >> 4;
    const int b = blockIdx.x >> 4, c = blockIdx.x & 15;
    const int bh = b * NHEADS + h;

    {
        const int r = tid >> 2, c0 = (tid & 3) * 16;
        const size_t g = (size_t)(bn0 + r) * QKVN + DIMS + h * HDIM + c0;  // k at +DIMS
        s8v v0 = *(const s8v*)&qkvh[g];
        s8v v1 = *(const s8v*)&qkvh[g + 8];
        *(s8v*)&lq[r][c0] = v0;
        *(s8v*)&lq[r][c0 + 8] = v1;
        float p = 0.f;
        #pragma unroll
        for (int j = 0; j < 8; ++j) {
            float a = h2f(((ushort*)&v0)[j]); p += a * a;
            float bb2 = h2f(((ushort*)&v1)[j]); p += bb2 * bb2;
        }
        p += __shfl_xor(p, 1); p += __shfl_xor(p, 2);
        if ((tid & 3) == 0) lnorm[r] = p;
    }
    {
        const int m = tid >> 1, c0 = (tid & 1) * 32;
        #pragma unroll
        for (int i = 0; i < 4; ++i)
            *(s8v*)&lom[m * 72 + c0 + i * 8] = *(const s8v*)&omh[m * HDIM + c0 + i * 8];
    }
    {
        const int r = tid >> 2, c0 = (tid & 3) * 16;
        const size_t g = (size_t)(bn0 + r) * QKVN + 2 * DIMS + h * HDIM + c0;
        *(s8v*)&lv[r][c0]     = *(const s8v*)&qkvh[g];
        *(s8v*)&lv[r][c0 + 8] = *(const s8v*)&qkvh[g + 8];
    }
    __syncthreads();

    f4v acc[8] = {};
    #pragma unroll
    for (int k0 = 0; k0 < 64; k0 += 32) {
        h8v a = *(h8v*)&lq[w * 16 + lr][k0 + lg * 8];
        #pragma unroll
        for (int ct = 0; ct < 8; ++ct) {
            h8v bo = *(h8v*)&lom[(ct * 16 + lr) * 72 + k0 + lg * 8];
            acc[ct] = __builtin_amdgcn_mfma_f32_16x16x32_f16(a, bo, acc[ct], 0, 0, 0);
        }
    }

    const float hs2 = 0.5f * SCALE * SCALE;
    float lvv[4][8];
    float bmax = -3.4e38f;
    #pragma unroll
    for (int rg = 0; rg < 4; ++rg) {
        const int row = w * 16 + lg * 4 + rg;
        const float nh = hs2 * lnorm[row];
        #pragma unroll
        for (int ct = 0; ct < 8; ++ct) {
            lvv[rg][ct] = SCALE * acc[ct][rg] - nh;
            bmax = fmaxf(bmax, lvv[rg][ct]);
        }
    }
    #pragma unroll
    for (int o = 32; o >= 1; o >>= 1) bmax = fmaxf(bmax, __shfl_xor(bmax, o));
    if (l == 0) wred[w] = bmax;
    __syncthreads();   // lom (omega) done + wred ready

    const float bm = fmaxf(fmaxf(wred[0], wred[1]), fmaxf(wred[2], wred[3]));
    if (tid == 0) blockmax[h * 32 + blockIdx.x] = bm;
    // stage p = exp(lvv - bm) into lom-as-[64][136]
    #pragma unroll
    for (int rg = 0; rg < 4; ++rg) {
        const int row = w * 16 + lg * 4 + rg;
        #pragma unroll
        for (int ct = 0; ct < 8; ++ct)
            lom[row * 136 + ct * 16 + lr] = f2h(expf(lvv[rg][ct] - bm));
    }
    __syncthreads();

    // p^T -> lktT
    {
        const int m = tid >> 1, nh2 = (tid & 1) * 32;
        ushort tp[32];
        #pragma unroll
        for (int i = 0; i < 32; ++i) tp[i] = lom[(nh2 + i) * 136 + m];
        #pragma unroll
        for (int i = 0; i < 4; ++i) *(s8v*)&lktT[m][nh2 + i * 8] = *(s8v*)&tp[i * 8];
    }
    // V^T -> global + LDS
    {
        const int d = tid >> 2, s0 = (tid & 3) * 16;
        ushort tp[16];
        #pragma unroll
        for (int i = 0; i < 16; ++i) tp[i] = lv[s0 + i][d];
        const size_t tb = ((size_t)bh * HDIM + d) * NN + c * CSZ + s0;
        *(s8v*)&vt[tb] = *(s8v*)&tp[0];
        *(s8v*)&vt[tb + 8] = *(s8v*)&tp[8];
        *(s8v*)&lvt[d][s0] = *(s8v*)&tp[0];
        *(s8v*)&lvt[d][s0 + 8] = *(s8v*)&tp[8];
    }
    __syncthreads();

    // ssum_raw[d][m] = sum_n V[n,d]*p[n,m]
    f4v ac2[8] = {};
    #pragma unroll
    for (int k0 = 0; k0 < 64; k0 += 32) {
        h8v a = *(h8v*)&lvt[w * 16 + lr][k0 + lg * 8];
        #pragma unroll
        for (int ct = 0; ct < 8; ++ct) {
            h8v bf = *(h8v*)&lktT[ct * 16 + lr][k0 + lg * 8];
            ac2[ct] = __builtin_amdgcn_mfma_f32_16x16x32_f16(a, bf, ac2[ct], 0, 0, 0);
        }
    }
    const size_t obase = ((size_t)bh * NCH + c) * (HDIM * NFEAT);
    #pragma unroll
    for (int ct = 0; ct < 8; ++ct)
        #pragma unroll
        for (int rg = 0; rg < 4; ++rg) {
            const int d = w * 16 + lg * 4 + rg, m = ct * 16 + lr;
            ssum16[obase + (size_t)d * NFEAT + m] = f2h(ac2[ct][rg]);
        }
    if (tid < 128) {
        float s = 0.f;
        #pragma unroll 8
        for (int i = 0; i < 64; ++i) s += h2f(lktT[tid][i]);
        kcsum[((size_t)bh * NCH + c) * NFEAT + tid] = s;
    }
    if (tid < 64) {
        float s = 0.f;
        #pragma unroll 8
        for (int i = 0; i < 64; ++i) s += h2f(lvt[tid][i]);
        vsum[((size_t)bh * NCH + c) * HDIM + tid] = s;
    }
}

// ---------------- scan_final: recomputes phi(q,k) for own chunk; inline prefix ----------------
// grid (NCH, 32bh). LDS pool with overlays (73.7 KB -> 2 blocks/CU).
__global__ __launch_bounds__(256) void scan_final(const ushort* __restrict__ qkvh,
                                                  const ushort* __restrict__ omh,
                                                  const ushort* __restrict__ vt,
                                                  const ushort* __restrict__ ssum16,
                                                  const float* __restrict__ kcsum,
                                                  const float* __restrict__ vsum,
                                                  const float* __restrict__ blockmax,
                                                  ushort* __restrict__ att_h) {
    __shared__ __attribute__((aligned(16))) ushort pool[35840];
    ushort (*lqt)[72]  = (ushort(*)[72]) &pool[0];       // q then k tile; later lA
    ushort*  lom       = &pool[4608];                    // omega; later lsp
    ushort (*lvt)[72]  = (ushort(*)[72]) &pool[13824];
    ushort (*lq)[136]  = (ushort(*)[136])&pool[18432];   // phiq
    ushort (*lk)[136]  = (ushort(*)[136])&pool[27136];   // phik
    ushort (*lA)[72]   = (ushort(*)[72]) &pool[0];       // overlay lqt
    ushort (*lsp)[136] = (ushort(*)[136])&pool[4608];    // overlay lom
    __shared__ float kc[NFEAT];
    __shared__ float zin[64];
    __shared__ float zp[4][64];
    __shared__ float gred[4];
    __shared__ float lnorm[64];
    const int tid = threadIdx.x;
    const int c = blockIdx.x, bh = blockIdx.y;
    const int b = bh >> 4, h = bh & 15;
    const int n0 = c * CSZ;
    const size_t rowbase = (size_t)b * NN + n0;
    const int w = tid >> 6, l = tid & 63, lr = l & 15, lg = l >> 4;

    // gmax partial (gred read after S0)
    {
        float mxv = fmaxf(blockmax[tid], blockmax[tid + 256]);
        #pragma unroll
        for (int o = 32; o >= 1; o >>= 1) mxv = fmaxf(mxv, __shfl_xor(mxv, o));
        if (l == 0) gred[w] = mxv;
    }
    // load q tile + norms, omega, vt
    {
        const int r = tid >> 2, c0 = (tid & 3) * 16;
        const size_t g = (rowbase + r) * QKVN + h * HDIM + c0;
        s8v v0 = *(const s8v*)&qkvh[g];
        s8v v1 = *(const s8v*)&qkvh[g + 8];
        *(s8v*)&lqt[r][c0] = v0;
        *(s8v*)&lqt[r][c0 + 8] = v1;
        float p = 0.f;
        #pragma unroll
        for (int j = 0; j < 8; ++j) {
            float a = h2f(((ushort*)&v0)[j]); p += a * a;
            float bb2 = h2f(((ushort*)&v1)[j]); p += bb2 * bb2;
        }
        p += __shfl_xor(p, 1); p += __shfl_xor(p, 2);
        if ((tid & 3) == 0) lnorm[r] = p;
    }
    {
        const int m = tid >> 1, c0 = (tid & 1) * 32;
        #pragma unroll
        for (int i = 0; i < 4; ++i)
            *(s8v*)&lom[m * 72 + c0 + i * 8] = *(const s8v*)&omh[m * HDIM + c0 + i * 8];
    }
    {
        const int d = tid >> 2, s = (tid & 3) * 16;
        const size_t g = ((size_t)bh * HDIM + d) * NN + n0 + s;
        *(s8v*)&lvt[d][s]     = *(const s8v*)&vt[g];
        *(s8v*)&lvt[d][s + 8] = *(const s8v*)&vt[g + 8];
    }
    __syncthreads();   // S0

    const float gm = fmaxf(fmaxf(gred[0], gred[1]), fmaxf(gred[2], gred[3]));
    const float hs2 = 0.5f * SCALE * SCALE;

    // q-MFMA -> phiq into lq
    {
        f4v acc[8] = {};
        #pragma unroll
        for (int k0 = 0; k0 < 64; k0 += 32) {
            h8v a = *(h8v*)&lqt[w * 16 + lr][k0 + lg * 8];
            #pragma unroll
            for (int ct = 0; ct < 8; ++ct) {
                h8v bo = *(h8v*)&lom[(ct * 16 + lr) * 72 + k0 + lg * 8];
                acc[ct] = __builtin_amdgcn_mfma_f32_16x16x32_f16(a, bo, acc[ct], 0, 0, 0);
            }
        }
        #pragma unroll
        for (int rg = 0; rg < 4; ++rg) {
            const int row = w * 16 + lg * 4 + rg;
            const float nh = hs2 * lnorm[row];
            float lvv[8];
            float mx = -3.4e38f;
            #pragma unroll
            for (int ct = 0; ct < 8; ++ct) {
                lvv[ct] = SCALE * acc[ct][rg] - nh;
                mx = fmaxf(mx, lvv[ct]);
            }
            #pragma unroll
            for (int o = 8; o >= 1; o >>= 1) mx = fmaxf(mx, __shfl_xor(mx, o));
            #pragma unroll
            for (int ct = 0; ct < 8; ++ct)
                lq[row][ct * 16 + lr] = f2h(expf(lvv[ct] - mx) * INV_SQRT_M + 1e-4f);
        }
    }
    __syncthreads();   // S1: lqt free for k-tile

    // load k tile + norms
    {
        const int r = tid >> 2, c0 = (tid & 3) * 16;
        const size_t g = (rowbase + r) * QKVN + DIMS + h * HDIM + c0;
        s8v v0 = *(const s8v*)&qkvh[g];
        s8v v1 = *(const s8v*)&qkvh[g + 8];
        *(s8v*)&lqt[r][c0] = v0;
        *(s8v*)&lqt[r][c0 + 8] = v1;
        float p = 0.f;
        #pragma unroll
        for (int j = 0; j < 8; ++j) {
            float a = h2f(((ushort*)&v0)[j]); p += a * a;
            float bb2 = h2f(((ushort*)&v1)[j]); p += bb2 * bb2;
        }
        p += __shfl_xor(p, 1); p += __shfl_xor(p, 2);
        if ((tid & 3) == 0) lnorm[r] = p;
    }
    __syncthreads();   // S2

    // k-MFMA -> phik into lk
    const float bm = blockmax[h * 32 + b * 16 + c];
    const float fac = expf(bm - gm) * INV_SQRT_M;
    {
        f4v acc[8] = {};
        #pragma unroll
        for (int k0 = 0; k0 < 64; k0 += 32) {
            h8v a = *(h8v*)&lqt[w * 16 + lr][k0 + lg * 8];
            #pragma unroll
            for (int ct = 0; ct < 8; ++ct) {
                h8v bo = *(h8v*)&lom[(ct * 16 + lr) * 72 + k0 + lg * 8];
                acc[ct] = __builtin_amdgcn_mfma_f32_16x16x32_f16(a, bo, acc[ct], 0, 0, 0);
            }
        }
        #pragma unroll
        for (int rg = 0; rg < 4; ++rg) {
            const int row = w * 16 + lg * 4 + rg;
            const float nh = hs2 * lnorm[row];
            #pragma unroll
            for (int ct = 0; ct < 8; ++ct) {
                const float lv = SCALE * acc[ct][rg] - nh;
                lk[row][ct * 16 + lr] = f2h(expf(lv - bm) * fac + 1e-4f);
            }
        }
    }
    __syncthreads();   // S3: lk ready; lom/lqt dead -> lsp/lA usable

    // inline prefix: lsp = sum_{c'<c} fac_c'*ssum_raw + 1e-4*vsum ; kc prefix
    {
        const int d = tid >> 2;
        const int m0 = (tid & 3) * 32;
        float acc[32] = {};
        float vs_tot = 0.f;
        for (int cp = 0; cp < c; ++cp) {
            const float facp = expf(blockmax[h * 32 + b * 16 + cp] - gm) * INV_SQRT_M;
            vs_tot += vsum[((size_t)bh * NCH + cp) * HDIM + d];
            const size_t cb = ((size_t)bh * NCH + cp) * (HDIM * NFEAT) + (size_t)d * NFEAT + m0;
            #pragma unroll
            for (int i = 0; i < 4; ++i) {
                s8v v = *(const s8v*)&ssum16[cb + i * 8];
                #pragma unroll
                for (int j = 0; j < 8; ++j) acc[i * 8 + j] += facp * h2f(((ushort*)&v)[j]);
            }
        }
        const float vadd = 1e-4f * vs_tot;
        ushort o[32];
        #pragma unroll
        for (int i = 0; i < 32; ++i) o[i] = f2h(acc[i] + vadd);
        #pragma unroll
        for (int i = 0; i < 4; ++i) *(s8v*)&lsp[d][m0 + i * 8] = *(s8v*)&o[i * 8];
    }
    if (tid < NFEAT) {
        float a = 0.f;
        for (int cp = 0; cp < c; ++cp) {
            const float facp = expf(blockmax[h * 32 + b * 16 + cp] - gm) * INV_SQRT_M;
            a += facp * kcsum[((size_t)bh * NCH + cp) * NFEAT + tid] + 64.0f * 1e-4f;
        }
        kc[tid] = a;
    }
    __syncthreads();   // S4: lsp, kc ready

    // Phase 1: A = phiq @ phik^T
    f4v a4[4] = {};
    #pragma unroll
    for (int k0 = 0; k0 < 128; k0 += 32) {
        h8v av = *(h8v*)&lq[w * 16 + lr][k0 + lg * 8];
        #pragma unroll
        for (int ct = 0; ct < 4; ++ct) {
            h8v bv = *(h8v*)&lk[ct * 16 + lr][k0 + lg * 8];
            a4[ct] = __builtin_amdgcn_mfma_f32_16x16x32_f16(av, bv, a4[ct], 0, 0, 0);
        }
    }
    float zi[4] = {0.f, 0.f, 0.f, 0.f};
    #pragma unroll
    for (int ct = 0; ct < 4; ++ct) {
        #pragma unroll
        for (int rg = 0; rg < 4; ++rg) {
            const int row = w * 16 + lg * 4 + rg;
            const int col = ct * 16 + lr;
            const float val = (col <= row) ? a4[ct][rg] : 0.f;
            const ushort hq = f2h(val);
            zi[rg] += h2f(hq);
            lA[row][col] = hq;
        }
    }
    #pragma unroll
    for (int rg = 0; rg < 4; ++rg) {
        float z = zi[rg];
        z += __shfl_xor(z, 1); z += __shfl_xor(z, 2);
        z += __shfl_xor(z, 4); z += __shfl_xor(z, 8);
        if (lr == 0) zin[w * 16 + lg * 4 + rg] = z;
    }
    {
        const int row = tid & 63, qq = tid >> 6;
        float s = 0.f;
        #pragma unroll 8
        for (int m = 0; m < 32; ++m) s += h2f(lq[row][qq * 32 + m]) * kc[qq * 32 + m];
        zp[qq][row] = s;
    }
    __syncthreads();   // S5

    // Phase 2: out = Amask @ V + phiq @ Spre
    f4v o4[4] = {};
    #pragma unroll
    for (int k0 = 0; k0 < 64; k0 += 32) {
        h8v av = *(h8v*)&lA[w * 16 + lr][k0 + lg * 8];
        #pragma unroll
        for (int ct = 0; ct < 4; ++ct) {
            h8v bv = *(h8v*)&lvt[ct * 16 + lr][k0 + lg * 8];
            o4[ct] = __builtin_amdgcn_mfma_f32_16x16x32_f16(av, bv, o4[ct], 0, 0, 0);
        }
    }
    #pragma unroll
    for (int k0 = 0; k0 < 128; k0 += 32) {
        h8v av = *(h8v*)&lq[w * 16 + lr][k0 + lg * 8];
        #pragma unroll
        for (int ct = 0; ct < 4; ++ct) {
            h8v bv = *(h8v*)&lsp[ct * 16 + lr][k0 + lg * 8];
            o4[ct] = __builtin_amdgcn_mfma_f32_16x16x32_f16(av, bv, o4[ct], 0, 0, 0);
        }
    }
    #pragma unroll
    for (int rg = 0; rg < 4; ++rg) {
        const int row = w * 16 + lg * 4 + rg;
        const float z = zin[row] + zp[0][row] + zp[1][row] + zp[2][row] + zp[3][row] + 1e-6f;
        const float rz = 1.f / z;
        #pragma unroll
        for (int ct = 0; ct < 4; ++ct) {
            const int d = ct * 16 + lr;
            att_h[(rowbase + row) * DIMS + h * HDIM + d] = f2h(o4[ct][rg] * rz);
        }
    }
}

extern "C" void kernel_launch(void* const* d_in, const int* in_sizes, int n_in,
                              void* d_out, int out_size, void* d_ws, size_t ws_size,
                              hipStream_t stream) {
    const float* x     = (const float*)d_in[0];
    const float* omega = (const float*)d_in[1];
    const float* Wq    = (const float*)d_in[2];
    const float* Wk    = (const float*)d_in[3];
    const float* Wv    = (const float*)d_in[4];
    const float* Wo    = (const float*)d_in[5];
    const float* bo    = (const float*)d_in[6];
    float* out = (float*)d_out;

    const size_t PROJ = (size_t)BN * DIMS;                 // 2M elems
    const size_t PHI  = (size_t)BB * NHEADS * NN * NFEAT;  // 4M elems
    ushort* qkvh    = (ushort*)d_ws;                       // 12 MB
    ushort* xh      = qkvh + (size_t)BN * QKVN;            // 4 MB
    ushort* wqkvh   = xh + PROJ;                           // 6 MB
    ushort* woh     = wqkvh + (size_t)QKVN * DIMS;         // 2 MB
    ushort* omh     = woh + WW;                            // 16 KB
    ushort* vt_h    = omh + NFEAT * HDIM;                  // 4 MB
    ushort* ssum16  = vt_h + PROJ;                         // 8 MB
    ushort* att_hb  = ssum16 + PHI;                        // 4 MB
    float*  kcsum   = (float*)(att_hb + PROJ);             // 256 KB
    float*  blockmax= kcsum + 32 * NCH * NFEAT;            // 512
    float*  vsum    = blockmax + 512;                      // 32*16*64

    // 1: fused casts (x, Wq,k,v, Wo, omega)
    cast_all<<<(NX + 4 * NW + NOM) / 256, 256, 0, stream>>>(x, Wq, Wk, Wv, Wo, omega,
                                                            xh, wqkvh, woh, omh);

    // 2: fused QKV projection -> fp16 [2048 x 3072]; BK=64, 768 blocks = 3/CU
    gemm_nt_lds<64, true><<<(BN / 64) * (QKVN / 128), 256, 0, stream>>>(
        xh, wqkvh, nullptr, qkvh, nullptr, BN, QKVN, DIMS, BN / 64);

    // 3: key-path phi + chunk stats (512 blocks)
    dim3 pg(32, NHEADS);
    phik_stats<<<pg, 256, 0, stream>>>(qkvh, omh, blockmax, vt_h, ssum16, kcsum, vsum);

    // 4: causal attention; recomputes phi(q,k) per chunk, inline prefix
    dim3 cg(NCH, BB * NHEADS);
    scan_final<<<cg, 256, 0, stream>>>(qkvh, omh, vt_h, ssum16, kcsum, vsum,
                                       blockmax, att_hb);

    // 5: output projection; BM=32 -> 512 blocks = 2/CU
    gemm_nt_lds<32, false><<<(BN / 32) * (DIMS / 128), 256, 0, stream>>>(
        att_hb, woh, out, nullptr, bo, BN, DIMS, DIMS, BN / 32);
}

// Round 15
// 80.084 us; speedup vs baseline: 8.3415x; 1.0029x over previous
//
#include <hip/hip_runtime.h>
#include <hip/hip_bf16.h>
#include <math.h>

#define DIMS 1024
#define NHEADS 16
#define HDIM 64
#define NFEAT 128
#define BB 2
#define NN 1024
#define BN (BB*NN)   // 2048
#define NCH 16       // chunks per (b,h)
#define CSZ 64       // chunk size
#define WW (DIMS*DIMS)
#define QKVN (3*DIMS) // 3072

#define SCALE 0.3535533905932738f       // 64^-0.25
#define INV_SQRT_M 0.08838834764831845f // 1/sqrt(128)

typedef __attribute__((ext_vector_type(8))) _Float16 h8v;  // 8 fp16 (4 VGPRs)
typedef __attribute__((ext_vector_type(8))) short s8v;     // raw 16B
typedef __attribute__((ext_vector_type(4))) float f4v;     // mfma accumulator

__device__ __forceinline__ ushort f2h(float x) {
    _Float16 h = (_Float16)x;
    return *(ushort*)&h;
}
__device__ __forceinline__ float h2f(ushort u) {
    _Float16 h = *(_Float16*)&u;
    return (float)h;
}
__device__ __forceinline__ void gload16(const void* g, void* l) {
    __builtin_amdgcn_global_load_lds(
        (const __attribute__((address_space(1))) unsigned int*)g,
        (__attribute__((address_space(3))) unsigned int*)l,
        16, 0, 0);
}

// ---------------- fused cast f32 -> fp16 for x, Wq,k,v, Wo, omega ----------------
#define NX (BN*DIMS/8)   // 262144
#define NW (WW/8)        // 131072
#define NOM (NFEAT*HDIM/8) // 1024
__global__ __launch_bounds__(256) void cast_all(const float* __restrict__ x,
                                                const float* __restrict__ Wq,
                                                const float* __restrict__ Wk,
                                                const float* __restrict__ Wv,
                                                const float* __restrict__ Wo,
                                                const float* __restrict__ omega,
                                                ushort* __restrict__ xh,
                                                ushort* __restrict__ wqkvh,
                                                ushort* __restrict__ woh,
                                                ushort* __restrict__ omh) {
    const int i = blockIdx.x * 256 + threadIdx.x;
    const float* src; ushort* dst; int off;
    if (i < NX)               { src = x;     dst = xh;                     off = i; }
    else if (i < NX + NW)     { src = Wq;    dst = wqkvh;                  off = i - NX; }
    else if (i < NX + 2 * NW) { src = Wk;    dst = wqkvh + WW;             off = i - NX - NW; }
    else if (i < NX + 3 * NW) { src = Wv;    dst = wqkvh + 2 * (size_t)WW; off = i - NX - 2 * NW; }
    else if (i < NX + 4 * NW) { src = Wo;    dst = woh;                    off = i - NX - 3 * NW; }
    else                      { src = omega; dst = omh;                    off = i - NX - 4 * NW; }
    float4 a = ((const float4*)src)[2 * (size_t)off];
    float4 b = ((const float4*)src)[2 * (size_t)off + 1];
    float v[8] = {a.x, a.y, a.z, a.w, b.x, b.y, b.z, b.w};
    ushort h8[8];
    #pragma unroll
    for (int j = 0; j < 8; ++j) h8[j] = f2h(v[j]);
    *(s8v*)&dst[(size_t)off * 8] = *(s8v*)&h8[0];
}

// ---------------- MFMA GEMM NT; BK=64, swizzled LDS; XCD-bijective 1D grid ----------------
template<int BM, bool HOUT>
__global__ __launch_bounds__(256) void gemm_nt_lds(const ushort* __restrict__ A,
                                                   const ushort* __restrict__ B,
                                                   float* __restrict__ C,
                                                   ushort* __restrict__ C16,
                                                   const float* __restrict__ bias,
                                                   int M, int N, int K, int nbx) {
    constexpr int MF = BM / 32;
    constexpr int AI = BM / 32;
    __shared__ __attribute__((aligned(16))) ushort lA[BM][64];
    __shared__ __attribute__((aligned(16))) ushort lB[128][64];
    const int tid = threadIdx.x;
    const int w = tid >> 6, l = tid & 63, lr = l & 15, lg = l >> 4;
    const int wm = (w >> 1) * (BM / 2), wn = (w & 1) * 64;
    const int nwg = gridDim.x;
    const int q8 = nwg >> 3;
    const int neu = (blockIdx.x & 7) * q8 + (blockIdx.x >> 3);
    const int bx = neu % nbx, by = neu / nbx;
    const int bi = bx * BM, bj = by * 128;
    const int srow = l >> 3;
    const int scol = ((l & 7) ^ (l >> 3)) * 8;

    f4v acc[MF][4] = {};
    for (int k0 = 0; k0 < K; k0 += 64) {
        #pragma unroll
        for (int i = 0; i < AI; ++i) {
            const int r0 = w * (8 * AI) + i * 8;
            gload16(&A[(size_t)(bi + r0 + srow) * K + k0 + scol], &lA[r0][0]);
        }
        #pragma unroll
        for (int i = 0; i < 4; ++i) {
            const int r0 = w * 32 + i * 8;
            gload16(&B[(size_t)(bj + r0 + srow) * K + k0 + scol], &lB[r0][0]);
        }
        __syncthreads();
        #pragma unroll
        for (int kk = 0; kk < 2; ++kk) {
            const int soff = ((kk * 4 + lg) ^ (lr & 7)) * 8;
            h8v b_[4];
            #pragma unroll
            for (int j = 0; j < 4; ++j) b_[j] = *(h8v*)&lB[wn + j * 16 + lr][soff];
            #pragma unroll
            for (int i = 0; i < MF; ++i) {
                h8v a_ = *(h8v*)&lA[wm + i * 16 + lr][soff];
                #pragma unroll
                for (int j = 0; j < 4; ++j)
                    acc[i][j] = __builtin_amdgcn_mfma_f32_16x16x32_f16(a_, b_[j], acc[i][j], 0, 0, 0);
            }
        }
        __syncthreads();
    }
    #pragma unroll
    for (int i = 0; i < MF; ++i)
        #pragma unroll
        for (int j = 0; j < 4; ++j)
            #pragma unroll
            for (int rg = 0; rg < 4; ++rg) {
                const int row = bi + wm + i * 16 + lg * 4 + rg;
                const int col = bj + wn + j * 16 + lr;
                if (HOUT) {
                    C16[(size_t)row * N + col] = f2h(acc[i][j][rg]);
                } else {
                    float r = acc[i][j][rg] + bias[col];
                    C[(size_t)row * N + col] = r;
                }
            }
}

// ---------------- phik_stats: k-path phi + chunk stats ----------------
// grid (32 = b*16+c, NHEADS). Emits blockmax, ssum_raw (fp16), kcsum_raw, vsum.
__global__ __launch_bounds__(256) void phik_stats(const ushort* __restrict__ qkvh,
                                                  const ushort* __restrict__ omh,
                                                  float* __restrict__ blockmax,
                                                  ushort* __restrict__ ssum16,
                                                  float* __restrict__ kcsum,
                                                  float* __restrict__ vsum) {
    __shared__ __attribute__((aligned(16))) ushort lq[64][72];
    __shared__ __attribute__((aligned(16))) ushort lom[128 * 72]; // omega; reused as staging [64][136]
    __shared__ __attribute__((aligned(16))) ushort lktT[128][72];
    __shared__ __attribute__((aligned(16))) ushort lv[64][72];
    __shared__ __attribute__((aligned(16))) ushort lvt[64][72];
    __shared__ float lnorm[64];
    __shared__ float wred[4];
    const int tid = threadIdx.x;
    const int h = blockIdx.y;
    const int bn0 = blockIdx.x * 64;
    const int w = tid >> 6, l = tid & 63, lr = l & 15, lg = l >> 4;
    const int b = blockIdx.x >> 4, c = blockIdx.x & 15;
    const int bh = b * NHEADS + h;

    {
        const int r = tid >> 2, c0 = (tid & 3) * 16;
        const size_t g = (size_t)(bn0 + r) * QKVN + DIMS + h * HDIM + c0;  // k at +DIMS
        s8v v0 = *(const s8v*)&qkvh[g];
        s8v v1 = *(const s8v*)&qkvh[g + 8];
        *(s8v*)&lq[r][c0] = v0;
        *(s8v*)&lq[r][c0 + 8] = v1;
        float p = 0.f;
        #pragma unroll
        for (int j = 0; j < 8; ++j) {
            float a = h2f(((ushort*)&v0)[j]); p += a * a;
            float bb2 = h2f(((ushort*)&v1)[j]); p += bb2 * bb2;
        }
        p += __shfl_xor(p, 1); p += __shfl_xor(p, 2);
        if ((tid & 3) == 0) lnorm[r] = p;
    }
    {
        const int m = tid >> 1, c0 = (tid & 1) * 32;
        #pragma unroll
        for (int i = 0; i < 4; ++i)
            *(s8v*)&lom[m * 72 + c0 + i * 8] = *(const s8v*)&omh[m * HDIM + c0 + i * 8];
    }
    {
        const int r = tid >> 2, c0 = (tid & 3) * 16;
        const size_t g = (size_t)(bn0 + r) * QKVN + 2 * DIMS + h * HDIM + c0;
        *(s8v*)&lv[r][c0]     = *(const s8v*)&qkvh[g];
        *(s8v*)&lv[r][c0 + 8] = *(const s8v*)&qkvh[g + 8];
    }
    __syncthreads();

    f4v acc[8] = {};
    #pragma unroll
    for (int k0 = 0; k0 < 64; k0 += 32) {
        h8v a = *(h8v*)&lq[w * 16 + lr][k0 + lg * 8];
        #pragma unroll
        for (int ct = 0; ct < 8; ++ct) {
            h8v bo = *(h8v*)&lom[(ct * 16 + lr) * 72 + k0 + lg * 8];
            acc[ct] = __builtin_amdgcn_mfma_f32_16x16x32_f16(a, bo, acc[ct], 0, 0, 0);
        }
    }

    const float hs2 = 0.5f * SCALE * SCALE;
    float lvv[4][8];
    float bmax = -3.4e38f;
    #pragma unroll
    for (int rg = 0; rg < 4; ++rg) {
        const int row = w * 16 + lg * 4 + rg;
        const float nh = hs2 * lnorm[row];
        #pragma unroll
        for (int ct = 0; ct < 8; ++ct) {
            lvv[rg][ct] = SCALE * acc[ct][rg] - nh;
            bmax = fmaxf(bmax, lvv[rg][ct]);
        }
    }
    #pragma unroll
    for (int o = 32; o >= 1; o >>= 1) bmax = fmaxf(bmax, __shfl_xor(bmax, o));
    if (l == 0) wred[w] = bmax;
    __syncthreads();   // lom (omega) done + wred ready

    const float bm = fmaxf(fmaxf(wred[0], wred[1]), fmaxf(wred[2], wred[3]));
    if (tid == 0) blockmax[h * 32 + blockIdx.x] = bm;
    #pragma unroll
    for (int rg = 0; rg < 4; ++rg) {
        const int row = w * 16 + lg * 4 + rg;
        #pragma unroll
        for (int ct = 0; ct < 8; ++ct)
            lom[row * 136 + ct * 16 + lr] = f2h(expf(lvv[rg][ct] - bm));
    }
    __syncthreads();

    // p^T -> lktT
    {
        const int m = tid >> 1, nh2 = (tid & 1) * 32;
        ushort tp[32];
        #pragma unroll
        for (int i = 0; i < 32; ++i) tp[i] = lom[(nh2 + i) * 136 + m];
        #pragma unroll
        for (int i = 0; i < 4; ++i) *(s8v*)&lktT[m][nh2 + i * 8] = *(s8v*)&tp[i * 8];
    }
    // V^T -> LDS only
    {
        const int d = tid >> 2, s0 = (tid & 3) * 16;
        ushort tp[16];
        #pragma unroll
        for (int i = 0; i < 16; ++i) tp[i] = lv[s0 + i][d];
        *(s8v*)&lvt[d][s0] = *(s8v*)&tp[0];
        *(s8v*)&lvt[d][s0 + 8] = *(s8v*)&tp[8];
    }
    __syncthreads();

    // ssum_raw[d][m] = sum_n V[n,d]*p[n,m]
    f4v ac2[8] = {};
    #pragma unroll
    for (int k0 = 0; k0 < 64; k0 += 32) {
        h8v a = *(h8v*)&lvt[w * 16 + lr][k0 + lg * 8];
        #pragma unroll
        for (int ct = 0; ct < 8; ++ct) {
            h8v bf = *(h8v*)&lktT[ct * 16 + lr][k0 + lg * 8];
            ac2[ct] = __builtin_amdgcn_mfma_f32_16x16x32_f16(a, bf, ac2[ct], 0, 0, 0);
        }
    }
    const size_t obase = ((size_t)bh * NCH + c) * (HDIM * NFEAT);
    #pragma unroll
    for (int ct = 0; ct < 8; ++ct)
        #pragma unroll
        for (int rg = 0; rg < 4; ++rg) {
            const int d = w * 16 + lg * 4 + rg, m = ct * 16 + lr;
            ssum16[obase + (size_t)d * NFEAT + m] = f2h(ac2[ct][rg]);
        }
    if (tid < 128) {
        float s = 0.f;
        #pragma unroll 8
        for (int i = 0; i < 64; ++i) s += h2f(lktT[tid][i]);
        kcsum[((size_t)bh * NCH + c) * NFEAT + tid] = s;
    }
    if (tid < 64) {
        float s = 0.f;
        #pragma unroll 8
        for (int i = 0; i < 64; ++i) s += h2f(lvt[tid][i]);
        vsum[((size_t)bh * NCH + c) * HDIM + tid] = s;
    }
}

// ---------------- scan_final: recomputes phi(q,k) + V^T in-LDS; inline prefix ----------------
// grid (NCH, 32bh). LDS pool with overlays (73.7 KB -> 2 blocks/CU).
__global__ __launch_bounds__(256) void scan_final(const ushort* __restrict__ qkvh,
                                                  const ushort* __restrict__ omh,
                                                  const ushort* __restrict__ ssum16,
                                                  const float* __restrict__ kcsum,
                                                  const float* __restrict__ vsum,
                                                  const float* __restrict__ blockmax,
                                                  ushort* __restrict__ att_h) {
    __shared__ __attribute__((aligned(16))) ushort pool[35840];
    ushort (*lqt)[72]  = (ushort(*)[72]) &pool[0];       // q then k tile; later lA
    ushort*  lom       = &pool[4608];                    // omega; later lsp
    ushort (*lvt)[72]  = (ushort(*)[72]) &pool[13824];
    ushort (*lq)[136]  = (ushort(*)[136])&pool[18432];   // phiq
    ushort (*lk)[136]  = (ushort(*)[136])&pool[27136];   // phik; first 4608 = V-row staging
    ushort (*lv)[72]   = (ushort(*)[72]) &pool[27136];   // V rows overlay (dead before phik)
    ushort (*lA)[72]   = (ushort(*)[72]) &pool[0];       // overlay lqt
    ushort (*lsp)[136] = (ushort(*)[136])&pool[4608];    // overlay lom
    __shared__ float kc[NFEAT];
    __shared__ float zin[64];
    __shared__ float zp[4][64];
    __shared__ float gred[4];
    __shared__ float lnorm[64];
    const int tid = threadIdx.x;
    const int c = blockIdx.x, bh = blockIdx.y;
    const int b = bh >> 4, h = bh & 15;
    const int n0 = c * CSZ;
    const size_t rowbase = (size_t)b * NN + n0;
    const int w = tid >> 6, l = tid & 63, lr = l & 15, lg = l >> 4;

    // gmax partial (gred read after S0)
    {
        float mxv = fmaxf(blockmax[tid], blockmax[tid + 256]);
        #pragma unroll
        for (int o = 32; o >= 1; o >>= 1) mxv = fmaxf(mxv, __shfl_xor(mxv, o));
        if (l == 0) gred[w] = mxv;
    }
    // load q tile + norms, omega, V rows
    {
        const int r = tid >> 2, c0 = (tid & 3) * 16;
        const size_t g = (rowbase + r) * QKVN + h * HDIM + c0;
        s8v v0 = *(const s8v*)&qkvh[g];
        s8v v1 = *(const s8v*)&qkvh[g + 8];
        *(s8v*)&lqt[r][c0] = v0;
        *(s8v*)&lqt[r][c0 + 8] = v1;
        float p = 0.f;
        #pragma unroll
        for (int j = 0; j < 8; ++j) {
            float a = h2f(((ushort*)&v0)[j]); p += a * a;
            float bb2 = h2f(((ushort*)&v1)[j]); p += bb2 * bb2;
        }
        p += __shfl_xor(p, 1); p += __shfl_xor(p, 2);
        if ((tid & 3) == 0) lnorm[r] = p;
    }
    {
        const int m = tid >> 1, c0 = (tid & 1) * 32;
        #pragma unroll
        for (int i = 0; i < 4; ++i)
            *(s8v*)&lom[m * 72 + c0 + i * 8] = *(const s8v*)&omh[m * HDIM + c0 + i * 8];
    }
    {
        const int r = tid >> 2, c0 = (tid & 3) * 16;
        const size_t g = (rowbase + r) * QKVN + 2 * DIMS + h * HDIM + c0;
        *(s8v*)&lv[r][c0]     = *(const s8v*)&qkvh[g];
        *(s8v*)&lv[r][c0 + 8] = *(const s8v*)&qkvh[g + 8];
    }
    __syncthreads();   // S0

    const float gm = fmaxf(fmaxf(gred[0], gred[1]), fmaxf(gred[2], gred[3]));
    const float hs2 = 0.5f * SCALE * SCALE;

    // V^T: lv -> lvt
    {
        const int d = tid >> 2, s0 = (tid & 3) * 16;
        ushort tp[16];
        #pragma unroll
        for (int i = 0; i < 16; ++i) tp[i] = lv[s0 + i][d];
        *(s8v*)&lvt[d][s0] = *(s8v*)&tp[0];
        *(s8v*)&lvt[d][s0 + 8] = *(s8v*)&tp[8];
    }
    // q-MFMA -> phiq into lq
    {
        f4v acc[8] = {};
        #pragma unroll
        for (int k0 = 0; k0 < 64; k0 += 32) {
            h8v a = *(h8v*)&lqt[w * 16 + lr][k0 + lg * 8];
            #pragma unroll
            for (int ct = 0; ct < 8; ++ct) {
                h8v bo = *(h8v*)&lom[(ct * 16 + lr) * 72 + k0 + lg * 8];
                acc[ct] = __builtin_amdgcn_mfma_f32_16x16x32_f16(a, bo, acc[ct], 0, 0, 0);
            }
        }
        #pragma unroll
        for (int rg = 0; rg < 4; ++rg) {
            const int row = w * 16 + lg * 4 + rg;
            const float nh = hs2 * lnorm[row];
            float lvv[8];
            float mx = -3.4e38f;
            #pragma unroll
            for (int ct = 0; ct < 8; ++ct) {
                lvv[ct] = SCALE * acc[ct][rg] - nh;
                mx = fmaxf(mx, lvv[ct]);
            }
            #pragma unroll
            for (int o = 8; o >= 1; o >>= 1) mx = fmaxf(mx, __shfl_xor(mx, o));
            #pragma unroll
            for (int ct = 0; ct < 8; ++ct)
                lq[row][ct * 16 + lr] = f2h(expf(lvv[ct] - mx) * INV_SQRT_M + 1e-4f);
        }
    }
    __syncthreads();   // S1: lqt free for k-tile; lv consumed

    // load k tile + norms
    {
        const int r = tid >> 2, c0 = (tid & 3) * 16;
        const size_t g = (rowbase + r) * QKVN + DIMS + h * HDIM + c0;
        s8v v0 = *(const s8v*)&qkvh[g];
        s8v v1 = *(const s8v*)&qkvh[g + 8];
        *(s8v*)&lqt[r][c0] = v0;
        *(s8v*)&lqt[r][c0 + 8] = v1;
        float p = 0.f;
        #pragma unroll
        for (int j = 0; j < 8; ++j) {
            float a = h2f(((ushort*)&v0)[j]); p += a * a;
            float bb2 = h2f(((ushort*)&v1)[j]); p += bb2 * bb2;
        }
        p += __shfl_xor(p, 1); p += __shfl_xor(p, 2);
        if ((tid & 3) == 0) lnorm[r] = p;
    }
    __syncthreads();   // S2

    // k-MFMA -> phik into lk (overwrites lv staging, dead)
    const float bm = blockmax[h * 32 + b * 16 + c];
    const float fac = expf(bm - gm) * INV_SQRT_M;
    {
        f4v acc[8] = {};
        #pragma unroll
        for (int k0 = 0; k0 < 64; k0 += 32) {
            h8v a = *(h8v*)&lqt[w * 16 + lr][k0 + lg * 8];
            #pragma unroll
            for (int ct = 0; ct < 8; ++ct) {
                h8v bo = *(h8v*)&lom[(ct * 16 + lr) * 72 + k0 + lg * 8];
                acc[ct] = __builtin_amdgcn_mfma_f32_16x16x32_f16(a, bo, acc[ct], 0, 0, 0);
            }
        }
        __syncthreads();   // S3a: everyone's V-row reads & omega reads done before lk write
        #pragma unroll
        for (int rg = 0; rg < 4; ++rg) {
            const int row = w * 16 + lg * 4 + rg;
            const float nh = hs2 * lnorm[row];
            #pragma unroll
            for (int ct = 0; ct < 8; ++ct) {
                const float lv2 = SCALE * acc[ct][rg] - nh;
                lk[row][ct * 16 + lr] = f2h(expf(lv2 - bm) * fac + 1e-4f);
            }
        }
    }
    __syncthreads();   // S3: lk ready; lom/lqt dead -> lsp/lA usable

    // inline prefix: lsp = sum_{c'<c} fac_c'*ssum_raw + 1e-4*vsum ; kc prefix
    {
        const int d = tid >> 2;
        const int m0 = (tid & 3) * 32;
        float acc[32] = {};
        float vs_tot = 0.f;
        for (int cp = 0; cp < c; ++cp) {
            const float facp = expf(blockmax[h * 32 + b * 16 + cp] - gm) * INV_SQRT_M;
            vs_tot += vsum[((size_t)bh * NCH + cp) * HDIM + d];
            const size_t cb = ((size_t)bh * NCH + cp) * (HDIM * NFEAT) + (size_t)d * NFEAT + m0;
            #pragma unroll
            for (int i = 0; i < 4; ++i) {
                s8v v = *(const s8v*)&ssum16[cb + i * 8];
                #pragma unroll
                for (int j = 0; j < 8; ++j) acc[i * 8 + j] += facp * h2f(((ushort*)&v)[j]);
            }
        }
        const float vadd = 1e-4f * vs_tot;
        ushort o[32];
        #pragma unroll
        for (int i = 0; i < 32; ++i) o[i] = f2h(acc[i] + vadd);
        #pragma unroll
        for (int i = 0; i < 4; ++i) *(s8v*)&lsp[d][m0 + i * 8] = *(s8v*)&o[i * 8];
    }
    if (tid < NFEAT) {
        float a = 0.f;
        for (int cp = 0; cp < c; ++cp) {
            const float facp = expf(blockmax[h * 32 + b * 16 + cp] - gm) * INV_SQRT_M;
            a += facp * kcsum[((size_t)bh * NCH + cp) * NFEAT + tid] + 64.0f * 1e-4f;
        }
        kc[tid] = a;
    }
    __syncthreads();   // S4: lsp, kc ready

    // Phase 1: A = phiq @ phik^T
    f4v a4[4] = {};
    #pragma unroll
    for (int k0 = 0; k0 < 128; k0 += 32) {
        h8v av = *(h8v*)&lq[w * 16 + lr][k0 + lg * 8];
        #pragma unroll
        for (int ct = 0; ct < 4; ++ct) {
            h8v bv = *(h8v*)&lk[ct * 16 + lr][k0 + lg * 8];
            a4[ct] = __builtin_amdgcn_mfma_f32_16x16x32_f16(av, bv, a4[ct], 0, 0, 0);
        }
    }
    float zi[4] = {0.f, 0.f, 0.f, 0.f};
    #pragma unroll
    for (int ct = 0; ct < 4; ++ct) {
        #pragma unroll
        for (int rg = 0; rg < 4; ++rg) {
            const int row = w * 16 + lg * 4 + rg;
            const int col = ct * 16 + lr;
            const float val = (col <= row) ? a4[ct][rg] : 0.f;
            const ushort hq = f2h(val);
            zi[rg] += h2f(hq);
            lA[row][col] = hq;
        }
    }
    #pragma unroll
    for (int rg = 0; rg < 4; ++rg) {
        float z = zi[rg];
        z += __shfl_xor(z, 1); z += __shfl_xor(z, 2);
        z += __shfl_xor(z, 4); z += __shfl_xor(z, 8);
        if (lr == 0) zin[w * 16 + lg * 4 + rg] = z;
    }
    {
        const int row = tid & 63, qq = tid >> 6;
        float s = 0.f;
        #pragma unroll 8
        for (int m = 0; m < 32; ++m) s += h2f(lq[row][qq * 32 + m]) * kc[qq * 32 + m];
        zp[qq][row] = s;
    }
    __syncthreads();   // S5

    // Phase 2: out = Amask @ V + phiq @ Spre
    f4v o4[4] = {};
    #pragma unroll
    for (int k0 = 0; k0 < 64; k0 += 32) {
        h8v av = *(h8v*)&lA[w * 16 + lr][k0 + lg * 8];
        #pragma unroll
        for (int ct = 0; ct < 4; ++ct) {
            h8v bv = *(h8v*)&lvt[ct * 16 + lr][k0 + lg * 8];
            o4[ct] = __builtin_amdgcn_mfma_f32_16x16x32_f16(av, bv, o4[ct], 0, 0, 0);
        }
    }
    #pragma unroll
    for (int k0 = 0; k0 < 128; k0 += 32) {
        h8v av = *(h8v*)&lq[w * 16 + lr][k0 + lg * 8];
        #pragma unroll
        for (int ct = 0; ct < 4; ++ct) {
            h8v bv = *(h8v*)&lsp[ct * 16 + lr][k0 + lg * 8];
            o4[ct] = __builtin_amdgcn_mfma_f32_16x16x32_f16(av, bv, o4[ct], 0, 0, 0);
        }
    }
    #pragma unroll
    for (int rg = 0; rg < 4; ++rg) {
        const int row = w * 16 + lg * 4 + rg;
        const float z = zin[row] + zp[0][row] + zp[1][row] + zp[2][row] + zp[3][row] + 1e-6f;
        const float rz = 1.f / z;
        #pragma unroll
        for (int ct = 0; ct < 4; ++ct) {
            const int d = ct * 16 + lr;
            att_h[(rowbase + row) * DIMS + h * HDIM + d] = f2h(o4[ct][rg] * rz);
        }
    }
}

extern "C" void kernel_launch(void* const* d_in, const int* in_sizes, int n_in,
                              void* d_out, int out_size, void* d_ws, size_t ws_size,
                              hipStream_t stream) {
    const float* x     = (const float*)d_in[0];
    const float* omega = (const float*)d_in[1];
    const float* Wq    = (const float*)d_in[2];
    const float* Wk    = (const float*)d_in[3];
    const float* Wv    = (const float*)d_in[4];
    const float* Wo    = (const float*)d_in[5];
    const float* bo    = (const float*)d_in[6];
    float* out = (float*)d_out;

    const size_t PROJ = (size_t)BN * DIMS;                 // 2M elems
    const size_t PHI  = (size_t)BB * NHEADS * NN * NFEAT;  // 4M elems
    ushort* qkvh    = (ushort*)d_ws;                       // 12 MB
    ushort* xh      = qkvh + (size_t)BN * QKVN;            // 4 MB
    ushort* wqkvh   = xh + PROJ;                           // 6 MB
    ushort* woh     = wqkvh + (size_t)QKVN * DIMS;         // 2 MB
    ushort* omh     = woh + WW;                            // 16 KB
    ushort* ssum16  = omh + NFEAT * HDIM;                  // 8 MB
    ushort* att_hb  = ssum16 + PHI;                        // 4 MB
    float*  kcsum   = (float*)(att_hb + PROJ);             // 256 KB
    float*  blockmax= kcsum + 32 * NCH * NFEAT;            // 512
    float*  vsum    = blockmax + 512;                      // 32*16*64

    // 1: fused casts (x, Wq,k,v, Wo, omega)
    cast_all<<<(NX + 4 * NW + NOM) / 256, 256, 0, stream>>>(x, Wq, Wk, Wv, Wo, omega,
                                                            xh, wqkvh, woh, omh);

    // 2: fused QKV projection -> fp16 [2048 x 3072]; BK=64, 768 blocks = 3/CU
    gemm_nt_lds<64, true><<<(BN / 64) * (QKVN / 128), 256, 0, stream>>>(
        xh, wqkvh, nullptr, qkvh, nullptr, BN, QKVN, DIMS, BN / 64);

    // 3: key-path phi + chunk stats (512 blocks)
    dim3 pg(32, NHEADS);
    phik_stats<<<pg, 256, 0, stream>>>(qkvh, omh, blockmax, ssum16, kcsum, vsum);

    // 4: causal attention; recomputes phi(q,k) + V^T per chunk, inline prefix
    dim3 cg(NCH, BB * NHEADS);
    scan_final<<<cg, 256, 0, stream>>>(qkvh, omh, ssum16, kcsum, vsum,
                                       blockmax, att_hb);

    // 5: output projection; BM=32 -> 512 blocks = 2/CU
    gemm_nt_lds<32, false><<<(BN / 32) * (DIMS / 128), 256, 0, stream>>>(
        att_hb, woh, out, nullptr, bo, BN, DIMS, DIMS, BN / 32);
}

// Round 16
// 79.475 us; speedup vs baseline: 8.4054x; 1.0077x over previous
//
#include <hip/hip_runtime.h>
#include <hip/hip_bf16.h>
#include <math.h>

#define DIMS 1024
#define NHEADS 16
#define HDIM 64
#define NFEAT 128
#define BB 2
#define NN 1024
#define BN (BB*NN)   // 2048
#define NCH 16       // chunks per (b,h)
#define CSZ 64       // chunk size
#define WW (DIMS*DIMS)
#define QKVN (3*DIMS) // 3072

#define SCALE 0.3535533905932738f       // 64^-0.25
#define INV_SQRT_M 0.08838834764831845f // 1/sqrt(128)

typedef __attribute__((ext_vector_type(8))) _Float16 h8v;  // 8 fp16 (4 VGPRs)
typedef __attribute__((ext_vector_type(8))) short s8v;     // raw 16B
typedef __attribute__((ext_vector_type(4))) float f4v;     // mfma accumulator

__device__ __forceinline__ ushort f2h(float x) {
    _Float16 h = (_Float16)x;
    return *(ushort*)&h;
}
__device__ __forceinline__ float h2f(ushort u) {
    _Float16 h = *(_Float16*)&u;
    return (float)h;
}
__device__ __forceinline__ void gload16(const void* g, void* l) {
    __builtin_amdgcn_global_load_lds(
        (const __attribute__((address_space(1))) unsigned int*)g,
        (__attribute__((address_space(3))) unsigned int*)l,
        16, 0, 0);
}

// ---------------- fused cast f32 -> fp16 for x, Wq,k,v, Wo, omega ----------------
#define NX (BN*DIMS/8)   // 262144
#define NW (WW/8)        // 131072
#define NOM (NFEAT*HDIM/8) // 1024
__global__ __launch_bounds__(256) void cast_all(const float* __restrict__ x,
                                                const float* __restrict__ Wq,
                                                const float* __restrict__ Wk,
                                                const float* __restrict__ Wv,
                                                const float* __restrict__ Wo,
                                                const float* __restrict__ omega,
                                                ushort* __restrict__ xh,
                                                ushort* __restrict__ wqkvh,
                                                ushort* __restrict__ woh,
                                                ushort* __restrict__ omh) {
    const int i = blockIdx.x * 256 + threadIdx.x;
    const float* src; ushort* dst; int off;
    if (i < NX)               { src = x;     dst = xh;                     off = i; }
    else if (i < NX + NW)     { src = Wq;    dst = wqkvh;                  off = i - NX; }
    else if (i < NX + 2 * NW) { src = Wk;    dst = wqkvh + WW;             off = i - NX - NW; }
    else if (i < NX + 3 * NW) { src = Wv;    dst = wqkvh + 2 * (size_t)WW; off = i - NX - 2 * NW; }
    else if (i < NX + 4 * NW) { src = Wo;    dst = woh;                    off = i - NX - 3 * NW; }
    else                      { src = omega; dst = omh;                    off = i - NX - 4 * NW; }
    float4 a = ((const float4*)src)[2 * (size_t)off];
    float4 b = ((const float4*)src)[2 * (size_t)off + 1];
    float v[8] = {a.x, a.y, a.z, a.w, b.x, b.y, b.z, b.w};
    ushort h8[8];
    #pragma unroll
    for (int j = 0; j < 8; ++j) h8[j] = f2h(v[j]);
    *(s8v*)&dst[(size_t)off * 8] = *(s8v*)&h8[0];
}

// ---------------- MFMA GEMM NT; BK=64, swizzled LDS, double-buffered 2-phase pipeline ----------
// XCD-bijective 1D grid (nwg % 8 == 0). Swizzle: LDS (row, slot) holds global (row, slot^(row&7)).
// Pipeline: STAGE(next buf) issued BEFORE compute(cur); ONE barrier per K-step.
template<int BM, bool HOUT>
__global__ __launch_bounds__(256) void gemm_nt_lds(const ushort* __restrict__ A,
                                                   const ushort* __restrict__ B,
                                                   float* __restrict__ C,
                                                   ushort* __restrict__ C16,
                                                   const float* __restrict__ bias,
                                                   int M, int N, int K, int nbx) {
    constexpr int MF = BM / 32;
    constexpr int AI = BM / 32;
    __shared__ __attribute__((aligned(16))) ushort lA[2][BM][64];
    __shared__ __attribute__((aligned(16))) ushort lB[2][128][64];
    const int tid = threadIdx.x;
    const int w = tid >> 6, l = tid & 63, lr = l & 15, lg = l >> 4;
    const int wm = (w >> 1) * (BM / 2), wn = (w & 1) * 64;
    const int nwg = gridDim.x;
    const int q8 = nwg >> 3;
    const int neu = (blockIdx.x & 7) * q8 + (blockIdx.x >> 3);
    const int bx = neu % nbx, by = neu / nbx;
    const int bi = bx * BM, bj = by * 128;
    const int srow = l >> 3;
    const int scol = ((l & 7) ^ (l >> 3)) * 8;

    f4v acc[MF][4] = {};

    auto STAGE = [&](int buf, int k0) {
        #pragma unroll
        for (int i = 0; i < AI; ++i) {
            const int r0 = w * (8 * AI) + i * 8;
            gload16(&A[(size_t)(bi + r0 + srow) * K + k0 + scol], &lA[buf][r0][0]);
        }
        #pragma unroll
        for (int i = 0; i < 4; ++i) {
            const int r0 = w * 32 + i * 8;
            gload16(&B[(size_t)(bj + r0 + srow) * K + k0 + scol], &lB[buf][r0][0]);
        }
    };
    auto COMPUTE = [&](int buf) {
        #pragma unroll
        for (int kk = 0; kk < 2; ++kk) {
            const int soff = ((kk * 4 + lg) ^ (lr & 7)) * 8;
            h8v b_[4];
            #pragma unroll
            for (int j = 0; j < 4; ++j) b_[j] = *(h8v*)&lB[buf][wn + j * 16 + lr][soff];
            #pragma unroll
            for (int i = 0; i < MF; ++i) {
                h8v a_ = *(h8v*)&lA[buf][wm + i * 16 + lr][soff];
                #pragma unroll
                for (int j = 0; j < 4; ++j)
                    acc[i][j] = __builtin_amdgcn_mfma_f32_16x16x32_f16(a_, b_[j], acc[i][j], 0, 0, 0);
            }
        }
    };

    STAGE(0, 0);
    __syncthreads();                 // vmcnt(0): buf0 ready
    int cur = 0;
    for (int k0 = 64; k0 < K; k0 += 64) {
        STAGE(cur ^ 1, k0);          // next tile loads in flight under compute
        COMPUTE(cur);
        __syncthreads();             // drains vmcnt (next buf) + lgkm (cur reads)
        cur ^= 1;
    }
    COMPUTE(cur);

    #pragma unroll
    for (int i = 0; i < MF; ++i)
        #pragma unroll
        for (int j = 0; j < 4; ++j)
            #pragma unroll
            for (int rg = 0; rg < 4; ++rg) {
                const int row = bi + wm + i * 16 + lg * 4 + rg;
                const int col = bj + wn + j * 16 + lr;
                if (HOUT) {
                    C16[(size_t)row * N + col] = f2h(acc[i][j][rg]);
                } else {
                    float r = acc[i][j][rg] + bias[col];
                    C[(size_t)row * N + col] = r;
                }
            }
}

// ---------------- phik_stats: k-path phi + chunk stats ----------------
// grid (32 = b*16+c, NHEADS). Emits blockmax, ssum_raw (fp16), kcsum_raw, vsum.
__global__ __launch_bounds__(256) void phik_stats(const ushort* __restrict__ qkvh,
                                                  const ushort* __restrict__ omh,
                                                  float* __restrict__ blockmax,
                                                  ushort* __restrict__ ssum16,
                                                  float* __restrict__ kcsum,
                                                  float* __restrict__ vsum) {
    __shared__ __attribute__((aligned(16))) ushort lq[64][72];
    __shared__ __attribute__((aligned(16))) ushort lom[128 * 72]; // omega; reused as staging [64][136]
    __shared__ __attribute__((aligned(16))) ushort lktT[128][72];
    __shared__ __attribute__((aligned(16))) ushort lv[64][72];
    __shared__ __attribute__((aligned(16))) ushort lvt[64][72];
    __shared__ float lnorm[64];
    __shared__ float wred[4];
    const int tid = threadIdx.x;
    const int h = blockIdx.y;
    const int bn0 = blockIdx.x * 64;
    const int w = tid >> 6, l = tid & 63, lr = l & 15, lg = l >> 4;
    const int b = blockIdx.x >> 4, c = blockIdx.x & 15;
    const int bh = b * NHEADS + h;

    {
        const int r = tid >> 2, c0 = (tid & 3) * 16;
        const size_t g = (size_t)(bn0 + r) * QKVN + DIMS + h * HDIM + c0;  // k at +DIMS
        s8v v0 = *(const s8v*)&qkvh[g];
        s8v v1 = *(const s8v*)&qkvh[g + 8];
        *(s8v*)&lq[r][c0] = v0;
        *(s8v*)&lq[r][c0 + 8] = v1;
        float p = 0.f;
        #pragma unroll
        for (int j = 0; j < 8; ++j) {
            float a = h2f(((ushort*)&v0)[j]); p += a * a;
            float bb2 = h2f(((ushort*)&v1)[j]); p += bb2 * bb2;
        }
        p += __shfl_xor(p, 1); p += __shfl_xor(p, 2);
        if ((tid & 3) == 0) lnorm[r] = p;
    }
    {
        const int m = tid >> 1, c0 = (tid & 1) * 32;
        #pragma unroll
        for (int i = 0; i < 4; ++i)
            *(s8v*)&lom[m * 72 + c0 + i * 8] = *(const s8v*)&omh[m * HDIM + c0 + i * 8];
    }
    {
        const int r = tid >> 2, c0 = (tid & 3) * 16;
        const size_t g = (size_t)(bn0 + r) * QKVN + 2 * DIMS + h * HDIM + c0;
        *(s8v*)&lv[r][c0]     = *(const s8v*)&qkvh[g];
        *(s8v*)&lv[r][c0 + 8] = *(const s8v*)&qkvh[g + 8];
    }
    __syncthreads();

    f4v acc[8] = {};
    #pragma unroll
    for (int k0 = 0; k0 < 64; k0 += 32) {
        h8v a = *(h8v*)&lq[w * 16 + lr][k0 + lg * 8];
        #pragma unroll
        for (int ct = 0; ct < 8; ++ct) {
            h8v bo = *(h8v*)&lom[(ct * 16 + lr) * 72 + k0 + lg * 8];
            acc[ct] = __builtin_amdgcn_mfma_f32_16x16x32_f16(a, bo, acc[ct], 0, 0, 0);
        }
    }

    const float hs2 = 0.5f * SCALE * SCALE;
    float lvv[4][8];
    float bmax = -3.4e38f;
    #pragma unroll
    for (int rg = 0; rg < 4; ++rg) {
        const int row = w * 16 + lg * 4 + rg;
        const float nh = hs2 * lnorm[row];
        #pragma unroll
        for (int ct = 0; ct < 8; ++ct) {
            lvv[rg][ct] = SCALE * acc[ct][rg] - nh;
            bmax = fmaxf(bmax, lvv[rg][ct]);
        }
    }
    #pragma unroll
    for (int o = 32; o >= 1; o >>= 1) bmax = fmaxf(bmax, __shfl_xor(bmax, o));
    if (l == 0) wred[w] = bmax;
    __syncthreads();   // lom (omega) done + wred ready

    const float bm = fmaxf(fmaxf(wred[0], wred[1]), fmaxf(wred[2], wred[3]));
    if (tid == 0) blockmax[h * 32 + blockIdx.x] = bm;
    #pragma unroll
    for (int rg = 0; rg < 4; ++rg) {
        const int row = w * 16 + lg * 4 + rg;
        #pragma unroll
        for (int ct = 0; ct < 8; ++ct)
            lom[row * 136 + ct * 16 + lr] = f2h(expf(lvv[rg][ct] - bm));
    }
    __syncthreads();

    // p^T -> lktT
    {
        const int m = tid >> 1, nh2 = (tid & 1) * 32;
        ushort tp[32];
        #pragma unroll
        for (int i = 0; i < 32; ++i) tp[i] = lom[(nh2 + i) * 136 + m];
        #pragma unroll
        for (int i = 0; i < 4; ++i) *(s8v*)&lktT[m][nh2 + i * 8] = *(s8v*)&tp[i * 8];
    }
    // V^T -> LDS only
    {
        const int d = tid >> 2, s0 = (tid & 3) * 16;
        ushort tp[16];
        #pragma unroll
        for (int i = 0; i < 16; ++i) tp[i] = lv[s0 + i][d];
        *(s8v*)&lvt[d][s0] = *(s8v*)&tp[0];
        *(s8v*)&lvt[d][s0 + 8] = *(s8v*)&tp[8];
    }
    __syncthreads();

    // ssum_raw[d][m] = sum_n V[n,d]*p[n,m]
    f4v ac2[8] = {};
    #pragma unroll
    for (int k0 = 0; k0 < 64; k0 += 32) {
        h8v a = *(h8v*)&lvt[w * 16 + lr][k0 + lg * 8];
        #pragma unroll
        for (int ct = 0; ct < 8; ++ct) {
            h8v bf = *(h8v*)&lktT[ct * 16 + lr][k0 + lg * 8];
            ac2[ct] = __builtin_amdgcn_mfma_f32_16x16x32_f16(a, bf, ac2[ct], 0, 0, 0);
        }
    }
    const size_t obase = ((size_t)bh * NCH + c) * (HDIM * NFEAT);
    #pragma unroll
    for (int ct = 0; ct < 8; ++ct)
        #pragma unroll
        for (int rg = 0; rg < 4; ++rg) {
            const int d = w * 16 + lg * 4 + rg, m = ct * 16 + lr;
            ssum16[obase + (size_t)d * NFEAT + m] = f2h(ac2[ct][rg]);
        }
    if (tid < 128) {
        float s = 0.f;
        #pragma unroll 8
        for (int i = 0; i < 64; ++i) s += h2f(lktT[tid][i]);
        kcsum[((size_t)bh * NCH + c) * NFEAT + tid] = s;
    }
    if (tid < 64) {
        float s = 0.f;
        #pragma unroll 8
        for (int i = 0; i < 64; ++i) s += h2f(lvt[tid][i]);
        vsum[((size_t)bh * NCH + c) * HDIM + tid] = s;
    }
}

// ---------------- scan_final: recomputes phi(q,k) + V^T in-LDS; inline prefix ----------------
// grid (NCH, 32bh). LDS pool with overlays (73.7 KB -> 2 blocks/CU).
__global__ __launch_bounds__(256) void scan_final(const ushort* __restrict__ qkvh,
                                                  const ushort* __restrict__ omh,
                                                  const ushort* __restrict__ ssum16,
                                                  const float* __restrict__ kcsum,
                                                  const float* __restrict__ vsum,
                                                  const float* __restrict__ blockmax,
                                                  ushort* __restrict__ att_h) {
    __shared__ __attribute__((aligned(16))) ushort pool[35840];
    ushort (*lqt)[72]  = (ushort(*)[72]) &pool[0];       // q then k tile; later lA
    ushort*  lom       = &pool[4608];                    // omega; later lsp
    ushort (*lvt)[72]  = (ushort(*)[72]) &pool[13824];
    ushort (*lq)[136]  = (ushort(*)[136])&pool[18432];   // phiq
    ushort (*lk)[136]  = (ushort(*)[136])&pool[27136];   // phik; first 4608 = V-row staging
    ushort (*lv)[72]   = (ushort(*)[72]) &pool[27136];   // V rows overlay (dead before phik)
    ushort (*lA)[72]   = (ushort(*)[72]) &pool[0];       // overlay lqt
    ushort (*lsp)[136] = (ushort(*)[136])&pool[4608];    // overlay lom
    __shared__ float kc[NFEAT];
    __shared__ float zin[64];
    __shared__ float zp[4][64];
    __shared__ float gred[4];
    __shared__ float lnorm[64];
    const int tid = threadIdx.x;
    const int c = blockIdx.x, bh = blockIdx.y;
    const int b = bh >> 4, h = bh & 15;
    const int n0 = c * CSZ;
    const size_t rowbase = (size_t)b * NN + n0;
    const int w = tid >> 6, l = tid & 63, lr = l & 15, lg = l >> 4;

    // gmax partial (gred read after S0)
    {
        float mxv = fmaxf(blockmax[tid], blockmax[tid + 256]);
        #pragma unroll
        for (int o = 32; o >= 1; o >>= 1) mxv = fmaxf(mxv, __shfl_xor(mxv, o));
        if (l == 0) gred[w] = mxv;
    }
    // load q tile + norms, omega, V rows
    {
        const int r = tid >> 2, c0 = (tid & 3) * 16;
        const size_t g = (rowbase + r) * QKVN + h * HDIM + c0;
        s8v v0 = *(const s8v*)&qkvh[g];
        s8v v1 = *(const s8v*)&qkvh[g + 8];
        *(s8v*)&lqt[r][c0] = v0;
        *(s8v*)&lqt[r][c0 + 8] = v1;
        float p = 0.f;
        #pragma unroll
        for (int j = 0; j < 8; ++j) {
            float a = h2f(((ushort*)&v0)[j]); p += a * a;
            float bb2 = h2f(((ushort*)&v1)[j]); p += bb2 * bb2;
        }
        p += __shfl_xor(p, 1); p += __shfl_xor(p, 2);
        if ((tid & 3) == 0) lnorm[r] = p;
    }
    {
        const int m = tid >> 1, c0 = (tid & 1) * 32;
        #pragma unroll
        for (int i = 0; i < 4; ++i)
            *(s8v*)&lom[m * 72 + c0 + i * 8] = *(const s8v*)&omh[m * HDIM + c0 + i * 8];
    }
    {
        const int r = tid >> 2, c0 = (tid & 3) * 16;
        const size_t g = (rowbase + r) * QKVN + 2 * DIMS + h * HDIM + c0;
        *(s8v*)&lv[r][c0]     = *(const s8v*)&qkvh[g];
        *(s8v*)&lv[r][c0 + 8] = *(const s8v*)&qkvh[g + 8];
    }
    __syncthreads();   // S0

    const float gm = fmaxf(fmaxf(gred[0], gred[1]), fmaxf(gred[2], gred[3]));
    const float hs2 = 0.5f * SCALE * SCALE;

    // V^T: lv -> lvt
    {
        const int d = tid >> 2, s0 = (tid & 3) * 16;
        ushort tp[16];
        #pragma unroll
        for (int i = 0; i < 16; ++i) tp[i] = lv[s0 + i][d];
        *(s8v*)&lvt[d][s0] = *(s8v*)&tp[0];
        *(s8v*)&lvt[d][s0 + 8] = *(s8v*)&tp[8];
    }
    // q-MFMA -> phiq into lq
    {
        f4v acc[8] = {};
        #pragma unroll
        for (int k0 = 0; k0 < 64; k0 += 32) {
            h8v a = *(h8v*)&lqt[w * 16 + lr][k0 + lg * 8];
            #pragma unroll
            for (int ct = 0; ct < 8; ++ct) {
                h8v bo = *(h8v*)&lom[(ct * 16 + lr) * 72 + k0 + lg * 8];
                acc[ct] = __builtin_amdgcn_mfma_f32_16x16x32_f16(a, bo, acc[ct], 0, 0, 0);
            }
        }
        #pragma unroll
        for (int rg = 0; rg < 4; ++rg) {
            const int row = w * 16 + lg * 4 + rg;
            const float nh = hs2 * lnorm[row];
            float lvv[8];
            float mx = -3.4e38f;
            #pragma unroll
            for (int ct = 0; ct < 8; ++ct) {
                lvv[ct] = SCALE * acc[ct][rg] - nh;
                mx = fmaxf(mx, lvv[ct]);
            }
            #pragma unroll
            for (int o = 8; o >= 1; o >>= 1) mx = fmaxf(mx, __shfl_xor(mx, o));
            #pragma unroll
            for (int ct = 0; ct < 8; ++ct)
                lq[row][ct * 16 + lr] = f2h(expf(lvv[ct] - mx) * INV_SQRT_M + 1e-4f);
        }
    }
    __syncthreads();   // S1: lqt free for k-tile; lv consumed

    // load k tile + norms
    {
        const int r = tid >> 2, c0 = (tid & 3) * 16;
        const size_t g = (rowbase + r) * QKVN + DIMS + h * HDIM + c0;
        s8v v0 = *(const s8v*)&qkvh[g];
        s8v v1 = *(const s8v*)&qkvh[g + 8];
        *(s8v*)&lqt[r][c0] = v0;
        *(s8v*)&lqt[r][c0 + 8] = v1;
        float p = 0.f;
        #pragma unroll
        for (int j = 0; j < 8; ++j) {
            float a = h2f(((ushort*)&v0)[j]); p += a * a;
            float bb2 = h2f(((ushort*)&v1)[j]); p += bb2 * bb2;
        }
        p += __shfl_xor(p, 1); p += __shfl_xor(p, 2);
        if ((tid & 3) == 0) lnorm[r] = p;
    }
    __syncthreads();   // S2

    // k-MFMA -> phik into lk (overwrites lv staging, dead)
    const float bm = blockmax[h * 32 + b * 16 + c];
    const float fac = expf(bm - gm) * INV_SQRT_M;
    {
        f4v acc[8] = {};
        #pragma unroll
        for (int k0 = 0; k0 < 64; k0 += 32) {
            h8v a = *(h8v*)&lqt[w * 16 + lr][k0 + lg * 8];
            #pragma unroll
            for (int ct = 0; ct < 8; ++ct) {
                h8v bo = *(h8v*)&lom[(ct * 16 + lr) * 72 + k0 + lg * 8];
                acc[ct] = __builtin_amdgcn_mfma_f32_16x16x32_f16(a, bo, acc[ct], 0, 0, 0);
            }
        }
        __syncthreads();   // S3a: everyone's V-row reads & omega reads done before lk write
        #pragma unroll
        for (int rg = 0; rg < 4; ++rg) {
            const int row = w * 16 + lg * 4 + rg;
            const float nh = hs2 * lnorm[row];
            #pragma unroll
            for (int ct = 0; ct < 8; ++ct) {
                const float lv2 = SCALE * acc[ct][rg] - nh;
                lk[row][ct * 16 + lr] = f2h(expf(lv2 - bm) * fac + 1e-4f);
            }
        }
    }
    __syncthreads();   // S3: lk ready; lom/lqt dead -> lsp/lA usable

    // inline prefix: lsp = sum_{c'<c} fac_c'*ssum_raw + 1e-4*vsum ; kc prefix
    {
        const int d = tid >> 2;
        const int m0 = (tid & 3) * 32;
        float acc[32] = {};
        float vs_tot = 0.f;
        for (int cp = 0; cp < c; ++cp) {
            const float facp = expf(blockmax[h * 32 + b * 16 + cp] - gm) * INV_SQRT_M;
            vs_tot += vsum[((size_t)bh * NCH + cp) * HDIM + d];
            const size_t cb = ((size_t)bh * NCH + cp) * (HDIM * NFEAT) + (size_t)d * NFEAT + m0;
            #pragma unroll
            for (int i = 0; i < 4; ++i) {
                s8v v = *(const s8v*)&ssum16[cb + i * 8];
                #pragma unroll
                for (int j = 0; j < 8; ++j) acc[i * 8 + j] += facp * h2f(((ushort*)&v)[j]);
            }
        }
        const float vadd = 1e-4f * vs_tot;
        ushort o[32];
        #pragma unroll
        for (int i = 0; i < 32; ++i) o[i] = f2h(acc[i] + vadd);
        #pragma unroll
        for (int i = 0; i < 4; ++i) *(s8v*)&lsp[d][m0 + i * 8] = *(s8v*)&o[i * 8];
    }
    if (tid < NFEAT) {
        float a = 0.f;
        for (int cp = 0; cp < c; ++cp) {
            const float facp = expf(blockmax[h * 32 + b * 16 + cp] - gm) * INV_SQRT_M;
            a += facp * kcsum[((size_t)bh * NCH + cp) * NFEAT + tid] + 64.0f * 1e-4f;
        }
        kc[tid] = a;
    }
    __syncthreads();   // S4: lsp, kc ready

    // Phase 1: A = phiq @ phik^T
    f4v a4[4] = {};
    #pragma unroll
    for (int k0 = 0; k0 < 128; k0 += 32) {
        h8v av = *(h8v*)&lq[w * 16 + lr][k0 + lg * 8];
        #pragma unroll
        for (int ct = 0; ct < 4; ++ct) {
            h8v bv = *(h8v*)&lk[ct * 16 + lr][k0 + lg * 8];
            a4[ct] = __builtin_amdgcn_mfma_f32_16x16x32_f16(av, bv, a4[ct], 0, 0, 0);
        }
    }
    float zi[4] = {0.f, 0.f, 0.f, 0.f};
    #pragma unroll
    for (int ct = 0; ct < 4; ++ct) {
        #pragma unroll
        for (int rg = 0; rg < 4; ++rg) {
            const int row = w * 16 + lg * 4 + rg;
            const int col = ct * 16 + lr;
            const float val = (col <= row) ? a4[ct][rg] : 0.f;
            const ushort hq = f2h(val);
            zi[rg] += h2f(hq);
            lA[row][col] = hq;
        }
    }
    #pragma unroll
    for (int rg = 0; rg < 4; ++rg) {
        float z = zi[rg];
        z += __shfl_xor(z, 1); z += __shfl_xor(z, 2);
        z += __shfl_xor(z, 4); z += __shfl_xor(z, 8);
        if (lr == 0) zin[w * 16 + lg * 4 + rg] = z;
    }
    {
        const int row = tid & 63, qq = tid >> 6;
        float s = 0.f;
        #pragma unroll 8
        for (int m = 0; m < 32; ++m) s += h2f(lq[row][qq * 32 + m]) * kc[qq * 32 + m];
        zp[qq][row] = s;
    }
    __syncthreads();   // S5

    // Phase 2: out = Amask @ V + phiq @ Spre
    f4v o4[4] = {};
    #pragma unroll
    for (int k0 = 0; k0 < 64; k0 += 32) {
        h8v av = *(h8v*)&lA[w * 16 + lr][k0 + lg * 8];
        #pragma unroll
        for (int ct = 0; ct < 4; ++ct) {
            h8v bv = *(h8v*)&lvt[ct * 16 + lr][k0 + lg * 8];
            o4[ct] = __builtin_amdgcn_mfma_f32_16x16x32_f16(av, bv, o4[ct], 0, 0, 0);
        }
    }
    #pragma unroll
    for (int k0 = 0; k0 < 128; k0 += 32) {
        h8v av = *(h8v*)&lq[w * 16 + lr][k0 + lg * 8];
        #pragma unroll
        for (int ct = 0; ct < 4; ++ct) {
            h8v bv = *(h8v*)&lsp[ct * 16 + lr][k0 + lg * 8];
            o4[ct] = __builtin_amdgcn_mfma_f32_16x16x32_f16(av, bv, o4[ct], 0, 0, 0);
        }
    }
    #pragma unroll
    for (int rg = 0; rg < 4; ++rg) {
        const int row = w * 16 + lg * 4 + rg;
        const float z = zin[row] + zp[0][row] + zp[1][row] + zp[2][row] + zp[3][row] + 1e-6f;
        const float rz = 1.f / z;
        #pragma unroll
        for (int ct = 0; ct < 4; ++ct) {
            const int d = ct * 16 + lr;
            att_h[(rowbase + row) * DIMS + h * HDIM + d] = f2h(o4[ct][rg] * rz);
        }
    }
}

extern "C" void kernel_launch(void* const* d_in, const int* in_sizes, int n_in,
                              void* d_out, int out_size, void* d_ws, size_t ws_size,
                              hipStream_t stream) {
    const float* x     = (const float*)d_in[0];
    const float* omega = (const float*)d_in[1];
    const float* Wq    = (const float*)d_in[2];
    const float* Wk    = (const float*)d_in[3];
    const float* Wv    = (const float*)d_in[4];
    const float* Wo    = (const float*)d_in[5];
    const float* bo    = (const float*)d_in[6];
    float* out = (float*)d_out;

    const size_t PROJ = (size_t)BN * DIMS;                 // 2M elems
    const size_t PHI  = (size_t)BB * NHEADS * NN * NFEAT;  // 4M elems
    ushort* qkvh    = (ushort*)d_ws;                       // 12 MB
    ushort* xh      = qkvh + (size_t)BN * QKVN;            // 4 MB
    ushort* wqkvh   = xh + PROJ;                           // 6 MB
    ushort* woh     = wqkvh + (size_t)QKVN * DIMS;         // 2 MB
    ushort* omh     = woh + WW;                            // 16 KB
    ushort* ssum16  = omh + NFEAT * HDIM;                  // 8 MB
    ushort* att_hb  = ssum16 + PHI;                        // 4 MB
    float*  kcsum   = (float*)(att_hb + PROJ);             // 256 KB
    float*  blockmax= kcsum + 32 * NCH * NFEAT;            // 512
    float*  vsum    = blockmax + 512;                      // 32*16*64

    // 1: fused casts (x, Wq,k,v, Wo, omega)
    cast_all<<<(NX + 4 * NW + NOM) / 256, 256, 0, stream>>>(x, Wq, Wk, Wv, Wo, omega,
                                                            xh, wqkvh, woh, omh);

    // 2: fused QKV projection -> fp16 [2048 x 3072]; BK=64 dbuf pipeline, 768 blocks = 3/CU
    gemm_nt_lds<64, true><<<(BN / 64) * (QKVN / 128), 256, 0, stream>>>(
        xh, wqkvh, nullptr, qkvh, nullptr, BN, QKVN, DIMS, BN / 64);

    // 3: key-path phi + chunk stats (512 blocks)
    dim3 pg(32, NHEADS);
    phik_stats<<<pg, 256, 0, stream>>>(qkvh, omh, blockmax, ssum16, kcsum, vsum);

    // 4: causal attention; recomputes phi(q,k) + V^T per chunk, inline prefix
    dim3 cg(NCH, BB * NHEADS);
    scan_final<<<cg, 256, 0, stream>>>(qkvh, omh, ssum16, kcsum, vsum,
                                       blockmax, att_hb);

    // 5: output projection; BM=32 dbuf pipeline -> 512 blocks = 2/CU
    gemm_nt_lds<32, false><<<(BN / 32) * (DIMS / 128), 256, 0, stream>>>(
        att_hb, woh, out, nullptr, bo, BN, DIMS, DIMS, BN / 32);
}